// Round 2
// baseline (5841.887 us; speedup 1.0000x reference)
//
#include <hip/hip_runtime.h>
#include <hip/hip_bf16.h>
#include <cstddef>

// ---------------- problem constants ----------------
#define TT   365
#define NN   400
#define TN   (TT*NN)            // 146000
#define HD   26                 // head dim
#define NH   4                  // heads

#define CEILDIV(a,b) (((a)+(b)-1)/(b))

typedef __hip_bfloat16 bf16;
__device__ __forceinline__ float b2f(bf16 v){ return __bfloat162float(v); }
__device__ __forceinline__ bf16  f2b(float v){ return __float2bfloat16(v); }

// ---------------- workspace layout ----------------
// bf16 region (elements):
//   B0: h / h1 (in-place LN1)                          TN*104
//   B1: z1 -> att1 -> m                                TN*104
//   B2: hcat -> qkv(+concat in [0:208]) -> p0|p1 -> mlp hidden   TN*312
//   B3: att0 -> h2                                     TN*104
// fp32 region: kvs_s, ksum_s, kvs_t, ksum_t, y
static constexpr size_t NB0 = (size_t)TN*104;
static constexpr size_t NB1 = (size_t)TN*104;
static constexpr size_t NB2 = (size_t)TN*312;
static constexpr size_t NB3 = (size_t)TN*104;
static constexpr size_t NBF = NB0+NB1+NB2+NB3;               // bf16 elems
static constexpr size_t NKVS_S  = (size_t)TT*NH*HD*HD;
static constexpr size_t NKSUM_S = (size_t)TT*NH*HD;
static constexpr size_t NKVS_T  = (size_t)NN*NH*HD*HD;
static constexpr size_t NKSUM_T = (size_t)NN*NH*HD;
static constexpr size_t NY      = (size_t)NN*104;
static constexpr size_t WS_NEEDED = NBF*2 + (NKVS_S+NKSUM_S+NKVS_T+NKSUM_T+NY)*4;

// ---------------- kernels ----------------

// hcat[t,n,0:24] = x[n,t,:] @ W_in + b_in ; hcat[t,n,24:104] = adp[t,n,:]
__global__ void __launch_bounds__(128) hcat_kernel(
    const float* __restrict__ x, const float* __restrict__ W_in,
    const float* __restrict__ b_in, const float* __restrict__ adp,
    bf16* __restrict__ hcat)
{
    int bid = blockIdx.x;            // t*400 + n
    int t = bid / NN, n = bid - t*NN;
    int tid = threadIdx.x;
    if (tid < 24) {
        float s = b_in[tid];
        size_t xb = ((size_t)n*TT + t)*3;
        #pragma unroll
        for (int i = 0; i < 3; ++i) s += x[xb + i] * W_in[i*24 + tid];
        hcat[(size_t)bid*104 + tid] = f2b(s);
    } else if (tid < 104) {
        hcat[(size_t)bid*104 + tid] = f2b(adp[(size_t)bid*80 + (tid - 24)]);
    }
}

// C[M,Nc] = A[M,K](lda, bf16) @ W[K,Nc](ldw, fp32) + bias, optional relu. 32 rows x 64 cols.
__global__ void __launch_bounds__(256) gemm_rt(
    const bf16* __restrict__ A, int lda,
    const float* __restrict__ W, int ldw, const float* __restrict__ bias,
    bf16* __restrict__ C, int M, int K, int Nc, int relu)
{
    __shared__ float As[32][210];      // K <= 208
    int m0 = blockIdx.x * 32;
    int c0 = blockIdx.y * 64;
    int tid = threadIdx.x;
    int cc = tid & 63, rg = tid >> 6;  // rg 0..3

    for (int r = rg; r < 32; r += 4) {
        int m = m0 + r;
        const bf16* ap = A + (size_t)m * lda;
        for (int k = cc; k < K; k += 64)
            As[r][k] = (m < M) ? b2f(ap[k]) : 0.f;
    }
    __syncthreads();

    int c = c0 + cc;
    if (c < Nc) {
        float acc[8];
        #pragma unroll
        for (int i = 0; i < 8; ++i) acc[i] = 0.f;
        const float* wp = W + c;
        for (int k = 0; k < K; ++k) {
            float w = wp[(size_t)k * ldw];
            #pragma unroll
            for (int i = 0; i < 8; ++i) acc[i] += As[rg*8 + i][k] * w;
        }
        float b = bias ? bias[c] : 0.f;
        #pragma unroll
        for (int i = 0; i < 8; ++i) {
            int m = m0 + rg*8 + i;
            if (m < M) {
                float v = acc[i] + b;
                if (relu) v = fmaxf(v, 0.f);
                C[(size_t)m * Nc + c] = f2b(v);
            }
        }
    }
}

// z1[t] = softmax(relu(adp[t] @ adp[t]^T), axis=-1) @ h[t]   (flash-style, 16 rows/block)
#define ZR 16
__global__ void __launch_bounds__(256) z1_fused(
    const float* __restrict__ adp, const bf16* __restrict__ h,
    bf16* __restrict__ z1)
{
    int t  = blockIdx.y;
    int r0 = blockIdx.x * ZR;
    int tid = threadIdx.x;
    __shared__ float S[ZR][404];
    __shared__ float Ar[ZR][80];
    __shared__ float stage[6720];      // union: adp cols (stride 81) / h cols (stride 105)
    __shared__ float red[ZR][16];
    __shared__ float rstat[2*ZR];

    for (int idx = tid; idx < ZR*80; idx += 256) {
        int r = idx / 80, e = idx - r*80;
        int row = r0 + r;
        Ar[r][e] = (row < NN) ? adp[((size_t)t*NN + row)*80 + e] : 0.f;
    }
    int cc = tid & 63, rb = tid >> 6;
    // phase 1: S = relu(Ar @ adp^T)
    for (int c0 = 0; c0 < NN; c0 += 64) {
        int cw = min(64, NN - c0);
        __syncthreads();
        for (int idx = tid; idx < cw*80; idx += 256) {
            int cL = idx / 80, e = idx - cL*80;
            stage[cL*81 + e] = adp[((size_t)t*NN + c0 + cL)*80 + e];
        }
        __syncthreads();
        if (cc < cw) {
            float dot[4] = {0.f,0.f,0.f,0.f};
            for (int e = 0; e < 80; ++e) {
                float bb = stage[cc*81 + e];
                #pragma unroll
                for (int i = 0; i < 4; ++i) dot[i] += Ar[rb + 4*i][e] * bb;
            }
            #pragma unroll
            for (int i = 0; i < 4; ++i) S[rb + 4*i][c0 + cc] = fmaxf(dot[i], 0.f);
        }
    }
    __syncthreads();
    // phase 2: softmax over 400 cols per row (relu vals >= 0, so max-init 0 is exact)
    int r = tid >> 4, j = tid & 15;
    float mx = 0.f;
    for (int c = j; c < NN; c += 16) mx = fmaxf(mx, S[r][c]);
    red[r][j] = mx;
    __syncthreads();
    if (j == 0) {
        float m2 = red[r][0];
        #pragma unroll
        for (int k = 1; k < 16; ++k) m2 = fmaxf(m2, red[r][k]);
        rstat[r] = m2;
    }
    __syncthreads();
    float m2 = rstat[r];
    float sm = 0.f;
    for (int c = j; c < NN; c += 16) {
        float e = __expf(S[r][c] - m2);
        S[r][c] = e;
        sm += e;
    }
    red[r][j] = sm;
    __syncthreads();
    if (j == 0) {
        float s2 = 0.f;
        #pragma unroll
        for (int k = 0; k < 16; ++k) s2 += red[r][k];
        rstat[ZR + r] = 1.f / s2;
    }
    // phase 3: z1 = P @ h  (normalization folded into epilogue)
    float acc[7] = {0.f,0.f,0.f,0.f,0.f,0.f,0.f};
    for (int c0 = 0; c0 < NN; c0 += 64) {
        int cw = min(64, NN - c0);
        __syncthreads();
        for (int idx = tid; idx < cw*104; idx += 256) {
            int cL = idx / 104, d = idx - cL*104;
            stage[cL*105 + d] = b2f(h[((size_t)t*NN + c0 + cL)*104 + d]);
        }
        __syncthreads();
        for (int c = 0; c < cw; ++c) {
            float p = S[r][c0 + c];
            #pragma unroll
            for (int i = 0; i < 7; ++i) {
                int d = j + 16*i;
                if (d < 104) acc[i] += p * stage[c*105 + d];
            }
        }
    }
    int row = r0 + r;
    if (row < NN) {
        float inv = rstat[ZR + r];
        #pragma unroll
        for (int i = 0; i < 7; ++i) {
            int d = j + 16*i;
            if (d < 104) z1[((size_t)t*NN + row)*104 + d] = f2b(acc[i] * inv);
        }
    }
}

// KV summary: kvs[b,h,m,d] = sum_l kn[l,m]*v[l,d]; ksum[b,h,m] = sum_l kn[l,m]
__global__ void __launch_bounds__(256) kvs_kernel(
    const bf16* __restrict__ qkv, float* __restrict__ kvs, float* __restrict__ ksum,
    int L, long long strideB, long long strideL)
{
    int b = blockIdx.x, head = blockIdx.y;
    long long base = (long long)b*strideB + 104 + head*HD;   // k; v at +104
    __shared__ float kc[32][27], vc[32][27], inv[32];
    int tid = threadIdx.x;
    float acc[3] = {0.f,0.f,0.f};
    float ks = 0.f;
    for (int l0 = 0; l0 < L; l0 += 32) {
        int lw = min(32, L - l0);
        __syncthreads();
        for (int idx = tid; idx < lw*HD; idx += 256) {
            int ll = idx / HD, m = idx - ll*HD;
            long long a = base + (long long)(l0 + ll)*strideL + m;
            kc[ll][m] = b2f(qkv[a]);
            vc[ll][m] = b2f(qkv[a + 104]);
        }
        __syncthreads();
        if (tid < lw) {
            float ss = 0.f;
            #pragma unroll
            for (int m = 0; m < HD; ++m) { float v = kc[tid][m]; ss += v*v; }
            inv[tid] = 1.f / fmaxf(sqrtf(ss), 1e-12f);
        }
        __syncthreads();
        for (int idx = tid; idx < lw*HD; idx += 256) {
            int ll = idx / HD, m = idx - ll*HD;
            kc[ll][m] *= inv[ll];
        }
        __syncthreads();
        #pragma unroll
        for (int jj = 0; jj < 3; ++jj) {
            int p = tid + jj*256;
            if (p < HD*HD) {
                int m = p / HD, d = p - m*HD;
                float a = 0.f;
                for (int ll = 0; ll < lw; ++ll) a += kc[ll][m] * vc[ll][d];
                acc[jj] += a;
            }
        }
        if (tid < HD) {
            float a = 0.f;
            for (int ll = 0; ll < lw; ++ll) a += kc[ll][tid];
            ks += a;
        }
    }
    long long ob = ((long long)b*NH + head) * (HD*HD);
    #pragma unroll
    for (int jj = 0; jj < 3; ++jj) {
        int p = tid + jj*256;
        if (p < HD*HD) kvs[ob + p] = acc[jj];
    }
    if (tid < HD) ksum[((long long)b*NH + head)*HD + tid] = ks;
}

// Apply linear attention (spatial + temporal); write concat into qkv[row][0:208]
__global__ void __launch_bounds__(256) attn_apply(
    bf16* __restrict__ qkv,
    const float* __restrict__ kvs_s, const float* __restrict__ ksum_s,
    const float* __restrict__ kvs_t, const float* __restrict__ ksum_t)
{
    int bid = blockIdx.x;
    int t = bid / NN, n = bid - t*NN;
    int tid = threadIdx.x;
    __shared__ float qn[104], vrow[104], invq[NH], den[2*NH];
    size_t rb = (size_t)bid * 312;
    if (tid < 104) { qn[tid] = b2f(qkv[rb + tid]); vrow[tid] = b2f(qkv[rb + 208 + tid]); }
    __syncthreads();
    if (tid < NH) {
        float ss = 0.f;
        #pragma unroll
        for (int m = 0; m < HD; ++m) { float v = qn[tid*HD + m]; ss += v*v; }
        invq[tid] = 1.f / fmaxf(sqrtf(ss), 1e-12f);
    }
    __syncthreads();
    if (tid < 104) qn[tid] *= invq[tid / HD];
    __syncthreads();
    if (tid < 2*NH) {
        int hh = tid & 3;
        const float* ks = (tid < NH) ? &ksum_s[((size_t)t*NH + hh)*HD]
                                     : &ksum_t[((size_t)n*NH + hh)*HD];
        float s = 0.f;
        #pragma unroll
        for (int m = 0; m < HD; ++m) s += qn[hh*HD + m] * ks[m];
        den[tid] = s + ((tid < NH) ? (float)NN : (float)TT);
    }
    __syncthreads();
    if (tid < 208) {
        int sp = (tid < 104);
        int d  = sp ? tid : tid - 104;
        int hh = d / HD, dd = d - hh*HD;
        const float* kv = sp ? &kvs_s[((size_t)t*NH + hh)*(HD*HD) + dd]
                             : &kvs_t[((size_t)n*NH + hh)*(HD*HD) + dd];
        float num = 0.f;
        #pragma unroll
        for (int m = 0; m < HD; ++m) num += qn[hh*HD + m] * kv[m*HD];
        float Lf = sp ? (float)NN : (float)TT;
        num += Lf * vrow[d];
        qkv[rb + tid] = f2b(num / den[sp ? hh : NH + hh]);
    }
}

__device__ __forceinline__ float bsum128(float v, float* red, int tid) {
    #pragma unroll
    for (int off = 32; off > 0; off >>= 1) v += __shfl_down(v, off, 64);
    __syncthreads();
    if ((tid & 63) == 0) red[tid >> 6] = v;
    __syncthreads();
    return red[0] + red[1];
}

// h1 = LN(2*(h + att0*p0 + 0.01*att1*p1)) -> in-place into h
__global__ void __launch_bounds__(128) ln1_kernel(
    bf16* __restrict__ h, const bf16* __restrict__ att0, const bf16* __restrict__ att1,
    const bf16* __restrict__ p0, const bf16* __restrict__ p1,
    const float* __restrict__ gamma, const float* __restrict__ beta)
{
    int tid = threadIdx.x;
    size_t base = (size_t)blockIdx.x * 104;
    __shared__ float red[2];
    float x = 0.f;
    if (tid < 104) {
        float hv = b2f(h[base + tid]);
        x = 2.f * (hv + b2f(att0[base + tid])*b2f(p0[base + tid])
                      + 0.01f*b2f(att1[base + tid])*b2f(p1[base + tid]));
    }
    float mean = bsum128(x, red, tid) * (1.f/104.f);
    float dx = (tid < 104) ? (x - mean) : 0.f;
    float var = bsum128(dx*dx, red, tid) * (1.f/104.f);
    if (tid < 104)
        h[base + tid] = f2b(dx * rsqrtf(var + 1e-5f) * gamma[tid] + beta[tid]);
}

// h2 = LN(h1 + m)
__global__ void __launch_bounds__(128) ln2_kernel(
    const bf16* __restrict__ h1, const bf16* __restrict__ m,
    const float* __restrict__ gamma, const float* __restrict__ beta,
    bf16* __restrict__ h2)
{
    int tid = threadIdx.x;
    size_t base = (size_t)blockIdx.x * 104;
    __shared__ float red[2];
    float x = 0.f;
    if (tid < 104) x = b2f(h1[base + tid]) + b2f(m[base + tid]);
    float mean = bsum128(x, red, tid) * (1.f/104.f);
    float dx = (tid < 104) ? (x - mean) : 0.f;
    float var = bsum128(dx*dx, red, tid) * (1.f/104.f);
    if (tid < 104)
        h2[base + tid] = f2b(dx * rsqrtf(var + 1e-5f) * gamma[tid] + beta[tid]);
}

__global__ void __launch_bounds__(256) y_init_kernel(float* __restrict__ y, const float* __restrict__ ep_b) {
    int i = blockIdx.x*256 + threadIdx.x;
    if (i < NN*104) y[i] = ep_b[i % 104];
}

// y[n,j] += sum_{t in chunk, d} h2[t,n,d] * ep_w[(t*104+d)*104 + j]   (split-K, atomic)
__global__ void __launch_bounds__(256) ep_kernel(
    const bf16* __restrict__ h2, const float* __restrict__ ep_w, float* __restrict__ y)
{
    int n0 = blockIdx.x * 32;
    int t0 = blockIdx.y * 12;
    int t1 = min(TT, t0 + 12);
    int tid = threadIdx.x;
    int r = tid >> 3, j = tid & 7;
    __shared__ float hs[32][105];
    float acc[13];
    #pragma unroll
    for (int i = 0; i < 13; ++i) acc[i] = 0.f;
    for (int t = t0; t < t1; ++t) {
        __syncthreads();
        for (int idx = tid; idx < 32*104; idx += 256) {
            int rr = idx / 104, d = idx - rr*104;
            int n = n0 + rr;
            hs[rr][d] = (n < NN) ? b2f(h2[((size_t)t*NN + n)*104 + d]) : 0.f;
        }
        __syncthreads();
        const float* wp = ep_w + (size_t)t*104*104 + j;
        for (int d = 0; d < 104; ++d) {
            float a = hs[r][d];
            const float* w = wp + (size_t)d*104;
            #pragma unroll
            for (int i = 0; i < 13; ++i) acc[i] += a * w[8*i];
        }
    }
    int n = n0 + r;
    if (n < NN) {
        #pragma unroll
        for (int i = 0; i < 13; ++i) atomicAdd(&y[(size_t)n*104 + j + 8*i], acc[i]);
    }
}

// y = y + relu(y@w1+b1)@w2+b2   (one block per row)
__global__ void __launch_bounds__(256) enc_kernel(
    float* __restrict__ y, const float* __restrict__ w1, const float* __restrict__ b1,
    const float* __restrict__ w2, const float* __restrict__ b2)
{
    int n = blockIdx.x;
    int tid = threadIdx.x;
    __shared__ float yr[104], hid[208];
    if (tid < 104) yr[tid] = y[(size_t)n*104 + tid];
    __syncthreads();
    if (tid < 208) {
        float s = b1[tid];
        for (int k = 0; k < 104; ++k) s += yr[k] * w1[(size_t)k*208 + tid];
        hid[tid] = fmaxf(s, 0.f);
    }
    __syncthreads();
    if (tid < 104) {
        float s = b2[tid];
        for (int k = 0; k < 208; ++k) s += hid[k] * w2[(size_t)k*104 + tid];
        y[(size_t)n*104 + tid] = yr[tid] + s;
    }
}

// out[n,t] = y[n,:] @ out_w[:,t] + out_b[t]
__global__ void __launch_bounds__(256) out_kernel(
    const float* __restrict__ y, const float* __restrict__ out_w,
    const float* __restrict__ out_b, float* __restrict__ out)
{
    int n = blockIdx.x;
    int tid = threadIdx.x;
    __shared__ float yr[104];
    if (tid < 104) yr[tid] = y[(size_t)n*104 + tid];
    __syncthreads();
    for (int t = tid; t < TT; t += 256) {
        float s = out_b[t];
        for (int d = 0; d < 104; ++d) s += yr[d] * out_w[(size_t)d*TT + t];
        out[(size_t)n*TT + t] = s;
    }
}

// ---------------- launch ----------------
extern "C" void kernel_launch(void* const* d_in, const int* in_sizes, int n_in,
                              void* d_out, int out_size, void* d_ws, size_t ws_size,
                              hipStream_t stream) {
    if (ws_size < WS_NEEDED) return;   // fail validation readably instead of faulting

    const float* x      = (const float*)d_in[0];
    const float* W_in   = (const float*)d_in[1];
    const float* b_in   = (const float*)d_in[2];
    const float* adp    = (const float*)d_in[3];
    const float* W_tp   = (const float*)d_in[4];
    const float* b_tp   = (const float*)d_in[5];
    const float* qkv_w  = (const float*)d_in[6];
    const float* op_w   = (const float*)d_in[7];
    const float* op_b   = (const float*)d_in[8];
    const float* pw_w   = (const float*)d_in[9];
    const float* pw_b   = (const float*)d_in[10];
    const float* fc_w1  = (const float*)d_in[11];
    const float* fc_b1  = (const float*)d_in[12];
    const float* fc_w2  = (const float*)d_in[13];
    const float* fc_b2  = (const float*)d_in[14];
    const float* ln1_g  = (const float*)d_in[15];
    const float* ln1_b  = (const float*)d_in[16];
    const float* ln2_g  = (const float*)d_in[17];
    const float* ln2_b  = (const float*)d_in[18];
    const float* ep_w   = (const float*)d_in[19];
    const float* ep_b   = (const float*)d_in[20];
    const float* enc_w1 = (const float*)d_in[21];
    const float* enc_b1 = (const float*)d_in[22];
    const float* enc_w2 = (const float*)d_in[23];
    const float* enc_b2 = (const float*)d_in[24];
    const float* out_w  = (const float*)d_in[25];
    const float* out_b  = (const float*)d_in[26];

    bf16* B0 = (bf16*)d_ws;            // h / h1
    bf16* B1 = B0 + NB0;               // z1 / att1 / m
    bf16* B2 = B1 + NB1;               // hcat / qkv+concat / p0|p1 / hidden
    bf16* B3 = B2 + NB2;               // att0 / h2
    float* kvs_s  = (float*)(B3 + NB3);
    float* ksum_s = kvs_s + NKVS_S;
    float* kvs_t  = ksum_s + NKSUM_S;
    float* ksum_t = kvs_t + NKVS_T;
    float* ybuf   = ksum_t + NKSUM_T;

    dim3 gM32c2(CEILDIV(TN,32), 2);   // Nc=104
    dim3 gM32c4(CEILDIV(TN,32), 4);   // Nc=208
    dim3 gM32c5(CEILDIV(TN,32), 5);   // Nc=312

    // 1. hcat = [input_proj(x), adp]  -> B2 (104w)
    hcat_kernel<<<TN, 128, 0, stream>>>(x, W_in, b_in, adp, B2);
    // 2. h = hcat @ W_tp + b_tp  -> B0
    gemm_rt<<<gM32c2, 256, 0, stream>>>(B2, 104, W_tp, 104, b_tp, B0, TN, 104, 104, 0);
    // 3. z1 = softmax(relu(adp adp^T)) @ h  -> B1
    z1_fused<<<dim3(CEILDIV(NN,ZR), TT), 256, 0, stream>>>(adp, B0, B1);
    // 4. attention 0 on h
    gemm_rt<<<gM32c5, 256, 0, stream>>>(B0, 104, qkv_w, 312, nullptr, B2, TN, 104, 312, 0);
    kvs_kernel<<<dim3(TT, NH), 256, 0, stream>>>(B2, kvs_s, ksum_s, NN, (long long)NN*312, 312);
    kvs_kernel<<<dim3(NN, NH), 256, 0, stream>>>(B2, kvs_t, ksum_t, TT, 312, (long long)NN*312);
    attn_apply<<<TN, 256, 0, stream>>>(B2, kvs_s, ksum_s, kvs_t, ksum_t);
    gemm_rt<<<gM32c2, 256, 0, stream>>>(B2, 312, op_w, 104, op_b, B3, TN, 208, 104, 0);   // att0 -> B3
    // 5. attention 1 on z1
    gemm_rt<<<gM32c5, 256, 0, stream>>>(B1, 104, qkv_w + 104*312, 312, nullptr, B2, TN, 104, 312, 0);
    kvs_kernel<<<dim3(TT, NH), 256, 0, stream>>>(B2, kvs_s, ksum_s, NN, (long long)NN*312, 312);
    kvs_kernel<<<dim3(NN, NH), 256, 0, stream>>>(B2, kvs_t, ksum_t, TT, 312, (long long)NN*312);
    attn_apply<<<TN, 256, 0, stream>>>(B2, kvs_s, ksum_s, kvs_t, ksum_t);
    gemm_rt<<<gM32c2, 256, 0, stream>>>(B2, 312, op_w + 208*104, 104, op_b + 104, B1, TN, 208, 104, 0); // att1 -> B1
    // 6. pointwise gates -> B2 (p0 at [0:TN*104], p1 after)
    gemm_rt<<<gM32c2, 256, 0, stream>>>(B0, 104, pw_w, 104, pw_b, B2, TN, 104, 104, 0);
    gemm_rt<<<gM32c2, 256, 0, stream>>>(B3, 104, pw_w + 104*104, 104, pw_b + 104, B2 + (size_t)TN*104, TN, 104, 104, 0);
    // 7. g + LN1 (in-place B0 -> h1)
    ln1_kernel<<<TN, 128, 0, stream>>>(B0, B3, B1, B2, B2 + (size_t)TN*104, ln1_g, ln1_b);
    // 8. MLP + LN2
    gemm_rt<<<gM32c4, 256, 0, stream>>>(B0, 104, fc_w1, 208, fc_b1, B2, TN, 104, 208, 1);   // hidden -> B2
    gemm_rt<<<gM32c2, 256, 0, stream>>>(B2, 208, fc_w2, 104, fc_b2, B1, TN, 208, 104, 0);   // m -> B1
    ln2_kernel<<<TN, 128, 0, stream>>>(B0, B1, ln2_g, ln2_b, B3);                           // h2 -> B3
    // 9. encoder_proj (split-K GEMM with atomics)
    y_init_kernel<<<CEILDIV(NN*104,256), 256, 0, stream>>>(ybuf, ep_b);
    ep_kernel<<<dim3(CEILDIV(NN,32), CEILDIV(TT,12)), 256, 0, stream>>>(B3, ep_w, ybuf);
    // 10. residual MLP blocks
    for (int i = 0; i < 3; ++i)
        enc_kernel<<<NN, 256, 0, stream>>>(ybuf, enc_w1 + (size_t)i*104*208, enc_b1 + (size_t)i*208,
                                           enc_w2 + (size_t)i*208*104, enc_b2 + (size_t)i*104);
    // 11. output projection
    out_kernel<<<NN, 256, 0, stream>>>(ybuf, out_w, out_b, (float*)d_out);
}

// Round 3
// 4272.918 us; speedup vs baseline: 1.3672x; 1.3672x over previous
//
#include <hip/hip_runtime.h>
#include <hip/hip_bf16.h>
#include <cstddef>

// ---------------- problem constants ----------------
#define TT   365
#define NN   400
#define TN   (TT*NN)            // 146000
#define HD   26                 // head dim
#define NH   4                  // heads

#define CEILDIV(a,b) (((a)+(b)-1)/(b))

typedef __hip_bfloat16 bf16;
typedef short short8v __attribute__((ext_vector_type(8)));
typedef float float4v __attribute__((ext_vector_type(4)));
__device__ __forceinline__ float b2f(bf16 v){ return __bfloat162float(v); }
__device__ __forceinline__ bf16  f2b(float v){ return __float2bfloat16(v); }

// ---------------- workspace layout ----------------
static constexpr size_t NB0 = (size_t)TN*104;   // h / h1
static constexpr size_t NB1 = (size_t)TN*104;   // z1 -> att1 -> m
static constexpr size_t NB2 = (size_t)TN*312;   // hcat -> qkv+concat -> p0|p1 -> hidden
static constexpr size_t NB3 = (size_t)TN*104;   // att0 -> h2
static constexpr size_t NBF = NB0+NB1+NB2+NB3;
static constexpr size_t NKVS_S  = (size_t)TT*NH*HD*HD;
static constexpr size_t NKSUM_S = (size_t)TT*NH*HD;
static constexpr size_t NKVS_T  = (size_t)NN*NH*HD*HD;
static constexpr size_t NKSUM_T = (size_t)NN*NH*HD;
static constexpr size_t NY      = (size_t)NN*104;
static constexpr size_t NAUX    = NKVS_S+NKSUM_S+NKVS_T+NKSUM_T+NY;
// transposed bf16 weights (Wt[n][kp], zero-padded k)
static constexpr size_t NW_TP   = 104*128;
static constexpr size_t NW_QKV  = 312*128;   // x2
static constexpr size_t NW_OP   = 104*224;   // x2
static constexpr size_t NW_PW   = 104*128;   // x2
static constexpr size_t NW_FC1  = 208*128;
static constexpr size_t NW_FC2  = 104*224;
static constexpr size_t NWT     = NW_TP + 2*NW_QKV + 2*NW_OP + 2*NW_PW + NW_FC1 + NW_FC2;
static constexpr size_t WS_NEEDED = NBF*2 + NAUX*4 + NWT*2;

// ---------------- weight prep: Wt[n*KP+k] = bf16(W[k*Nc+n]), zero pad k>=K ----------------
__global__ void __launch_bounds__(256) prep_w(
    const float* __restrict__ W, bf16* __restrict__ Wt, int K, int Nc, int KP)
{
    int idx = blockIdx.x*256 + threadIdx.x;
    if (idx >= Nc*KP) return;
    int n = idx / KP, k = idx - n*KP;
    Wt[idx] = (k < K) ? f2b(W[(size_t)k*Nc + n]) : f2b(0.f);
}

// ---------------- hcat ----------------
__global__ void __launch_bounds__(128) hcat_kernel(
    const float* __restrict__ x, const float* __restrict__ W_in,
    const float* __restrict__ b_in, const float* __restrict__ adp,
    bf16* __restrict__ hcat)
{
    int bid = blockIdx.x;            // t*400 + n
    int t = bid / NN, n = bid - t*NN;
    int tid = threadIdx.x;
    if (tid < 24) {
        float s = b_in[tid];
        size_t xb = ((size_t)n*TT + t)*3;
        #pragma unroll
        for (int i = 0; i < 3; ++i) s += x[xb + i] * W_in[i*24 + tid];
        hcat[(size_t)bid*104 + tid] = f2b(s);
    } else if (tid < 104) {
        hcat[(size_t)bid*104 + tid] = f2b(adp[(size_t)bid*80 + (tid - 24)]);
    }
}

// ---------------- MFMA GEMM: C[M,Nc] = A[M,K](lda,bf16) @ W + bias ----------------
// Wt is pre-transposed [Nc][KP] bf16. Block = 64 rows x 64 cols, 4 waves.
template<int KP>
__global__ void __launch_bounds__(256) gemm_mf(
    const bf16* __restrict__ A, int lda, int K,
    const bf16* __restrict__ Wt, const float* __restrict__ bias,
    bf16* __restrict__ C, int M, int Nc, int relu)
{
    constexpr int STR = KP + 8;          // bf16 elems; +8 keeps b128 reads 2-way (free)
    __shared__ bf16 As[64*STR];
    __shared__ bf16 Ws[64*STR];
    int m0 = blockIdx.x * 64;
    int c0 = blockIdx.y * 64;
    int tid = threadIdx.x;
    const int KW = KP/2;                 // uints per row
    for (int idx = tid; idx < 64*KW; idx += 256) {
        int r = idx / KW, kw = idx - r*KW;
        int m = m0 + r, k = kw*2;
        uint v = 0;
        if (m < M && k < K) v = *(const uint*)(A + (size_t)m*lda + k);
        *(uint*)(&As[r*STR + k]) = v;
    }
    for (int idx = tid; idx < 64*KW; idx += 256) {
        int r = idx / KW, kw = idx - r*KW;
        int n = c0 + r, k = kw*2;
        uint v = 0;
        if (n < Nc) v = *(const uint*)(Wt + (size_t)n*KP + k);
        *(uint*)(&Ws[r*STR + k]) = v;
    }
    __syncthreads();

    int lane = tid & 63, w = tid >> 6;
    int n16 = lane & 15, quad = lane >> 4;
    constexpr int KS = KP/32;
    short8v af[KS];
    #pragma unroll
    for (int s = 0; s < KS; ++s)
        af[s] = *(const short8v*)(&As[(16*w + n16)*STR + s*32 + quad*8]);
    float4v acc[4];
    #pragma unroll
    for (int ct = 0; ct < 4; ++ct) { float4v z = {0.f,0.f,0.f,0.f}; acc[ct] = z; }
    #pragma unroll
    for (int ct = 0; ct < 4; ++ct) {
        #pragma unroll
        for (int s = 0; s < KS; ++s) {
            short8v bfr = *(const short8v*)(&Ws[(ct*16 + n16)*STR + s*32 + quad*8]);
            acc[ct] = __builtin_amdgcn_mfma_f32_16x16x32_bf16(af[s], bfr, acc[ct], 0, 0, 0);
        }
    }
    #pragma unroll
    for (int ct = 0; ct < 4; ++ct) {
        int c = c0 + ct*16 + n16;
        if (c < Nc) {
            float b = bias ? bias[c] : 0.f;
            #pragma unroll
            for (int reg = 0; reg < 4; ++reg) {
                int m = m0 + 16*w + quad*4 + reg;
                if (m < M) {
                    float v = acc[ct][reg] + b;
                    if (relu) v = fmaxf(v, 0.f);
                    C[(size_t)m*Nc + c] = f2b(v);
                }
            }
        }
    }
}

// ---------------- MFMA z1: z1[t] = softmax(relu(adp adp^T)) @ h[t] ----------------
// scores are tiny (|S| < ~0.5) so exp without max-subtraction is exact (shift-invariant).
__global__ void __launch_bounds__(256) z1_mf(
    const float* __restrict__ adp, const bf16* __restrict__ h, bf16* __restrict__ z1)
{
    constexpr int SAD = 104;  // stride for 96-wide (K=80 padded) tiles
    constexpr int SP  = 72;   // stride for P / Ht (64 k-cols)
    __shared__ bf16 As[64*SAD];     // adp rows (A operand of S), persists
    __shared__ bf16 P[64*SP];       // exp(S) chunk in A-layout
    __shared__ bf16 U[112*SP];      // union: Bt (64*104=6656) / Ht (112*72=8064)
    int t = blockIdx.y;
    int r0 = blockIdx.x * 64;
    int tid = threadIdx.x;
    int lane = tid & 63, w = tid >> 6, n16 = lane & 15, quad = lane >> 4;

    for (int idx = tid; idx < 64*96; idx += 256) {
        int r = idx / 96, e = idx - r*96;
        int row = r0 + r;
        float v = (row < NN && e < 80) ? adp[((size_t)t*NN + row)*80 + e] : 0.f;
        As[r*SAD + e] = f2b(v);
    }
    __syncthreads();
    short8v af[3];
    #pragma unroll
    for (int s = 0; s < 3; ++s)
        af[s] = *(const short8v*)(&As[(16*w + n16)*SAD + s*32 + quad*8]);

    float4v onum[7];
    #pragma unroll
    for (int dt = 0; dt < 7; ++dt) { float4v z = {0.f,0.f,0.f,0.f}; onum[dt] = z; }
    float rs[4] = {0.f,0.f,0.f,0.f};

    bf16* Bt = U;
    bf16* Ht = U;

    for (int c0 = 0; c0 < NN; c0 += 64) {
        int cw = min(64, NN - c0);
        // stage Bt: cols of S as rows (adp[t][c0+r][e])
        for (int idx = tid; idx < 64*96; idx += 256) {
            int r = idx / 96, e = idx - r*96;
            float v = (r < cw && e < 80) ? adp[((size_t)t*NN + c0 + r)*80 + e] : 0.f;
            Bt[r*SAD + e] = f2b(v);
        }
        __syncthreads();
        float4v sc[4];
        #pragma unroll
        for (int ct = 0; ct < 4; ++ct) { float4v z = {0.f,0.f,0.f,0.f}; sc[ct] = z; }
        #pragma unroll
        for (int ct = 0; ct < 4; ++ct) {
            #pragma unroll
            for (int s = 0; s < 3; ++s) {
                short8v bfr = *(const short8v*)(&Bt[(ct*16 + n16)*SAD + s*32 + quad*8]);
                sc[ct] = __builtin_amdgcn_mfma_f32_16x16x32_bf16(af[s], bfr, sc[ct], 0, 0, 0);
            }
        }
        __syncthreads();   // all waves done reading Bt before Ht overwrites U
        // exp + mask OOB cols + write P (A-layout round-trip) + rowsum
        #pragma unroll
        for (int ct = 0; ct < 4; ++ct) {
            bool colok = (c0 + ct*16 + n16) < NN;
            #pragma unroll
            for (int reg = 0; reg < 4; ++reg) {
                float e = colok ? __expf(fmaxf(sc[ct][reg], 0.f)) : 0.f;
                rs[reg] += e;
                P[(16*w + quad*4 + reg)*SP + ct*16 + n16] = f2b(e);
            }
        }
        // stage Ht[d][cL] = h[t][c0+cL][d]  (112 x 64, zero-padded)
        for (int idx = tid; idx < 112*64; idx += 256) {
            int d = idx % 112, cL = idx / 112;
            bf16 v = f2b(0.f);
            if (d < 104 && cL < cw) v = h[((size_t)t*NN + c0 + cL)*104 + d];
            Ht[d*SP + cL] = v;
        }
        __syncthreads();
        short8v pf[2];
        #pragma unroll
        for (int s = 0; s < 2; ++s)
            pf[s] = *(const short8v*)(&P[(16*w + n16)*SP + s*32 + quad*8]);
        #pragma unroll
        for (int dt = 0; dt < 7; ++dt) {
            #pragma unroll
            for (int s = 0; s < 2; ++s) {
                short8v bfr = *(const short8v*)(&Ht[(dt*16 + n16)*SP + s*32 + quad*8]);
                onum[dt] = __builtin_amdgcn_mfma_f32_16x16x32_bf16(pf[s], bfr, onum[dt], 0, 0, 0);
            }
        }
        __syncthreads();   // before next chunk overwrites Bt/Ht/P
    }
    #pragma unroll
    for (int reg = 0; reg < 4; ++reg) {
        float v = rs[reg];
        v += __shfl_xor(v, 1, 64);
        v += __shfl_xor(v, 2, 64);
        v += __shfl_xor(v, 4, 64);
        v += __shfl_xor(v, 8, 64);
        rs[reg] = v;
    }
    #pragma unroll
    for (int reg = 0; reg < 4; ++reg) {
        int row = r0 + 16*w + quad*4 + reg;
        if (row < NN) {
            float inv = 1.f / rs[reg];
            #pragma unroll
            for (int dt = 0; dt < 7; ++dt) {
                int d = dt*16 + n16;
                if (d < 104)
                    z1[((size_t)t*NN + row)*104 + d] = f2b(onum[dt][reg] * inv);
            }
        }
    }
}

// ---------------- linear-attention KV summaries ----------------
__global__ void __launch_bounds__(256) kvs_kernel(
    const bf16* __restrict__ qkv, float* __restrict__ kvs, float* __restrict__ ksum,
    int L, long long strideB, long long strideL)
{
    int b = blockIdx.x, head = blockIdx.y;
    long long base = (long long)b*strideB + 104 + head*HD;   // k; v at +104
    __shared__ float kc[32][27], vc[32][27], inv[32];
    int tid = threadIdx.x;
    float acc[3] = {0.f,0.f,0.f};
    float ks = 0.f;
    for (int l0 = 0; l0 < L; l0 += 32) {
        int lw = min(32, L - l0);
        __syncthreads();
        for (int idx = tid; idx < lw*HD; idx += 256) {
            int ll = idx / HD, m = idx - ll*HD;
            long long a = base + (long long)(l0 + ll)*strideL + m;
            kc[ll][m] = b2f(qkv[a]);
            vc[ll][m] = b2f(qkv[a + 104]);
        }
        __syncthreads();
        if (tid < lw) {
            float ss = 0.f;
            #pragma unroll
            for (int m = 0; m < HD; ++m) { float v = kc[tid][m]; ss += v*v; }
            inv[tid] = 1.f / fmaxf(sqrtf(ss), 1e-12f);
        }
        __syncthreads();
        for (int idx = tid; idx < lw*HD; idx += 256) {
            int ll = idx / HD, m = idx - ll*HD;
            kc[ll][m] *= inv[ll];
        }
        __syncthreads();
        #pragma unroll
        for (int jj = 0; jj < 3; ++jj) {
            int p = tid + jj*256;
            if (p < HD*HD) {
                int m = p / HD, d = p - m*HD;
                float a = 0.f;
                for (int ll = 0; ll < lw; ++ll) a += kc[ll][m] * vc[ll][d];
                acc[jj] += a;
            }
        }
        if (tid < HD) {
            float a = 0.f;
            for (int ll = 0; ll < lw; ++ll) a += kc[ll][tid];
            ks += a;
        }
    }
    long long ob = ((long long)b*NH + head) * (HD*HD);
    #pragma unroll
    for (int jj = 0; jj < 3; ++jj) {
        int p = tid + jj*256;
        if (p < HD*HD) kvs[ob + p] = acc[jj];
    }
    if (tid < HD) ksum[((long long)b*NH + head)*HD + tid] = ks;
}

// ---------------- apply linear attention; concat into qkv[row][0:208] ----------------
__global__ void __launch_bounds__(256) attn_apply(
    bf16* __restrict__ qkv,
    const float* __restrict__ kvs_s, const float* __restrict__ ksum_s,
    const float* __restrict__ kvs_t, const float* __restrict__ ksum_t)
{
    int bid = blockIdx.x;
    int t = bid / NN, n = bid - t*NN;
    int tid = threadIdx.x;
    __shared__ float qn[104], vrow[104], invq[NH], den[2*NH];
    size_t rb = (size_t)bid * 312;
    if (tid < 104) { qn[tid] = b2f(qkv[rb + tid]); vrow[tid] = b2f(qkv[rb + 208 + tid]); }
    __syncthreads();
    if (tid < NH) {
        float ss = 0.f;
        #pragma unroll
        for (int m = 0; m < HD; ++m) { float v = qn[tid*HD + m]; ss += v*v; }
        invq[tid] = 1.f / fmaxf(sqrtf(ss), 1e-12f);
    }
    __syncthreads();
    if (tid < 104) qn[tid] *= invq[tid / HD];
    __syncthreads();
    if (tid < 2*NH) {
        int hh = tid & 3;
        const float* ks = (tid < NH) ? &ksum_s[((size_t)t*NH + hh)*HD]
                                     : &ksum_t[((size_t)n*NH + hh)*HD];
        float s = 0.f;
        #pragma unroll
        for (int m = 0; m < HD; ++m) s += qn[hh*HD + m] * ks[m];
        den[tid] = s + ((tid < NH) ? (float)NN : (float)TT);
    }
    __syncthreads();
    if (tid < 208) {
        int sp = (tid < 104);
        int d  = sp ? tid : tid - 104;
        int hh = d / HD, dd = d - hh*HD;
        const float* kv = sp ? &kvs_s[((size_t)t*NH + hh)*(HD*HD) + dd]
                             : &kvs_t[((size_t)n*NH + hh)*(HD*HD) + dd];
        float num = 0.f;
        #pragma unroll
        for (int m = 0; m < HD; ++m) num += qn[hh*HD + m] * kv[m*HD];
        float Lf = sp ? (float)NN : (float)TT;
        num += Lf * vrow[d];
        qkv[rb + tid] = f2b(num / den[sp ? hh : NH + hh]);
    }
}

__device__ __forceinline__ float bsum128(float v, float* red, int tid) {
    #pragma unroll
    for (int off = 32; off > 0; off >>= 1) v += __shfl_down(v, off, 64);
    __syncthreads();
    if ((tid & 63) == 0) red[tid >> 6] = v;
    __syncthreads();
    return red[0] + red[1];
}

__global__ void __launch_bounds__(128) ln1_kernel(
    bf16* __restrict__ h, const bf16* __restrict__ att0, const bf16* __restrict__ att1,
    const bf16* __restrict__ p0, const bf16* __restrict__ p1,
    const float* __restrict__ gamma, const float* __restrict__ beta)
{
    int tid = threadIdx.x;
    size_t base = (size_t)blockIdx.x * 104;
    __shared__ float red[2];
    float x = 0.f;
    if (tid < 104) {
        float hv = b2f(h[base + tid]);
        x = 2.f * (hv + b2f(att0[base + tid])*b2f(p0[base + tid])
                      + 0.01f*b2f(att1[base + tid])*b2f(p1[base + tid]));
    }
    float mean = bsum128(x, red, tid) * (1.f/104.f);
    float dx = (tid < 104) ? (x - mean) : 0.f;
    float var = bsum128(dx*dx, red, tid) * (1.f/104.f);
    if (tid < 104)
        h[base + tid] = f2b(dx * rsqrtf(var + 1e-5f) * gamma[tid] + beta[tid]);
}

__global__ void __launch_bounds__(128) ln2_kernel(
    const bf16* __restrict__ h1, const bf16* __restrict__ m,
    const float* __restrict__ gamma, const float* __restrict__ beta,
    bf16* __restrict__ h2)
{
    int tid = threadIdx.x;
    size_t base = (size_t)blockIdx.x * 104;
    __shared__ float red[2];
    float x = 0.f;
    if (tid < 104) x = b2f(h1[base + tid]) + b2f(m[base + tid]);
    float mean = bsum128(x, red, tid) * (1.f/104.f);
    float dx = (tid < 104) ? (x - mean) : 0.f;
    float var = bsum128(dx*dx, red, tid) * (1.f/104.f);
    if (tid < 104)
        h2[base + tid] = f2b(dx * rsqrtf(var + 1e-5f) * gamma[tid] + beta[tid]);
}

__global__ void __launch_bounds__(256) y_init_kernel(float* __restrict__ y, const float* __restrict__ ep_b) {
    int i = blockIdx.x*256 + threadIdx.x;
    if (i < NN*104) y[i] = ep_b[i % 104];
}

__global__ void __launch_bounds__(256) ep_kernel(
    const bf16* __restrict__ h2, const float* __restrict__ ep_w, float* __restrict__ y)
{
    int n0 = blockIdx.x * 32;
    int t0 = blockIdx.y * 12;
    int t1 = min(TT, t0 + 12);
    int tid = threadIdx.x;
    int r = tid >> 3, j = tid & 7;
    __shared__ float hs[32][105];
    float acc[13];
    #pragma unroll
    for (int i = 0; i < 13; ++i) acc[i] = 0.f;
    for (int t = t0; t < t1; ++t) {
        __syncthreads();
        for (int idx = tid; idx < 32*104; idx += 256) {
            int rr = idx / 104, d = idx - rr*104;
            int n = n0 + rr;
            hs[rr][d] = (n < NN) ? b2f(h2[((size_t)t*NN + n)*104 + d]) : 0.f;
        }
        __syncthreads();
        const float* wp = ep_w + (size_t)t*104*104 + j;
        for (int d = 0; d < 104; ++d) {
            float a = hs[r][d];
            const float* w = wp + (size_t)d*104;
            #pragma unroll
            for (int i = 0; i < 13; ++i) acc[i] += a * w[8*i];
        }
    }
    int n = n0 + r;
    if (n < NN) {
        #pragma unroll
        for (int i = 0; i < 13; ++i) atomicAdd(&y[(size_t)n*104 + j + 8*i], acc[i]);
    }
}

__global__ void __launch_bounds__(256) enc_kernel(
    float* __restrict__ y, const float* __restrict__ w1, const float* __restrict__ b1,
    const float* __restrict__ w2, const float* __restrict__ b2)
{
    int n = blockIdx.x;
    int tid = threadIdx.x;
    __shared__ float yr[104], hid[208];
    if (tid < 104) yr[tid] = y[(size_t)n*104 + tid];
    __syncthreads();
    if (tid < 208) {
        float s = b1[tid];
        for (int k = 0; k < 104; ++k) s += yr[k] * w1[(size_t)k*208 + tid];
        hid[tid] = fmaxf(s, 0.f);
    }
    __syncthreads();
    if (tid < 104) {
        float s = b2[tid];
        for (int k = 0; k < 208; ++k) s += hid[k] * w2[(size_t)k*104 + tid];
        y[(size_t)n*104 + tid] = yr[tid] + s;
    }
}

__global__ void __launch_bounds__(256) out_kernel(
    const float* __restrict__ y, const float* __restrict__ out_w,
    const float* __restrict__ out_b, float* __restrict__ out)
{
    int n = blockIdx.x;
    int tid = threadIdx.x;
    __shared__ float yr[104];
    if (tid < 104) yr[tid] = y[(size_t)n*104 + tid];
    __syncthreads();
    for (int t = tid; t < TT; t += 256) {
        float s = out_b[t];
        for (int d = 0; d < 104; ++d) s += yr[d] * out_w[(size_t)d*TT + t];
        out[(size_t)n*TT + t] = s;
    }
}

// ---------------- launch ----------------
extern "C" void kernel_launch(void* const* d_in, const int* in_sizes, int n_in,
                              void* d_out, int out_size, void* d_ws, size_t ws_size,
                              hipStream_t stream) {
    if (ws_size < WS_NEEDED) return;   // readable failure instead of page fault

    const float* x      = (const float*)d_in[0];
    const float* W_in   = (const float*)d_in[1];
    const float* b_in   = (const float*)d_in[2];
    const float* adp    = (const float*)d_in[3];
    const float* W_tp   = (const float*)d_in[4];
    const float* b_tp   = (const float*)d_in[5];
    const float* qkv_w  = (const float*)d_in[6];
    const float* op_w   = (const float*)d_in[7];
    const float* op_b   = (const float*)d_in[8];
    const float* pw_w   = (const float*)d_in[9];
    const float* pw_b   = (const float*)d_in[10];
    const float* fc_w1  = (const float*)d_in[11];
    const float* fc_b1  = (const float*)d_in[12];
    const float* fc_w2  = (const float*)d_in[13];
    const float* fc_b2  = (const float*)d_in[14];
    const float* ln1_g  = (const float*)d_in[15];
    const float* ln1_b  = (const float*)d_in[16];
    const float* ln2_g  = (const float*)d_in[17];
    const float* ln2_b  = (const float*)d_in[18];
    const float* ep_w   = (const float*)d_in[19];
    const float* ep_b   = (const float*)d_in[20];
    const float* enc_w1 = (const float*)d_in[21];
    const float* enc_b1 = (const float*)d_in[22];
    const float* enc_w2 = (const float*)d_in[23];
    const float* enc_b2 = (const float*)d_in[24];
    const float* out_w  = (const float*)d_in[25];
    const float* out_b  = (const float*)d_in[26];

    bf16* B0 = (bf16*)d_ws;
    bf16* B1 = B0 + NB0;
    bf16* B2 = B1 + NB1;
    bf16* B3 = B2 + NB2;
    float* kvs_s  = (float*)(B3 + NB3);
    float* ksum_s = kvs_s + NKVS_S;
    float* kvs_t  = ksum_s + NKSUM_S;
    float* ksum_t = kvs_t + NKVS_T;
    float* ybuf   = ksum_t + NKSUM_T;
    bf16* wtp   = (bf16*)(ybuf + NY);
    bf16* wqkv0 = wtp + NW_TP;
    bf16* wqkv1 = wqkv0 + NW_QKV;
    bf16* wop0  = wqkv1 + NW_QKV;
    bf16* wop1  = wop0 + NW_OP;
    bf16* wpw0  = wop1 + NW_OP;
    bf16* wpw1  = wpw0 + NW_PW;
    bf16* wfc1  = wpw1 + NW_PW;
    bf16* wfc2  = wfc1 + NW_FC1;

    // 0. weight prep (tiny)
    prep_w<<<CEILDIV(104*128,256), 256, 0, stream>>>(W_tp, wtp, 104, 104, 128);
    prep_w<<<CEILDIV(312*128,256), 256, 0, stream>>>(qkv_w, wqkv0, 104, 312, 128);
    prep_w<<<CEILDIV(312*128,256), 256, 0, stream>>>(qkv_w + 104*312, wqkv1, 104, 312, 128);
    prep_w<<<CEILDIV(104*224,256), 256, 0, stream>>>(op_w, wop0, 208, 104, 224);
    prep_w<<<CEILDIV(104*224,256), 256, 0, stream>>>(op_w + 208*104, wop1, 208, 104, 224);
    prep_w<<<CEILDIV(104*128,256), 256, 0, stream>>>(pw_w, wpw0, 104, 104, 128);
    prep_w<<<CEILDIV(104*128,256), 256, 0, stream>>>(pw_w + 104*104, wpw1, 104, 104, 128);
    prep_w<<<CEILDIV(208*128,256), 256, 0, stream>>>(fc_w1, wfc1, 104, 208, 128);
    prep_w<<<CEILDIV(104*224,256), 256, 0, stream>>>(fc_w2, wfc2, 208, 104, 224);

    const int GX = CEILDIV(TN, 64);     // 2282
    dim3 g2(GX, 2), g4(GX, 4), g5(GX, 5);

    // 1. hcat -> B2
    hcat_kernel<<<TN, 128, 0, stream>>>(x, W_in, b_in, adp, B2);
    // 2. h = hcat @ W_tp + b_tp -> B0
    gemm_mf<128><<<g2, 256, 0, stream>>>(B2, 104, 104, wtp, b_tp, B0, TN, 104, 0);
    // 3. z1 -> B1
    z1_mf<<<dim3(7, TT), 256, 0, stream>>>(adp, B0, B1);
    // 4. attention 0 on h
    gemm_mf<128><<<g5, 256, 0, stream>>>(B0, 104, 104, wqkv0, nullptr, B2, TN, 312, 0);
    kvs_kernel<<<dim3(TT, NH), 256, 0, stream>>>(B2, kvs_s, ksum_s, NN, (long long)NN*312, 312);
    kvs_kernel<<<dim3(NN, NH), 256, 0, stream>>>(B2, kvs_t, ksum_t, TT, 312, (long long)NN*312);
    attn_apply<<<TN, 256, 0, stream>>>(B2, kvs_s, ksum_s, kvs_t, ksum_t);
    gemm_mf<224><<<g2, 256, 0, stream>>>(B2, 312, 208, wop0, op_b, B3, TN, 104, 0);      // att0 -> B3
    // 5. attention 1 on z1
    gemm_mf<128><<<g5, 256, 0, stream>>>(B1, 104, 104, wqkv1, nullptr, B2, TN, 312, 0);
    kvs_kernel<<<dim3(TT, NH), 256, 0, stream>>>(B2, kvs_s, ksum_s, NN, (long long)NN*312, 312);
    kvs_kernel<<<dim3(NN, NH), 256, 0, stream>>>(B2, kvs_t, ksum_t, TT, 312, (long long)NN*312);
    attn_apply<<<TN, 256, 0, stream>>>(B2, kvs_s, ksum_s, kvs_t, ksum_t);
    gemm_mf<224><<<g2, 256, 0, stream>>>(B2, 312, 208, wop1, op_b + 104, B1, TN, 104, 0); // att1 -> B1
    // 6. pointwise gates -> B2
    gemm_mf<128><<<g2, 256, 0, stream>>>(B0, 104, 104, wpw0, pw_b, B2, TN, 104, 0);
    gemm_mf<128><<<g2, 256, 0, stream>>>(B3, 104, 104, wpw1, pw_b + 104, B2 + (size_t)TN*104, TN, 104, 0);
    // 7. LN1 in-place (B0 -> h1)
    ln1_kernel<<<TN, 128, 0, stream>>>(B0, B3, B1, B2, B2 + (size_t)TN*104, ln1_g, ln1_b);
    // 8. MLP + LN2
    gemm_mf<128><<<g4, 256, 0, stream>>>(B0, 104, 104, wfc1, fc_b1, B2, TN, 208, 1);
    gemm_mf<224><<<g2, 256, 0, stream>>>(B2, 208, 208, wfc2, fc_b2, B1, TN, 104, 0);
    ln2_kernel<<<TN, 128, 0, stream>>>(B0, B1, ln2_g, ln2_b, B3);                        // h2 -> B3
    // 9. encoder_proj
    y_init_kernel<<<CEILDIV(NN*104,256), 256, 0, stream>>>(ybuf, ep_b);
    ep_kernel<<<dim3(CEILDIV(NN,32), CEILDIV(TT,12)), 256, 0, stream>>>(B3, ep_w, ybuf);
    // 10. residual MLP blocks
    for (int i = 0; i < 3; ++i)
        enc_kernel<<<NN, 256, 0, stream>>>(ybuf, enc_w1 + (size_t)i*104*208, enc_b1 + (size_t)i*208,
                                           enc_w2 + (size_t)i*208*104, enc_b2 + (size_t)i*104);
    // 11. output projection
    out_kernel<<<NN, 256, 0, stream>>>(ybuf, out_w, out_b, (float*)d_out);
}

// Round 4
// 2845.686 us; speedup vs baseline: 2.0529x; 1.5015x over previous
//
#include <hip/hip_runtime.h>
#include <hip/hip_bf16.h>
#include <cstddef>

// ---------------- problem constants ----------------
#define TT   365
#define NN   400
#define TN   (TT*NN)            // 146000
#define HD   26                 // head dim
#define NH   4                  // heads

#define CEILDIV(a,b) (((a)+(b)-1)/(b))

typedef __hip_bfloat16 bf16;
typedef short short8v __attribute__((ext_vector_type(8)));
typedef float float4v __attribute__((ext_vector_type(4)));
__device__ __forceinline__ float b2f(bf16 v){ return __bfloat162float(v); }
__device__ __forceinline__ bf16  f2b(float v){ return __float2bfloat16(v); }

// ---------------- workspace layout ----------------
static constexpr size_t NB0 = (size_t)TN*104;   // h / h1
static constexpr size_t NB1 = (size_t)TN*104;   // z1 -> att1 -> m
static constexpr size_t NB2 = (size_t)TN*312;   // hcat -> qkv+concat -> p0|p1 -> hidden
static constexpr size_t NB3 = (size_t)TN*104;   // att0 -> h2
static constexpr size_t NBF = NB0+NB1+NB2+NB3;
static constexpr size_t NKVS_S  = (size_t)TT*NH*HD*HD;
static constexpr size_t NKSUM_S = (size_t)TT*NH*HD;
static constexpr size_t NKVS_T  = (size_t)NN*NH*HD*HD;
static constexpr size_t NKSUM_T = (size_t)NN*NH*HD;
static constexpr size_t NY      = (size_t)NN*104;
static constexpr size_t NAUX    = NKVS_S+NKSUM_S+NKVS_T+NKSUM_T+NY;
// transposed bf16 weights (Wt[n][kp], zero-padded k)
static constexpr size_t NW_TP   = 104*128;
static constexpr size_t NW_QKV  = 312*128;   // x2
static constexpr size_t NW_OP   = 104*224;   // x2
static constexpr size_t NW_PW   = 104*128;   // x2
static constexpr size_t NW_FC1  = 208*128;
static constexpr size_t NW_FC2  = 104*224;
static constexpr size_t NW_EPT  = (size_t)104*37960;   // ep_w transposed, no pad
static constexpr size_t NWT     = NW_TP + 2*NW_QKV + 2*NW_OP + 2*NW_PW + NW_FC1 + NW_FC2 + NW_EPT;
static constexpr size_t WS_NEEDED = NBF*2 + NAUX*4 + NWT*2;

// ---------------- weight prep: Wt[n*KP+k] = bf16(W[k*Nc+n]), zero pad k>=K ----------------
__global__ void __launch_bounds__(256) prep_w(
    const float* __restrict__ W, bf16* __restrict__ Wt, int K, int Nc, int KP)
{
    int idx = blockIdx.x*256 + threadIdx.x;
    if (idx >= Nc*KP) return;
    int n = idx / KP, k = idx - n*KP;
    Wt[idx] = (k < K) ? f2b(W[(size_t)k*Nc + n]) : f2b(0.f);
}

// ---------------- hcat ----------------
__global__ void __launch_bounds__(128) hcat_kernel(
    const float* __restrict__ x, const float* __restrict__ W_in,
    const float* __restrict__ b_in, const float* __restrict__ adp,
    bf16* __restrict__ hcat)
{
    int bid = blockIdx.x;            // t*400 + n
    int t = bid / NN, n = bid - t*NN;
    int tid = threadIdx.x;
    if (tid < 24) {
        float s = b_in[tid];
        size_t xb = ((size_t)n*TT + t)*3;
        #pragma unroll
        for (int i = 0; i < 3; ++i) s += x[xb + i] * W_in[i*24 + tid];
        hcat[(size_t)bid*104 + tid] = f2b(s);
    } else if (tid < 104) {
        hcat[(size_t)bid*104 + tid] = f2b(adp[(size_t)bid*80 + (tid - 24)]);
    }
}

// ---------------- MFMA GEMM: C[M,Nc] = A[M,K](lda,bf16) @ W + bias ----------------
// Wt is pre-transposed [Nc][KP] bf16. Block = 64 rows x 64 cols, 4 waves.
template<int KP>
__global__ void __launch_bounds__(256) gemm_mf(
    const bf16* __restrict__ A, int lda, int K,
    const bf16* __restrict__ Wt, const float* __restrict__ bias,
    bf16* __restrict__ C, int M, int Nc, int relu)
{
    constexpr int STR = KP + 8;          // bf16 elems; +8 keeps b128 reads 2-way (free)
    __shared__ bf16 As[64*STR];
    __shared__ bf16 Ws[64*STR];
    int m0 = blockIdx.x * 64;
    int c0 = blockIdx.y * 64;
    int tid = threadIdx.x;
    const int KW = KP/2;                 // uints per row
    for (int idx = tid; idx < 64*KW; idx += 256) {
        int r = idx / KW, kw = idx - r*KW;
        int m = m0 + r, k = kw*2;
        uint v = 0;
        if (m < M && k < K) v = *(const uint*)(A + (size_t)m*lda + k);
        *(uint*)(&As[r*STR + k]) = v;
    }
    for (int idx = tid; idx < 64*KW; idx += 256) {
        int r = idx / KW, kw = idx - r*KW;
        int n = c0 + r, k = kw*2;
        uint v = 0;
        if (n < Nc) v = *(const uint*)(Wt + (size_t)n*KP + k);
        *(uint*)(&Ws[r*STR + k]) = v;
    }
    __syncthreads();

    int lane = tid & 63, w = tid >> 6;
    int n16 = lane & 15, quad = lane >> 4;
    constexpr int KS = KP/32;
    short8v af[KS];
    #pragma unroll
    for (int s = 0; s < KS; ++s)
        af[s] = *(const short8v*)(&As[(16*w + n16)*STR + s*32 + quad*8]);
    float4v acc[4];
    #pragma unroll
    for (int ct = 0; ct < 4; ++ct) { float4v z = {0.f,0.f,0.f,0.f}; acc[ct] = z; }
    #pragma unroll
    for (int ct = 0; ct < 4; ++ct) {
        #pragma unroll
        for (int s = 0; s < KS; ++s) {
            short8v bfr = *(const short8v*)(&Ws[(ct*16 + n16)*STR + s*32 + quad*8]);
            acc[ct] = __builtin_amdgcn_mfma_f32_16x16x32_bf16(af[s], bfr, acc[ct], 0, 0, 0);
        }
    }
    #pragma unroll
    for (int ct = 0; ct < 4; ++ct) {
        int c = c0 + ct*16 + n16;
        if (c < Nc) {
            float b = bias ? bias[c] : 0.f;
            #pragma unroll
            for (int reg = 0; reg < 4; ++reg) {
                int m = m0 + 16*w + quad*4 + reg;
                if (m < M) {
                    float v = acc[ct][reg] + b;
                    if (relu) v = fmaxf(v, 0.f);
                    C[(size_t)m*Nc + c] = f2b(v);
                }
            }
        }
    }
}

// ---------------- MFMA encoder_proj: y[400,104] += sum_t h2[t] @ ep_w[t] ----------------
// split-K over t-chunks of 8; atomicAdd into bias-initialized y (fp32).
__global__ void __launch_bounds__(256) ep_mf(
    const bf16* __restrict__ h2, const bf16* __restrict__ wt, float* __restrict__ y)
{
    constexpr int STR = 136;             // 128 padded K + 8
    __shared__ bf16 As[64*STR];
    __shared__ bf16 Ws[64*STR];
    int m0 = blockIdx.x * 64;
    int c0 = blockIdx.y * 64;
    int t0 = blockIdx.z * 8;
    int t1 = min(TT, t0 + 8);
    int tid = threadIdx.x;
    int lane = tid & 63, w = tid >> 6, n16 = lane & 15, quad = lane >> 4;

    float4v acc[4];
    #pragma unroll
    for (int ct = 0; ct < 4; ++ct) { float4v z = {0.f,0.f,0.f,0.f}; acc[ct] = z; }

    for (int t = t0; t < t1; ++t) {
        for (int idx = tid; idx < 64*64; idx += 256) {     // 64 rows x 64 uints
            int r = idx >> 6, k = (idx & 63)*2;
            int m = m0 + r;
            uint va = 0;
            if (m < NN && k < 104) va = *(const uint*)(h2 + ((size_t)t*NN + m)*104 + k);
            *(uint*)(&As[r*STR + k]) = va;
            int c = c0 + r;
            uint vw = 0;
            if (c < 104 && k < 104) vw = *(const uint*)(wt + (size_t)c*37960 + t*104 + k);
            *(uint*)(&Ws[r*STR + k]) = vw;
        }
        __syncthreads();
        short8v af[4];
        #pragma unroll
        for (int s = 0; s < 4; ++s)
            af[s] = *(const short8v*)(&As[(16*w + n16)*STR + s*32 + quad*8]);
        #pragma unroll
        for (int ct = 0; ct < 4; ++ct) {
            #pragma unroll
            for (int s = 0; s < 4; ++s) {
                short8v bfr = *(const short8v*)(&Ws[(ct*16 + n16)*STR + s*32 + quad*8]);
                acc[ct] = __builtin_amdgcn_mfma_f32_16x16x32_bf16(af[s], bfr, acc[ct], 0, 0, 0);
            }
        }
        __syncthreads();
    }
    #pragma unroll
    for (int ct = 0; ct < 4; ++ct) {
        int c = c0 + ct*16 + n16;
        if (c < 104) {
            #pragma unroll
            for (int reg = 0; reg < 4; ++reg) {
                int m = m0 + 16*w + quad*4 + reg;
                if (m < NN) atomicAdd(&y[(size_t)m*104 + c], acc[ct][reg]);
            }
        }
    }
}

// ---------------- MFMA z1: z1[t] = softmax(relu(adp adp^T)) @ h[t] ----------------
// scores are tiny (|S| < ~0.5) so exp without max-subtraction is exact (shift-invariant).
__global__ void __launch_bounds__(256) z1_mf(
    const float* __restrict__ adp, const bf16* __restrict__ h, bf16* __restrict__ z1)
{
    constexpr int SAD = 104;  // stride for 96-wide (K=80 padded) tiles
    constexpr int SP  = 72;   // stride for P / Ht (64 k-cols)
    __shared__ bf16 As[64*SAD];     // adp rows (A operand of S), persists
    __shared__ bf16 P[64*SP];       // exp(S) chunk in A-layout
    __shared__ bf16 U[112*SP];      // union: Bt (64*104=6656) / Ht (112*72=8064)
    int t = blockIdx.y;
    int r0 = blockIdx.x * 64;
    int tid = threadIdx.x;
    int lane = tid & 63, w = tid >> 6, n16 = lane & 15, quad = lane >> 4;

    for (int idx = tid; idx < 64*96; idx += 256) {
        int r = idx / 96, e = idx - r*96;
        int row = r0 + r;
        float v = (row < NN && e < 80) ? adp[((size_t)t*NN + row)*80 + e] : 0.f;
        As[r*SAD + e] = f2b(v);
    }
    __syncthreads();
    short8v af[3];
    #pragma unroll
    for (int s = 0; s < 3; ++s)
        af[s] = *(const short8v*)(&As[(16*w + n16)*SAD + s*32 + quad*8]);

    float4v onum[7];
    #pragma unroll
    for (int dt = 0; dt < 7; ++dt) { float4v z = {0.f,0.f,0.f,0.f}; onum[dt] = z; }
    float rs[4] = {0.f,0.f,0.f,0.f};

    bf16* Bt = U;
    bf16* Ht = U;

    for (int c0 = 0; c0 < NN; c0 += 64) {
        int cw = min(64, NN - c0);
        // stage Bt: cols of S as rows (adp[t][c0+r][e])
        for (int idx = tid; idx < 64*96; idx += 256) {
            int r = idx / 96, e = idx - r*96;
            float v = (r < cw && e < 80) ? adp[((size_t)t*NN + c0 + r)*80 + e] : 0.f;
            Bt[r*SAD + e] = f2b(v);
        }
        __syncthreads();
        float4v sc[4];
        #pragma unroll
        for (int ct = 0; ct < 4; ++ct) { float4v z = {0.f,0.f,0.f,0.f}; sc[ct] = z; }
        #pragma unroll
        for (int ct = 0; ct < 4; ++ct) {
            #pragma unroll
            for (int s = 0; s < 3; ++s) {
                short8v bfr = *(const short8v*)(&Bt[(ct*16 + n16)*SAD + s*32 + quad*8]);
                sc[ct] = __builtin_amdgcn_mfma_f32_16x16x32_bf16(af[s], bfr, sc[ct], 0, 0, 0);
            }
        }
        __syncthreads();   // all waves done reading Bt before Ht overwrites U
        // exp + mask OOB cols + write P (A-layout round-trip) + rowsum
        #pragma unroll
        for (int ct = 0; ct < 4; ++ct) {
            bool colok = (c0 + ct*16 + n16) < NN;
            #pragma unroll
            for (int reg = 0; reg < 4; ++reg) {
                float e = colok ? __expf(fmaxf(sc[ct][reg], 0.f)) : 0.f;
                rs[reg] += e;
                P[(16*w + quad*4 + reg)*SP + ct*16 + n16] = f2b(e);
            }
        }
        // stage Ht[d][cL] = h[t][c0+cL][d]  (112 x 64, zero-padded)
        for (int idx = tid; idx < 112*64; idx += 256) {
            int d = idx % 112, cL = idx / 112;
            bf16 v = f2b(0.f);
            if (d < 104 && cL < cw) v = h[((size_t)t*NN + c0 + cL)*104 + d];
            Ht[d*SP + cL] = v;
        }
        __syncthreads();
        short8v pf[2];
        #pragma unroll
        for (int s = 0; s < 2; ++s)
            pf[s] = *(const short8v*)(&P[(16*w + n16)*SP + s*32 + quad*8]);
        #pragma unroll
        for (int dt = 0; dt < 7; ++dt) {
            #pragma unroll
            for (int s = 0; s < 2; ++s) {
                short8v bfr = *(const short8v*)(&Ht[(dt*16 + n16)*SP + s*32 + quad*8]);
                onum[dt] = __builtin_amdgcn_mfma_f32_16x16x32_bf16(pf[s], bfr, onum[dt], 0, 0, 0);
            }
        }
        __syncthreads();   // before next chunk overwrites Bt/Ht/P
    }
    #pragma unroll
    for (int reg = 0; reg < 4; ++reg) {
        float v = rs[reg];
        v += __shfl_xor(v, 1, 64);
        v += __shfl_xor(v, 2, 64);
        v += __shfl_xor(v, 4, 64);
        v += __shfl_xor(v, 8, 64);
        rs[reg] = v;
    }
    #pragma unroll
    for (int reg = 0; reg < 4; ++reg) {
        int row = r0 + 16*w + quad*4 + reg;
        if (row < NN) {
            float inv = 1.f / rs[reg];
            #pragma unroll
            for (int dt = 0; dt < 7; ++dt) {
                int d = dt*16 + n16;
                if (d < 104)
                    z1[((size_t)t*NN + row)*104 + d] = f2b(onum[dt][reg] * inv);
            }
        }
    }
}

// ---------------- linear-attention KV summaries ----------------
__global__ void __launch_bounds__(256) kvs_kernel(
    const bf16* __restrict__ qkv, float* __restrict__ kvs, float* __restrict__ ksum,
    int L, long long strideB, long long strideL)
{
    int b = blockIdx.x, head = blockIdx.y;
    long long base = (long long)b*strideB + 104 + head*HD;   // k; v at +104
    __shared__ float kc[32][27], vc[32][27], inv[32];
    int tid = threadIdx.x;
    float acc[3] = {0.f,0.f,0.f};
    float ks = 0.f;
    for (int l0 = 0; l0 < L; l0 += 32) {
        int lw = min(32, L - l0);
        __syncthreads();
        for (int idx = tid; idx < lw*HD; idx += 256) {
            int ll = idx / HD, m = idx - ll*HD;
            long long a = base + (long long)(l0 + ll)*strideL + m;
            kc[ll][m] = b2f(qkv[a]);
            vc[ll][m] = b2f(qkv[a + 104]);
        }
        __syncthreads();
        if (tid < lw) {
            float ss = 0.f;
            #pragma unroll
            for (int m = 0; m < HD; ++m) { float v = kc[tid][m]; ss += v*v; }
            inv[tid] = 1.f / fmaxf(sqrtf(ss), 1e-12f);
        }
        __syncthreads();
        for (int idx = tid; idx < lw*HD; idx += 256) {
            int ll = idx / HD, m = idx - ll*HD;
            kc[ll][m] *= inv[ll];
        }
        __syncthreads();
        #pragma unroll
        for (int jj = 0; jj < 3; ++jj) {
            int p = tid + jj*256;
            if (p < HD*HD) {
                int m = p / HD, d = p - m*HD;
                float a = 0.f;
                for (int ll = 0; ll < lw; ++ll) a += kc[ll][m] * vc[ll][d];
                acc[jj] += a;
            }
        }
        if (tid < HD) {
            float a = 0.f;
            for (int ll = 0; ll < lw; ++ll) a += kc[ll][tid];
            ks += a;
        }
    }
    long long ob = ((long long)b*NH + head) * (HD*HD);
    #pragma unroll
    for (int jj = 0; jj < 3; ++jj) {
        int p = tid + jj*256;
        if (p < HD*HD) kvs[ob + p] = acc[jj];
    }
    if (tid < HD) ksum[((long long)b*NH + head)*HD + tid] = ks;
}

// ---------------- apply linear attention; concat into qkv[row][0:208] ----------------
__global__ void __launch_bounds__(256) attn_apply(
    bf16* __restrict__ qkv,
    const float* __restrict__ kvs_s, const float* __restrict__ ksum_s,
    const float* __restrict__ kvs_t, const float* __restrict__ ksum_t)
{
    int bid = blockIdx.x;
    int t = bid / NN, n = bid - t*NN;
    int tid = threadIdx.x;
    __shared__ float qn[104], vrow[104], invq[NH], den[2*NH];
    size_t rb = (size_t)bid * 312;
    if (tid < 104) { qn[tid] = b2f(qkv[rb + tid]); vrow[tid] = b2f(qkv[rb + 208 + tid]); }
    __syncthreads();
    if (tid < NH) {
        float ss = 0.f;
        #pragma unroll
        for (int m = 0; m < HD; ++m) { float v = qn[tid*HD + m]; ss += v*v; }
        invq[tid] = 1.f / fmaxf(sqrtf(ss), 1e-12f);
    }
    __syncthreads();
    if (tid < 104) qn[tid] *= invq[tid / HD];
    __syncthreads();
    if (tid < 2*NH) {
        int hh = tid & 3;
        const float* ks = (tid < NH) ? &ksum_s[((size_t)t*NH + hh)*HD]
                                     : &ksum_t[((size_t)n*NH + hh)*HD];
        float s = 0.f;
        #pragma unroll
        for (int m = 0; m < HD; ++m) s += qn[hh*HD + m] * ks[m];
        den[tid] = s + ((tid < NH) ? (float)NN : (float)TT);
    }
    __syncthreads();
    if (tid < 208) {
        int sp = (tid < 104);
        int d  = sp ? tid : tid - 104;
        int hh = d / HD, dd = d - hh*HD;
        const float* kv = sp ? &kvs_s[((size_t)t*NH + hh)*(HD*HD) + dd]
                             : &kvs_t[((size_t)n*NH + hh)*(HD*HD) + dd];
        float num = 0.f;
        #pragma unroll
        for (int m = 0; m < HD; ++m) num += qn[hh*HD + m] * kv[m*HD];
        float Lf = sp ? (float)NN : (float)TT;
        num += Lf * vrow[d];
        qkv[rb + tid] = f2b(num / den[sp ? hh : NH + hh]);
    }
}

__device__ __forceinline__ float bsum128(float v, float* red, int tid) {
    #pragma unroll
    for (int off = 32; off > 0; off >>= 1) v += __shfl_down(v, off, 64);
    __syncthreads();
    if ((tid & 63) == 0) red[tid >> 6] = v;
    __syncthreads();
    return red[0] + red[1];
}

__global__ void __launch_bounds__(128) ln1_kernel(
    bf16* __restrict__ h, const bf16* __restrict__ att0, const bf16* __restrict__ att1,
    const bf16* __restrict__ p0, const bf16* __restrict__ p1,
    const float* __restrict__ gamma, const float* __restrict__ beta)
{
    int tid = threadIdx.x;
    size_t base = (size_t)blockIdx.x * 104;
    __shared__ float red[2];
    float x = 0.f;
    if (tid < 104) {
        float hv = b2f(h[base + tid]);
        x = 2.f * (hv + b2f(att0[base + tid])*b2f(p0[base + tid])
                      + 0.01f*b2f(att1[base + tid])*b2f(p1[base + tid]));
    }
    float mean = bsum128(x, red, tid) * (1.f/104.f);
    float dx = (tid < 104) ? (x - mean) : 0.f;
    float var = bsum128(dx*dx, red, tid) * (1.f/104.f);
    if (tid < 104)
        h[base + tid] = f2b(dx * rsqrtf(var + 1e-5f) * gamma[tid] + beta[tid]);
}

__global__ void __launch_bounds__(128) ln2_kernel(
    const bf16* __restrict__ h1, const bf16* __restrict__ m,
    const float* __restrict__ gamma, const float* __restrict__ beta,
    bf16* __restrict__ h2)
{
    int tid = threadIdx.x;
    size_t base = (size_t)blockIdx.x * 104;
    __shared__ float red[2];
    float x = 0.f;
    if (tid < 104) x = b2f(h1[base + tid]) + b2f(m[base + tid]);
    float mean = bsum128(x, red, tid) * (1.f/104.f);
    float dx = (tid < 104) ? (x - mean) : 0.f;
    float var = bsum128(dx*dx, red, tid) * (1.f/104.f);
    if (tid < 104)
        h2[base + tid] = f2b(dx * rsqrtf(var + 1e-5f) * gamma[tid] + beta[tid]);
}

__global__ void __launch_bounds__(256) y_init_kernel(float* __restrict__ y, const float* __restrict__ ep_b) {
    int i = blockIdx.x*256 + threadIdx.x;
    if (i < NN*104) y[i] = ep_b[i % 104];
}

__global__ void __launch_bounds__(256) enc_kernel(
    float* __restrict__ y, const float* __restrict__ w1, const float* __restrict__ b1,
    const float* __restrict__ w2, const float* __restrict__ b2)
{
    int n = blockIdx.x;
    int tid = threadIdx.x;
    __shared__ float yr[104], hid[208];
    if (tid < 104) yr[tid] = y[(size_t)n*104 + tid];
    __syncthreads();
    if (tid < 208) {
        float s = b1[tid];
        for (int k = 0; k < 104; ++k) s += yr[k] * w1[(size_t)k*208 + tid];
        hid[tid] = fmaxf(s, 0.f);
    }
    __syncthreads();
    if (tid < 104) {
        float s = b2[tid];
        for (int k = 0; k < 208; ++k) s += hid[k] * w2[(size_t)k*104 + tid];
        y[(size_t)n*104 + tid] = yr[tid] + s;
    }
}

__global__ void __launch_bounds__(256) out_kernel(
    const float* __restrict__ y, const float* __restrict__ out_w,
    const float* __restrict__ out_b, float* __restrict__ out)
{
    int n = blockIdx.x;
    int tid = threadIdx.x;
    __shared__ float yr[104];
    if (tid < 104) yr[tid] = y[(size_t)n*104 + tid];
    __syncthreads();
    for (int t = tid; t < TT; t += 256) {
        float s = out_b[t];
        for (int d = 0; d < 104; ++d) s += yr[d] * out_w[(size_t)d*TT + t];
        out[(size_t)n*TT + t] = s;
    }
}

// ---------------- launch ----------------
extern "C" void kernel_launch(void* const* d_in, const int* in_sizes, int n_in,
                              void* d_out, int out_size, void* d_ws, size_t ws_size,
                              hipStream_t stream) {
    if (ws_size < WS_NEEDED) return;   // readable failure instead of page fault

    const float* x      = (const float*)d_in[0];
    const float* W_in   = (const float*)d_in[1];
    const float* b_in   = (const float*)d_in[2];
    const float* adp    = (const float*)d_in[3];
    const float* W_tp   = (const float*)d_in[4];
    const float* b_tp   = (const float*)d_in[5];
    const float* qkv_w  = (const float*)d_in[6];
    const float* op_w   = (const float*)d_in[7];
    const float* op_b   = (const float*)d_in[8];
    const float* pw_w   = (const float*)d_in[9];
    const float* pw_b   = (const float*)d_in[10];
    const float* fc_w1  = (const float*)d_in[11];
    const float* fc_b1  = (const float*)d_in[12];
    const float* fc_w2  = (const float*)d_in[13];
    const float* fc_b2  = (const float*)d_in[14];
    const float* ln1_g  = (const float*)d_in[15];
    const float* ln1_b  = (const float*)d_in[16];
    const float* ln2_g  = (const float*)d_in[17];
    const float* ln2_b  = (const float*)d_in[18];
    const float* ep_w   = (const float*)d_in[19];
    const float* ep_b   = (const float*)d_in[20];
    const float* enc_w1 = (const float*)d_in[21];
    const float* enc_b1 = (const float*)d_in[22];
    const float* enc_w2 = (const float*)d_in[23];
    const float* enc_b2 = (const float*)d_in[24];
    const float* out_w  = (const float*)d_in[25];
    const float* out_b  = (const float*)d_in[26];

    bf16* B0 = (bf16*)d_ws;
    bf16* B1 = B0 + NB0;
    bf16* B2 = B1 + NB1;
    bf16* B3 = B2 + NB2;
    float* kvs_s  = (float*)(B3 + NB3);
    float* ksum_s = kvs_s + NKVS_S;
    float* kvs_t  = ksum_s + NKSUM_S;
    float* ksum_t = kvs_t + NKVS_T;
    float* ybuf   = ksum_t + NKSUM_T;
    bf16* wtp   = (bf16*)(ybuf + NY);
    bf16* wqkv0 = wtp + NW_TP;
    bf16* wqkv1 = wqkv0 + NW_QKV;
    bf16* wop0  = wqkv1 + NW_QKV;
    bf16* wop1  = wop0 + NW_OP;
    bf16* wpw0  = wop1 + NW_OP;
    bf16* wpw1  = wpw0 + NW_PW;
    bf16* wfc1  = wpw1 + NW_PW;
    bf16* wfc2  = wfc1 + NW_FC1;
    bf16* wept  = wfc2 + NW_FC2;

    // 0. weight prep (tiny)
    prep_w<<<CEILDIV(104*128,256), 256, 0, stream>>>(W_tp, wtp, 104, 104, 128);
    prep_w<<<CEILDIV(312*128,256), 256, 0, stream>>>(qkv_w, wqkv0, 104, 312, 128);
    prep_w<<<CEILDIV(312*128,256), 256, 0, stream>>>(qkv_w + 104*312, wqkv1, 104, 312, 128);
    prep_w<<<CEILDIV(104*224,256), 256, 0, stream>>>(op_w, wop0, 208, 104, 224);
    prep_w<<<CEILDIV(104*224,256), 256, 0, stream>>>(op_w + 208*104, wop1, 208, 104, 224);
    prep_w<<<CEILDIV(104*128,256), 256, 0, stream>>>(pw_w, wpw0, 104, 104, 128);
    prep_w<<<CEILDIV(104*128,256), 256, 0, stream>>>(pw_w + 104*104, wpw1, 104, 104, 128);
    prep_w<<<CEILDIV(208*128,256), 256, 0, stream>>>(fc_w1, wfc1, 104, 208, 128);
    prep_w<<<CEILDIV(104*224,256), 256, 0, stream>>>(fc_w2, wfc2, 208, 104, 224);
    prep_w<<<CEILDIV(104*37960,256), 256, 0, stream>>>(ep_w, wept, 37960, 104, 37960);

    const int GX = CEILDIV(TN, 64);     // 2282
    dim3 g2(GX, 2), g4(GX, 4), g5(GX, 5);

    // 1. hcat -> B2
    hcat_kernel<<<TN, 128, 0, stream>>>(x, W_in, b_in, adp, B2);
    // 2. h = hcat @ W_tp + b_tp -> B0
    gemm_mf<128><<<g2, 256, 0, stream>>>(B2, 104, 104, wtp, b_tp, B0, TN, 104, 0);
    // 3. z1 -> B1
    z1_mf<<<dim3(7, TT), 256, 0, stream>>>(adp, B0, B1);
    // 4. attention 0 on h
    gemm_mf<128><<<g5, 256, 0, stream>>>(B0, 104, 104, wqkv0, nullptr, B2, TN, 312, 0);
    kvs_kernel<<<dim3(TT, NH), 256, 0, stream>>>(B2, kvs_s, ksum_s, NN, (long long)NN*312, 312);
    kvs_kernel<<<dim3(NN, NH), 256, 0, stream>>>(B2, kvs_t, ksum_t, TT, 312, (long long)NN*312);
    attn_apply<<<TN, 256, 0, stream>>>(B2, kvs_s, ksum_s, kvs_t, ksum_t);
    gemm_mf<224><<<g2, 256, 0, stream>>>(B2, 312, 208, wop0, op_b, B3, TN, 104, 0);      // att0 -> B3
    // 5. attention 1 on z1
    gemm_mf<128><<<g5, 256, 0, stream>>>(B1, 104, 104, wqkv1, nullptr, B2, TN, 312, 0);
    kvs_kernel<<<dim3(TT, NH), 256, 0, stream>>>(B2, kvs_s, ksum_s, NN, (long long)NN*312, 312);
    kvs_kernel<<<dim3(NN, NH), 256, 0, stream>>>(B2, kvs_t, ksum_t, TT, 312, (long long)NN*312);
    attn_apply<<<TN, 256, 0, stream>>>(B2, kvs_s, ksum_s, kvs_t, ksum_t);
    gemm_mf<224><<<g2, 256, 0, stream>>>(B2, 312, 208, wop1, op_b + 104, B1, TN, 104, 0); // att1 -> B1
    // 6. pointwise gates -> B2
    gemm_mf<128><<<g2, 256, 0, stream>>>(B0, 104, 104, wpw0, pw_b, B2, TN, 104, 0);
    gemm_mf<128><<<g2, 256, 0, stream>>>(B3, 104, 104, wpw1, pw_b + 104, B2 + (size_t)TN*104, TN, 104, 0);
    // 7. LN1 in-place (B0 -> h1)
    ln1_kernel<<<TN, 128, 0, stream>>>(B0, B3, B1, B2, B2 + (size_t)TN*104, ln1_g, ln1_b);
    // 8. MLP + LN2
    gemm_mf<128><<<g4, 256, 0, stream>>>(B0, 104, 104, wfc1, fc_b1, B2, TN, 208, 1);
    gemm_mf<224><<<g2, 256, 0, stream>>>(B2, 208, 208, wfc2, fc_b2, B1, TN, 104, 0);
    ln2_kernel<<<TN, 128, 0, stream>>>(B0, B1, ln2_g, ln2_b, B3);                        // h2 -> B3
    // 9. encoder_proj: MFMA split-K over t-chunks, atomic accumulate onto bias
    y_init_kernel<<<CEILDIV(NN*104,256), 256, 0, stream>>>(ybuf, ep_b);
    ep_mf<<<dim3(CEILDIV(NN,64), 2, CEILDIV(TT,8)), 256, 0, stream>>>(B3, wept, ybuf);
    // 10. residual MLP blocks
    for (int i = 0; i < 3; ++i)
        enc_kernel<<<NN, 256, 0, stream>>>(ybuf, enc_w1 + (size_t)i*104*208, enc_b1 + (size_t)i*208,
                                           enc_w2 + (size_t)i*208*104, enc_b2 + (size_t)i*104);
    // 11. output projection
    out_kernel<<<NN, 256, 0, stream>>>(ybuf, out_w, out_b, (float*)d_out);
}

// Round 6
// 2568.926 us; speedup vs baseline: 2.2741x; 1.1077x over previous
//
#include <hip/hip_runtime.h>
#include <hip/hip_bf16.h>
#include <cstddef>

// ---------------- problem constants ----------------
#define TT   365
#define NN   400
#define TN   (TT*NN)            // 146000
#define HD   26                 // head dim
#define NH   4                  // heads

#define CEILDIV(a,b) (((a)+(b)-1)/(b))

typedef __hip_bfloat16 bf16;
typedef short short8v __attribute__((ext_vector_type(8)));
typedef float float4v __attribute__((ext_vector_type(4)));
__device__ __forceinline__ float b2f(bf16 v){ return __bfloat162float(v); }
__device__ __forceinline__ bf16  f2b(float v){ return __float2bfloat16(v); }

// ---------------- workspace layout ----------------
static constexpr size_t NB0 = (size_t)TN*104;   // h / h1
static constexpr size_t NB1 = (size_t)TN*104;   // z1 -> att1 -> m
static constexpr size_t NB2 = (size_t)TN*312;   // hcat -> [adp_bf|hT] -> qkv+concat -> p0|p1 -> hidden
static constexpr size_t NB3 = (size_t)TN*104;   // att0 -> h2
static constexpr size_t NBF = NB0+NB1+NB2+NB3;
static constexpr size_t NKVS_S  = (size_t)TT*NH*HD*HD;
static constexpr size_t NKSUM_S = (size_t)TT*NH*HD;
static constexpr size_t NKVS_T  = (size_t)NN*NH*HD*HD;
static constexpr size_t NKSUM_T = (size_t)NN*NH*HD;
static constexpr size_t NY      = (size_t)NN*104;
static constexpr size_t NAUX    = NKVS_S+NKSUM_S+NKVS_T+NKSUM_T+NY;
// transposed bf16 weights (Wt[n][kp], zero-padded k)
static constexpr size_t NW_TP   = 104*128;
static constexpr size_t NW_QKV  = 312*128;   // x2
static constexpr size_t NW_OP   = 104*224;   // x2
static constexpr size_t NW_PW   = 104*128;   // x2
static constexpr size_t NW_FC1  = 208*128;
static constexpr size_t NW_FC2  = 104*224;
static constexpr size_t NW_EPT  = (size_t)104*37960;   // ep_w transposed, no pad
static constexpr size_t NWT     = NW_TP + 2*NW_QKV + 2*NW_OP + 2*NW_PW + NW_FC1 + NW_FC2 + NW_EPT;
static constexpr size_t WS_NEEDED = NBF*2 + NAUX*4 + NWT*2;
// z1 scratch lives inside B2 (dead between step 2 and step 4):
static constexpr size_t NADP_ROWS = (size_t)TN + 64;           // padded rows (last tile OOB-safe)
static constexpr size_t NADP = NADP_ROWS*96;                   // adp in bf16, width padded to 96
static constexpr size_t NHT  = ((size_t)TT*104 + 8)*448;       // h transposed, width padded to 448, +8 pad rows
static_assert(NADP + NHT <= NB2, "z1 scratch must fit in B2");

// ---------------- weight prep: Wt[n*KP+k] = bf16(W[k*Nc+n]), zero pad k>=K ----------------
__global__ void __launch_bounds__(256) prep_w(
    const float* __restrict__ W, bf16* __restrict__ Wt, int K, int Nc, int KP)
{
    int idx = blockIdx.x*256 + threadIdx.x;
    if (idx >= Nc*KP) return;
    int n = idx / KP, k = idx - n*KP;
    Wt[idx] = (k < K) ? f2b(W[(size_t)k*Nc + n]) : f2b(0.f);
}

// adp_bf[row][e] = bf16(adp[row][e]) for e<80 else 0; rows >= TN are zero.
__global__ void __launch_bounds__(256) prep_adp(
    const float* __restrict__ adp, bf16* __restrict__ out)
{
    size_t i = (size_t)blockIdx.x*256 + threadIdx.x;
    if (i >= NADP) return;
    size_t row = i / 96; int e = (int)(i - row*96);
    float v = (row < TN && e < 80) ? adp[row*80 + e] : 0.f;
    out[i] = f2b(v);
}

// hT[t][d][n] = h[t][n][d], n padded to 448 with zeros (LDS transpose, coalesced both ways)
__global__ void __launch_bounds__(256) ht_kernel(
    const bf16* __restrict__ h, bf16* __restrict__ hT)
{
    __shared__ bf16 As[64*106];
    int t = blockIdx.y, n0 = blockIdx.x*64;
    int tid = threadIdx.x;
    for (int idx = tid; idx < 64*52; idx += 256) {
        int r = idx / 52, k = idx - r*52;
        int n = n0 + r;
        uint v = 0;
        if (n < NN) v = *(const uint*)(h + ((size_t)t*NN + n)*104 + k*2);
        *(uint*)(&As[r*106 + k*2]) = v;
    }
    __syncthreads();
    for (int idx = tid; idx < 104*32; idx += 256) {
        int d = idx >> 5, np = idx & 31;
        int n = np*2;
        ushort lo = *(ushort*)&As[n*106 + d];
        ushort hi = *(ushort*)&As[(n+1)*106 + d];
        uint v = ((uint)hi << 16) | lo;
        *(uint*)(hT + ((size_t)t*104 + d)*448 + n0 + n) = v;
    }
}

// ---------------- hcat ----------------
__global__ void __launch_bounds__(128) hcat_kernel(
    const float* __restrict__ x, const float* __restrict__ W_in,
    const float* __restrict__ b_in, const float* __restrict__ adp,
    bf16* __restrict__ hcat)
{
    int bid = blockIdx.x;            // t*400 + n
    int t = bid / NN, n = bid - t*NN;
    int tid = threadIdx.x;
    if (tid < 24) {
        float s = b_in[tid];
        size_t xb = ((size_t)n*TT + t)*3;
        #pragma unroll
        for (int i = 0; i < 3; ++i) s += x[xb + i] * W_in[i*24 + tid];
        hcat[(size_t)bid*104 + tid] = f2b(s);
    } else if (tid < 104) {
        hcat[(size_t)bid*104 + tid] = f2b(adp[(size_t)bid*80 + (tid - 24)]);
    }
}

// ---------------- MFMA GEMM: C[M,Nc] = A[M,K](lda,bf16) @ W + bias ----------------
template<int KP>
__global__ void __launch_bounds__(256) gemm_mf(
    const bf16* __restrict__ A, int lda, int K,
    const bf16* __restrict__ Wt, const float* __restrict__ bias,
    bf16* __restrict__ C, int M, int Nc, int relu)
{
    constexpr int STR = KP + 8;          // bf16 elems; +8 keeps b128 reads 2-way (free)
    __shared__ bf16 As[64*STR];
    __shared__ bf16 Ws[64*STR];
    int m0 = blockIdx.x * 64;
    int c0 = blockIdx.y * 64;
    int tid = threadIdx.x;
    const int KW = KP/2;                 // uints per row
    for (int idx = tid; idx < 64*KW; idx += 256) {
        int r = idx / KW, kw = idx - r*KW;
        int m = m0 + r, k = kw*2;
        uint v = 0;
        if (m < M && k < K) v = *(const uint*)(A + (size_t)m*lda + k);
        *(uint*)(&As[r*STR + k]) = v;
    }
    for (int idx = tid; idx < 64*KW; idx += 256) {
        int r = idx / KW, kw = idx - r*KW;
        int n = c0 + r, k = kw*2;
        uint v = 0;
        if (n < Nc) v = *(const uint*)(Wt + (size_t)n*KP + k);
        *(uint*)(&Ws[r*STR + k]) = v;
    }
    __syncthreads();

    int lane = tid & 63, w = tid >> 6;
    int n16 = lane & 15, quad = lane >> 4;
    constexpr int KS = KP/32;
    short8v af[KS];
    #pragma unroll
    for (int s = 0; s < KS; ++s)
        af[s] = *(const short8v*)(&As[(16*w + n16)*STR + s*32 + quad*8]);
    float4v acc[4];
    #pragma unroll
    for (int ct = 0; ct < 4; ++ct) { float4v z = {0.f,0.f,0.f,0.f}; acc[ct] = z; }
    #pragma unroll
    for (int ct = 0; ct < 4; ++ct) {
        #pragma unroll
        for (int s = 0; s < KS; ++s) {
            short8v bfr = *(const short8v*)(&Ws[(ct*16 + n16)*STR + s*32 + quad*8]);
            acc[ct] = __builtin_amdgcn_mfma_f32_16x16x32_bf16(af[s], bfr, acc[ct], 0, 0, 0);
        }
    }
    #pragma unroll
    for (int ct = 0; ct < 4; ++ct) {
        int c = c0 + ct*16 + n16;
        if (c < Nc) {
            float b = bias ? bias[c] : 0.f;
            #pragma unroll
            for (int reg = 0; reg < 4; ++reg) {
                int m = m0 + 16*w + quad*4 + reg;
                if (m < M) {
                    float v = acc[ct][reg] + b;
                    if (relu) v = fmaxf(v, 0.f);
                    C[(size_t)m*Nc + c] = f2b(v);
                }
            }
        }
    }
}

// ---------------- MFMA encoder_proj: y[400,104] += sum_t h2[t] @ ep_w[t] ----------------
__global__ void __launch_bounds__(256) ep_mf(
    const bf16* __restrict__ h2, const bf16* __restrict__ wt, float* __restrict__ y)
{
    constexpr int STR = 136;             // 128 padded K + 8
    __shared__ bf16 As[64*STR];
    __shared__ bf16 Ws[64*STR];
    int m0 = blockIdx.x * 64;
    int c0 = blockIdx.y * 64;
    int t0 = blockIdx.z * 8;
    int t1 = min(TT, t0 + 8);
    int tid = threadIdx.x;
    int lane = tid & 63, w = tid >> 6, n16 = lane & 15, quad = lane >> 4;

    float4v acc[4];
    #pragma unroll
    for (int ct = 0; ct < 4; ++ct) { float4v z = {0.f,0.f,0.f,0.f}; acc[ct] = z; }

    for (int t = t0; t < t1; ++t) {
        for (int idx = tid; idx < 64*64; idx += 256) {     // 64 rows x 64 uints
            int r = idx >> 6, k = (idx & 63)*2;
            int m = m0 + r;
            uint va = 0;
            if (m < NN && k < 104) va = *(const uint*)(h2 + ((size_t)t*NN + m)*104 + k);
            *(uint*)(&As[r*STR + k]) = va;
            int c = c0 + r;
            uint vw = 0;
            if (c < 104 && k < 104) vw = *(const uint*)(wt + (size_t)c*37960 + t*104 + k);
            *(uint*)(&Ws[r*STR + k]) = vw;
        }
        __syncthreads();
        short8v af[4];
        #pragma unroll
        for (int s = 0; s < 4; ++s)
            af[s] = *(const short8v*)(&As[(16*w + n16)*STR + s*32 + quad*8]);
        #pragma unroll
        for (int ct = 0; ct < 4; ++ct) {
            #pragma unroll
            for (int s = 0; s < 4; ++s) {
                short8v bfr = *(const short8v*)(&Ws[(ct*16 + n16)*STR + s*32 + quad*8]);
                acc[ct] = __builtin_amdgcn_mfma_f32_16x16x32_bf16(af[s], bfr, acc[ct], 0, 0, 0);
            }
        }
        __syncthreads();
    }
    #pragma unroll
    for (int ct = 0; ct < 4; ++ct) {
        int c = c0 + ct*16 + n16;
        if (c < 104) {
            #pragma unroll
            for (int reg = 0; reg < 4; ++reg) {
                int m = m0 + 16*w + quad*4 + reg;
                if (m < NN) atomicAdd(&y[(size_t)m*104 + c], acc[ct][reg]);
            }
        }
    }
}

// ---------------- MFMA z1 (v2): z1[t] = softmax(relu(adp adp^T)) @ h[t] ----------------
// Inputs pre-staged as bf16: adp_bf[row][96] (zero-padded), hT[t][104][448] (zero-padded cols).
// relu scores are small (>=0, <~0.5) so exp without max-subtraction is exact.
// P is wave-private (wave w writes+reads only rows 16w..16w+15) -> only 2 barriers/chunk.
__global__ void __launch_bounds__(256) z1_mf(
    const bf16* __restrict__ adp_bf, const bf16* __restrict__ hT, bf16* __restrict__ z1)
{
    constexpr int SA = 104;   // 96 + 8
    constexpr int SP = 72;    // 64 + 8
    __shared__ bf16 As[64*SA];
    __shared__ bf16 Bt[64*SA];
    __shared__ bf16 Ht[112*SP];
    __shared__ bf16 P[64*SP];
    int t = blockIdx.y;
    int r0 = blockIdx.x * 64;
    int tid = threadIdx.x;
    int lane = tid & 63, w = tid >> 6, n16 = lane & 15, quad = lane >> 4;

    {   // stage As: 64 rows x 96 bf16 = 64 x 12 uint4  (uint4 = 8 bf16!)
        const uint4* src = (const uint4*)(adp_bf + ((size_t)t*NN + r0)*96);
        for (int idx = tid; idx < 768; idx += 256) {
            int r = idx / 12, q = idx - r*12;
            *(uint4*)(&As[r*SA + q*8]) = src[idx];
        }
    }
    __syncthreads();
    short8v af[3];
    #pragma unroll
    for (int s = 0; s < 3; ++s)
        af[s] = *(const short8v*)(&As[(16*w + n16)*SA + s*32 + quad*8]);

    float4v onum[7];
    #pragma unroll
    for (int dt = 0; dt < 7; ++dt) { float4v z = {0.f,0.f,0.f,0.f}; onum[dt] = z; }
    float rs[4] = {0.f,0.f,0.f,0.f};

    for (int c0 = 0; c0 < NN; c0 += 64) {
        {   // stage Bt: 64 rows x 12 uint4 (padded buffer -> branch-free)
            const uint4* srcB = (const uint4*)(adp_bf + ((size_t)t*NN + c0)*96);
            for (int idx = tid; idx < 768; idx += 256) {
                int r = idx / 12, q = idx - r*12;
                *(uint4*)(&Bt[r*SA + q*8]) = srcB[idx];
            }
        }
        {   // stage Ht: 112 rows x 8 uint4 (64 cols) from hT (rows >=104 garbage, masked later)
            const bf16* hb = hT + (size_t)t*104*448 + c0;
            for (int idx = tid; idx < 896; idx += 256) {
                int d = idx >> 3, q = idx & 7;
                *(uint4*)(&Ht[d*SP + q*8]) = *(const uint4*)(hb + (size_t)d*448 + q*8);
            }
        }
        __syncthreads();
        float4v sc[4];
        #pragma unroll
        for (int ct = 0; ct < 4; ++ct) { float4v z = {0.f,0.f,0.f,0.f}; sc[ct] = z; }
        #pragma unroll
        for (int ct = 0; ct < 4; ++ct) {
            #pragma unroll
            for (int s = 0; s < 3; ++s) {
                short8v bfr = *(const short8v*)(&Bt[(ct*16 + n16)*SA + s*32 + quad*8]);
                sc[ct] = __builtin_amdgcn_mfma_f32_16x16x32_bf16(af[s], bfr, sc[ct], 0, 0, 0);
            }
        }
        // exp + mask OOB cols + write P (own-wave rows) + rowsum
        #pragma unroll
        for (int ct = 0; ct < 4; ++ct) {
            bool colok = (c0 + ct*16 + n16) < NN;
            #pragma unroll
            for (int reg = 0; reg < 4; ++reg) {
                float e = colok ? __expf(fmaxf(sc[ct][reg], 0.f)) : 0.f;
                rs[reg] += e;
                P[(16*w + quad*4 + reg)*SP + ct*16 + n16] = f2b(e);
            }
        }
        short8v pf[2];
        #pragma unroll
        for (int s = 0; s < 2; ++s)
            pf[s] = *(const short8v*)(&P[(16*w + n16)*SP + s*32 + quad*8]);
        #pragma unroll
        for (int dt = 0; dt < 7; ++dt) {
            #pragma unroll
            for (int s = 0; s < 2; ++s) {
                short8v bfr = *(const short8v*)(&Ht[(dt*16 + n16)*SP + s*32 + quad*8]);
                onum[dt] = __builtin_amdgcn_mfma_f32_16x16x32_bf16(pf[s], bfr, onum[dt], 0, 0, 0);
            }
        }
        __syncthreads();
    }
    #pragma unroll
    for (int reg = 0; reg < 4; ++reg) {
        float v = rs[reg];
        v += __shfl_xor(v, 1, 64);
        v += __shfl_xor(v, 2, 64);
        v += __shfl_xor(v, 4, 64);
        v += __shfl_xor(v, 8, 64);
        rs[reg] = v;
    }
    #pragma unroll
    for (int reg = 0; reg < 4; ++reg) {
        int row = r0 + 16*w + quad*4 + reg;
        if (row < NN) {
            float inv = 1.f / rs[reg];
            #pragma unroll
            for (int dt = 0; dt < 7; ++dt) {
                int d = dt*16 + n16;
                if (d < 104)
                    z1[((size_t)t*NN + row)*104 + d] = f2b(onum[dt][reg] * inv);
            }
        }
    }
}

// ---------------- linear-attention KV summaries ----------------
__global__ void __launch_bounds__(256) kvs_kernel(
    const bf16* __restrict__ qkv, float* __restrict__ kvs, float* __restrict__ ksum,
    int L, long long strideB, long long strideL)
{
    int b = blockIdx.x, head = blockIdx.y;
    long long base = (long long)b*strideB + 104 + head*HD;   // k; v at +104
    __shared__ float kc[32][27], vc[32][27], inv[32];
    int tid = threadIdx.x;
    float acc[3] = {0.f,0.f,0.f};
    float ks = 0.f;
    for (int l0 = 0; l0 < L; l0 += 32) {
        int lw = min(32, L - l0);
        __syncthreads();
        for (int idx = tid; idx < lw*HD; idx += 256) {
            int ll = idx / HD, m = idx - ll*HD;
            long long a = base + (long long)(l0 + ll)*strideL + m;
            kc[ll][m] = b2f(qkv[a]);
            vc[ll][m] = b2f(qkv[a + 104]);
        }
        __syncthreads();
        if (tid < lw) {
            float ss = 0.f;
            #pragma unroll
            for (int m = 0; m < HD; ++m) { float v = kc[tid][m]; ss += v*v; }
            inv[tid] = 1.f / fmaxf(sqrtf(ss), 1e-12f);
        }
        __syncthreads();
        for (int idx = tid; idx < lw*HD; idx += 256) {
            int ll = idx / HD, m = idx - ll*HD;
            kc[ll][m] *= inv[ll];
        }
        __syncthreads();
        #pragma unroll
        for (int jj = 0; jj < 3; ++jj) {
            int p = tid + jj*256;
            if (p < HD*HD) {
                int m = p / HD, d = p - m*HD;
                float a = 0.f;
                for (int ll = 0; ll < lw; ++ll) a += kc[ll][m] * vc[ll][d];
                acc[jj] += a;
            }
        }
        if (tid < HD) {
            float a = 0.f;
            for (int ll = 0; ll < lw; ++ll) a += kc[ll][tid];
            ks += a;
        }
    }
    long long ob = ((long long)b*NH + head) * (HD*HD);
    #pragma unroll
    for (int jj = 0; jj < 3; ++jj) {
        int p = tid + jj*256;
        if (p < HD*HD) kvs[ob + p] = acc[jj];
    }
    if (tid < HD) ksum[((long long)b*NH + head)*HD + tid] = ks;
}

// ---------------- apply linear attention; concat into qkv[row][0:208] ----------------
__global__ void __launch_bounds__(256) attn_apply(
    bf16* __restrict__ qkv,
    const float* __restrict__ kvs_s, const float* __restrict__ ksum_s,
    const float* __restrict__ kvs_t, const float* __restrict__ ksum_t)
{
    int bid = blockIdx.x;
    int t = bid / NN, n = bid - t*NN;
    int tid = threadIdx.x;
    __shared__ float qn[104], vrow[104], invq[NH], den[2*NH];
    size_t rb = (size_t)bid * 312;
    if (tid < 104) { qn[tid] = b2f(qkv[rb + tid]); vrow[tid] = b2f(qkv[rb + 208 + tid]); }
    __syncthreads();
    if (tid < NH) {
        float ss = 0.f;
        #pragma unroll
        for (int m = 0; m < HD; ++m) { float v = qn[tid*HD + m]; ss += v*v; }
        invq[tid] = 1.f / fmaxf(sqrtf(ss), 1e-12f);
    }
    __syncthreads();
    if (tid < 104) qn[tid] *= invq[tid / HD];
    __syncthreads();
    if (tid < 2*NH) {
        int hh = tid & 3;
        const float* ks = (tid < NH) ? &ksum_s[((size_t)t*NH + hh)*HD]
                                     : &ksum_t[((size_t)n*NH + hh)*HD];
        float s = 0.f;
        #pragma unroll
        for (int m = 0; m < HD; ++m) s += qn[hh*HD + m] * ks[m];
        den[tid] = s + ((tid < NH) ? (float)NN : (float)TT);
    }
    __syncthreads();
    if (tid < 208) {
        int sp = (tid < 104);
        int d  = sp ? tid : tid - 104;
        int hh = d / HD, dd = d - hh*HD;
        const float* kv = sp ? &kvs_s[((size_t)t*NH + hh)*(HD*HD) + dd]
                             : &kvs_t[((size_t)n*NH + hh)*(HD*HD) + dd];
        float num = 0.f;
        #pragma unroll
        for (int m = 0; m < HD; ++m) num += qn[hh*HD + m] * kv[m*HD];
        float Lf = sp ? (float)NN : (float)TT;
        num += Lf * vrow[d];
        qkv[rb + tid] = f2b(num / den[sp ? hh : NH + hh]);
    }
}

__device__ __forceinline__ float bsum128(float v, float* red, int tid) {
    #pragma unroll
    for (int off = 32; off > 0; off >>= 1) v += __shfl_down(v, off, 64);
    __syncthreads();
    if ((tid & 63) == 0) red[tid >> 6] = v;
    __syncthreads();
    return red[0] + red[1];
}

__global__ void __launch_bounds__(128) ln1_kernel(
    bf16* __restrict__ h, const bf16* __restrict__ att0, const bf16* __restrict__ att1,
    const bf16* __restrict__ p0, const bf16* __restrict__ p1,
    const float* __restrict__ gamma, const float* __restrict__ beta)
{
    int tid = threadIdx.x;
    size_t base = (size_t)blockIdx.x * 104;
    __shared__ float red[2];
    float x = 0.f;
    if (tid < 104) {
        float hv = b2f(h[base + tid]);
        x = 2.f * (hv + b2f(att0[base + tid])*b2f(p0[base + tid])
                      + 0.01f*b2f(att1[base + tid])*b2f(p1[base + tid]));
    }
    float mean = bsum128(x, red, tid) * (1.f/104.f);
    float dx = (tid < 104) ? (x - mean) : 0.f;
    float var = bsum128(dx*dx, red, tid) * (1.f/104.f);
    if (tid < 104)
        h[base + tid] = f2b(dx * rsqrtf(var + 1e-5f) * gamma[tid] + beta[tid]);
}

__global__ void __launch_bounds__(128) ln2_kernel(
    const bf16* __restrict__ h1, const bf16* __restrict__ m,
    const float* __restrict__ gamma, const float* __restrict__ beta,
    bf16* __restrict__ h2)
{
    int tid = threadIdx.x;
    size_t base = (size_t)blockIdx.x * 104;
    __shared__ float red[2];
    float x = 0.f;
    if (tid < 104) x = b2f(h1[base + tid]) + b2f(m[base + tid]);
    float mean = bsum128(x, red, tid) * (1.f/104.f);
    float dx = (tid < 104) ? (x - mean) : 0.f;
    float var = bsum128(dx*dx, red, tid) * (1.f/104.f);
    if (tid < 104)
        h2[base + tid] = f2b(dx * rsqrtf(var + 1e-5f) * gamma[tid] + beta[tid]);
}

__global__ void __launch_bounds__(256) y_init_kernel(float* __restrict__ y, const float* __restrict__ ep_b) {
    int i = blockIdx.x*256 + threadIdx.x;
    if (i < NN*104) y[i] = ep_b[i % 104];
}

__global__ void __launch_bounds__(256) enc_kernel(
    float* __restrict__ y, const float* __restrict__ w1, const float* __restrict__ b1,
    const float* __restrict__ w2, const float* __restrict__ b2)
{
    int n = blockIdx.x;
    int tid = threadIdx.x;
    __shared__ float yr[104], hid[208];
    if (tid < 104) yr[tid] = y[(size_t)n*104 + tid];
    __syncthreads();
    if (tid < 208) {
        float s = b1[tid];
        for (int k = 0; k < 104; ++k) s += yr[k] * w1[(size_t)k*208 + tid];
        hid[tid] = fmaxf(s, 0.f);
    }
    __syncthreads();
    if (tid < 104) {
        float s = b2[tid];
        for (int k = 0; k < 208; ++k) s += hid[k] * w2[(size_t)k*104 + tid];
        y[(size_t)n*104 + tid] = yr[tid] + s;
    }
}

__global__ void __launch_bounds__(256) out_kernel(
    const float* __restrict__ y, const float* __restrict__ out_w,
    const float* __restrict__ out_b, float* __restrict__ out)
{
    int n = blockIdx.x;
    int tid = threadIdx.x;
    __shared__ float yr[104];
    if (tid < 104) yr[tid] = y[(size_t)n*104 + tid];
    __syncthreads();
    for (int t = tid; t < TT; t += 256) {
        float s = out_b[t];
        for (int d = 0; d < 104; ++d) s += yr[d] * out_w[(size_t)d*TT + t];
        out[(size_t)n*TT + t] = s;
    }
}

// ---------------- launch ----------------
extern "C" void kernel_launch(void* const* d_in, const int* in_sizes, int n_in,
                              void* d_out, int out_size, void* d_ws, size_t ws_size,
                              hipStream_t stream) {
    if (ws_size < WS_NEEDED) return;   // readable failure instead of page fault

    const float* x      = (const float*)d_in[0];
    const float* W_in   = (const float*)d_in[1];
    const float* b_in   = (const float*)d_in[2];
    const float* adp    = (const float*)d_in[3];
    const float* W_tp   = (const float*)d_in[4];
    const float* b_tp   = (const float*)d_in[5];
    const float* qkv_w  = (const float*)d_in[6];
    const float* op_w   = (const float*)d_in[7];
    const float* op_b   = (const float*)d_in[8];
    const float* pw_w   = (const float*)d_in[9];
    const float* pw_b   = (const float*)d_in[10];
    const float* fc_w1  = (const float*)d_in[11];
    const float* fc_b1  = (const float*)d_in[12];
    const float* fc_w2  = (const float*)d_in[13];
    const float* fc_b2  = (const float*)d_in[14];
    const float* ln1_g  = (const float*)d_in[15];
    const float* ln1_b  = (const float*)d_in[16];
    const float* ln2_g  = (const float*)d_in[17];
    const float* ln2_b  = (const float*)d_in[18];
    const float* ep_w   = (const float*)d_in[19];
    const float* ep_b   = (const float*)d_in[20];
    const float* enc_w1 = (const float*)d_in[21];
    const float* enc_b1 = (const float*)d_in[22];
    const float* enc_w2 = (const float*)d_in[23];
    const float* enc_b2 = (const float*)d_in[24];
    const float* out_w  = (const float*)d_in[25];
    const float* out_b  = (const float*)d_in[26];

    bf16* B0 = (bf16*)d_ws;
    bf16* B1 = B0 + NB0;
    bf16* B2 = B1 + NB1;
    bf16* B3 = B2 + NB2;
    float* kvs_s  = (float*)(B3 + NB3);
    float* ksum_s = kvs_s + NKVS_S;
    float* kvs_t  = ksum_s + NKSUM_S;
    float* ksum_t = kvs_t + NKVS_T;
    float* ybuf   = ksum_t + NKSUM_T;
    bf16* wtp   = (bf16*)(ybuf + NY);
    bf16* wqkv0 = wtp + NW_TP;
    bf16* wqkv1 = wqkv0 + NW_QKV;
    bf16* wop0  = wqkv1 + NW_QKV;
    bf16* wop1  = wop0 + NW_OP;
    bf16* wpw0  = wop1 + NW_OP;
    bf16* wpw1  = wpw0 + NW_PW;
    bf16* wfc1  = wpw1 + NW_PW;
    bf16* wfc2  = wfc1 + NW_FC1;
    bf16* wept  = wfc2 + NW_FC2;
    // z1 scratch aliases B2 (dead between step 2 and step 4)
    bf16* adp_bf = B2;
    bf16* hTbuf  = B2 + NADP;

    // 0. weight prep (tiny)
    prep_w<<<CEILDIV(104*128,256), 256, 0, stream>>>(W_tp, wtp, 104, 104, 128);
    prep_w<<<CEILDIV(312*128,256), 256, 0, stream>>>(qkv_w, wqkv0, 104, 312, 128);
    prep_w<<<CEILDIV(312*128,256), 256, 0, stream>>>(qkv_w + 104*312, wqkv1, 104, 312, 128);
    prep_w<<<CEILDIV(104*224,256), 256, 0, stream>>>(op_w, wop0, 208, 104, 224);
    prep_w<<<CEILDIV(104*224,256), 256, 0, stream>>>(op_w + 208*104, wop1, 208, 104, 224);
    prep_w<<<CEILDIV(104*128,256), 256, 0, stream>>>(pw_w, wpw0, 104, 104, 128);
    prep_w<<<CEILDIV(104*128,256), 256, 0, stream>>>(pw_w + 104*104, wpw1, 104, 104, 128);
    prep_w<<<CEILDIV(208*128,256), 256, 0, stream>>>(fc_w1, wfc1, 104, 208, 128);
    prep_w<<<CEILDIV(104*224,256), 256, 0, stream>>>(fc_w2, wfc2, 208, 104, 224);
    prep_w<<<CEILDIV(104*37960,256), 256, 0, stream>>>(ep_w, wept, 37960, 104, 37960);

    const int GX = CEILDIV(TN, 64);     // 2282
    dim3 g2(GX, 2), g4(GX, 4), g5(GX, 5);

    // 1. hcat -> B2
    hcat_kernel<<<TN, 128, 0, stream>>>(x, W_in, b_in, adp, B2);
    // 2. h = hcat @ W_tp + b_tp -> B0  (hcat dead afterwards)
    gemm_mf<128><<<g2, 256, 0, stream>>>(B2, 104, 104, wtp, b_tp, B0, TN, 104, 0);
    // 2b. z1 pre-staging into B2: adp -> bf16 padded; h -> hT
    prep_adp<<<CEILDIV((int)NADP,256), 256, 0, stream>>>(adp, adp_bf);
    ht_kernel<<<dim3(7, TT), 256, 0, stream>>>(B0, hTbuf);
    // 3. z1 -> B1
    z1_mf<<<dim3(7, TT), 256, 0, stream>>>(adp_bf, hTbuf, B1);
    // 4. attention 0 on h
    gemm_mf<128><<<g5, 256, 0, stream>>>(B0, 104, 104, wqkv0, nullptr, B2, TN, 312, 0);
    kvs_kernel<<<dim3(TT, NH), 256, 0, stream>>>(B2, kvs_s, ksum_s, NN, (long long)NN*312, 312);
    kvs_kernel<<<dim3(NN, NH), 256, 0, stream>>>(B2, kvs_t, ksum_t, TT, 312, (long long)NN*312);
    attn_apply<<<TN, 256, 0, stream>>>(B2, kvs_s, ksum_s, kvs_t, ksum_t);
    gemm_mf<224><<<g2, 256, 0, stream>>>(B2, 312, 208, wop0, op_b, B3, TN, 104, 0);      // att0 -> B3
    // 5. attention 1 on z1
    gemm_mf<128><<<g5, 256, 0, stream>>>(B1, 104, 104, wqkv1, nullptr, B2, TN, 312, 0);
    kvs_kernel<<<dim3(TT, NH), 256, 0, stream>>>(B2, kvs_s, ksum_s, NN, (long long)NN*312, 312);
    kvs_kernel<<<dim3(NN, NH), 256, 0, stream>>>(B2, kvs_t, ksum_t, TT, 312, (long long)NN*312);
    attn_apply<<<TN, 256, 0, stream>>>(B2, kvs_s, ksum_s, kvs_t, ksum_t);
    gemm_mf<224><<<g2, 256, 0, stream>>>(B2, 312, 208, wop1, op_b + 104, B1, TN, 104, 0); // att1 -> B1
    // 6. pointwise gates -> B2
    gemm_mf<128><<<g2, 256, 0, stream>>>(B0, 104, 104, wpw0, pw_b, B2, TN, 104, 0);
    gemm_mf<128><<<g2, 256, 0, stream>>>(B3, 104, 104, wpw1, pw_b + 104, B2 + (size_t)TN*104, TN, 104, 0);
    // 7. LN1 in-place (B0 -> h1)
    ln1_kernel<<<TN, 128, 0, stream>>>(B0, B3, B1, B2, B2 + (size_t)TN*104, ln1_g, ln1_b);
    // 8. MLP + LN2
    gemm_mf<128><<<g4, 256, 0, stream>>>(B0, 104, 104, wfc1, fc_b1, B2, TN, 208, 1);
    gemm_mf<224><<<g2, 256, 0, stream>>>(B2, 208, 208, wfc2, fc_b2, B1, TN, 104, 0);
    ln2_kernel<<<TN, 128, 0, stream>>>(B0, B1, ln2_g, ln2_b, B3);                        // h2 -> B3
    // 9. encoder_proj
    y_init_kernel<<<CEILDIV(NN*104,256), 256, 0, stream>>>(ybuf, ep_b);
    ep_mf<<<dim3(CEILDIV(NN,64), 2, CEILDIV(TT,8)), 256, 0, stream>>>(B3, wept, ybuf);
    // 10. residual MLP blocks
    for (int i = 0; i < 3; ++i)
        enc_kernel<<<NN, 256, 0, stream>>>(ybuf, enc_w1 + (size_t)i*104*208, enc_b1 + (size_t)i*208,
                                           enc_w2 + (size_t)i*208*104, enc_b2 + (size_t)i*104);
    // 11. output projection
    out_kernel<<<NN, 256, 0, stream>>>(ybuf, out_w, out_b, (float*)d_out);
}

// Round 7
// 2465.803 us; speedup vs baseline: 2.3692x; 1.0418x over previous
//
#include <hip/hip_runtime.h>
#include <hip/hip_bf16.h>
#include <cstddef>

// ---------------- problem constants ----------------
#define TT   365
#define NN   400
#define TN   (TT*NN)            // 146000
#define HD   26                 // head dim
#define NH   4                  // heads

#define CEILDIV(a,b) (((a)+(b)-1)/(b))

typedef __hip_bfloat16 bf16;
typedef short short8v __attribute__((ext_vector_type(8)));
typedef float float4v __attribute__((ext_vector_type(4)));
__device__ __forceinline__ float b2f(bf16 v){ return __bfloat162float(v); }
__device__ __forceinline__ bf16  f2b(float v){ return __float2bfloat16(v); }

// ---------------- workspace layout ----------------
static constexpr size_t NB0 = (size_t)TN*104;   // h / h1
static constexpr size_t NB1 = (size_t)TN*104;   // z1 -> att1 -> m
static constexpr size_t NB2 = (size_t)TN*312;   // hcat -> [adp_bf|hT] -> qkv+concat -> p0|p1 -> hidden
static constexpr size_t NB3 = (size_t)TN*104;   // att0 -> h2
static constexpr size_t NBF = NB0+NB1+NB2+NB3;
static constexpr size_t NKVS_S  = (size_t)TT*NH*HD*HD;
static constexpr size_t NKSUM_S = (size_t)TT*NH*HD;
static constexpr size_t NKVS_T  = (size_t)NN*NH*HD*HD;
static constexpr size_t NKSUM_T = (size_t)NN*NH*HD;
static constexpr size_t NY      = (size_t)NN*104;
static constexpr size_t NAUX    = NKVS_S+NKSUM_S+NKVS_T+NKSUM_T+NY;
// transposed bf16 weights (Wt[n][kp], zero-padded k)
static constexpr size_t NW_TP   = 104*128;
static constexpr size_t NW_QKV  = 312*128;   // x2
static constexpr size_t NW_OP   = 104*224;   // x2
static constexpr size_t NW_PW   = 104*128;   // x2
static constexpr size_t NW_FC1  = 208*128;
static constexpr size_t NW_FC2  = 104*224;
static constexpr size_t NW_EPT  = (size_t)104*37960;   // ep_w transposed, no pad
static constexpr size_t NWT     = NW_TP + 2*NW_QKV + 2*NW_OP + 2*NW_PW + NW_FC1 + NW_FC2 + NW_EPT;
static constexpr size_t WS_NEEDED = NBF*2 + NAUX*4 + NWT*2;
// z1 scratch lives inside B2 (dead between step 2 and step 4):
static constexpr size_t NADP_ROWS = (size_t)TN + 64;           // padded rows (last tile OOB-safe)
static constexpr size_t NADP = NADP_ROWS*96;                   // adp in bf16, width padded to 96
static constexpr size_t NHT  = ((size_t)TT*104 + 8)*448;       // h transposed, width padded to 448, +8 pad rows
static_assert(NADP + NHT <= NB2, "z1 scratch must fit in B2");

// ---------------- weight prep: Wt[n*KP+k] = bf16(W[k*Nc+n]), zero pad k>=K ----------------
__global__ void __launch_bounds__(256) prep_w(
    const float* __restrict__ W, bf16* __restrict__ Wt, int K, int Nc, int KP)
{
    int idx = blockIdx.x*256 + threadIdx.x;
    if (idx >= Nc*KP) return;
    int n = idx / KP, k = idx - n*KP;
    Wt[idx] = (k < K) ? f2b(W[(size_t)k*Nc + n]) : f2b(0.f);
}

// adp_bf[row][e] = bf16(adp[row][e]) for e<80 else 0; rows >= TN are zero.
__global__ void __launch_bounds__(256) prep_adp(
    const float* __restrict__ adp, bf16* __restrict__ out)
{
    size_t i = (size_t)blockIdx.x*256 + threadIdx.x;
    if (i >= NADP) return;
    size_t row = i / 96; int e = (int)(i - row*96);
    float v = (row < TN && e < 80) ? adp[row*80 + e] : 0.f;
    out[i] = f2b(v);
}

// hT[t][d][n] = h[t][n][d], n padded to 448 with zeros (LDS transpose, coalesced both ways)
__global__ void __launch_bounds__(256) ht_kernel(
    const bf16* __restrict__ h, bf16* __restrict__ hT)
{
    __shared__ bf16 As[64*106];
    int t = blockIdx.y, n0 = blockIdx.x*64;
    int tid = threadIdx.x;
    for (int idx = tid; idx < 64*52; idx += 256) {
        int r = idx / 52, k = idx - r*52;
        int n = n0 + r;
        uint v = 0;
        if (n < NN) v = *(const uint*)(h + ((size_t)t*NN + n)*104 + k*2);
        *(uint*)(&As[r*106 + k*2]) = v;
    }
    __syncthreads();
    for (int idx = tid; idx < 104*32; idx += 256) {
        int d = idx >> 5, np = idx & 31;
        int n = np*2;
        ushort lo = *(ushort*)&As[n*106 + d];
        ushort hi = *(ushort*)&As[(n+1)*106 + d];
        uint v = ((uint)hi << 16) | lo;
        *(uint*)(hT + ((size_t)t*104 + d)*448 + n0 + n) = v;
    }
}

// ---------------- hcat ----------------
__global__ void __launch_bounds__(128) hcat_kernel(
    const float* __restrict__ x, const float* __restrict__ W_in,
    const float* __restrict__ b_in, const float* __restrict__ adp,
    bf16* __restrict__ hcat)
{
    int bid = blockIdx.x;            // t*400 + n
    int t = bid / NN, n = bid - t*NN;
    int tid = threadIdx.x;
    if (tid < 24) {
        float s = b_in[tid];
        size_t xb = ((size_t)n*TT + t)*3;
        #pragma unroll
        for (int i = 0; i < 3; ++i) s += x[xb + i] * W_in[i*24 + tid];
        hcat[(size_t)bid*104 + tid] = f2b(s);
    } else if (tid < 104) {
        hcat[(size_t)bid*104 + tid] = f2b(adp[(size_t)bid*80 + (tid - 24)]);
    }
}

// ---------------- MFMA GEMM: C[M,Nc] = A[M,K](lda,bf16) @ W + bias ----------------
template<int KP>
__global__ void __launch_bounds__(256) gemm_mf(
    const bf16* __restrict__ A, int lda, int K,
    const bf16* __restrict__ Wt, const float* __restrict__ bias,
    bf16* __restrict__ C, int M, int Nc, int relu)
{
    constexpr int STR = KP + 8;          // bf16 elems; +8 keeps b128 reads 2-way (free)
    __shared__ bf16 As[64*STR];
    __shared__ bf16 Ws[64*STR];
    int m0 = blockIdx.x * 64;
    int c0 = blockIdx.y * 64;
    int tid = threadIdx.x;
    const int KW = KP/2;                 // uints per row
    for (int idx = tid; idx < 64*KW; idx += 256) {
        int r = idx / KW, kw = idx - r*KW;
        int m = m0 + r, k = kw*2;
        uint v = 0;
        if (m < M && k < K) v = *(const uint*)(A + (size_t)m*lda + k);
        *(uint*)(&As[r*STR + k]) = v;
    }
    for (int idx = tid; idx < 64*KW; idx += 256) {
        int r = idx / KW, kw = idx - r*KW;
        int n = c0 + r, k = kw*2;
        uint v = 0;
        if (n < Nc) v = *(const uint*)(Wt + (size_t)n*KP + k);
        *(uint*)(&Ws[r*STR + k]) = v;
    }
    __syncthreads();

    int lane = tid & 63, w = tid >> 6;
    int n16 = lane & 15, quad = lane >> 4;
    constexpr int KS = KP/32;
    short8v af[KS];
    #pragma unroll
    for (int s = 0; s < KS; ++s)
        af[s] = *(const short8v*)(&As[(16*w + n16)*STR + s*32 + quad*8]);
    float4v acc[4];
    #pragma unroll
    for (int ct = 0; ct < 4; ++ct) { float4v z = {0.f,0.f,0.f,0.f}; acc[ct] = z; }
    #pragma unroll
    for (int ct = 0; ct < 4; ++ct) {
        #pragma unroll
        for (int s = 0; s < KS; ++s) {
            short8v bfr = *(const short8v*)(&Ws[(ct*16 + n16)*STR + s*32 + quad*8]);
            acc[ct] = __builtin_amdgcn_mfma_f32_16x16x32_bf16(af[s], bfr, acc[ct], 0, 0, 0);
        }
    }
    #pragma unroll
    for (int ct = 0; ct < 4; ++ct) {
        int c = c0 + ct*16 + n16;
        if (c < Nc) {
            float b = bias ? bias[c] : 0.f;
            #pragma unroll
            for (int reg = 0; reg < 4; ++reg) {
                int m = m0 + 16*w + quad*4 + reg;
                if (m < M) {
                    float v = acc[ct][reg] + b;
                    if (relu) v = fmaxf(v, 0.f);
                    C[(size_t)m*Nc + c] = f2b(v);
                }
            }
        }
    }
}

// ---------------- MFMA encoder_proj: y[400,104] += sum_t h2[t] @ ep_w[t] ----------------
__global__ void __launch_bounds__(256) ep_mf(
    const bf16* __restrict__ h2, const bf16* __restrict__ wt, float* __restrict__ y)
{
    constexpr int STR = 136;             // 128 padded K + 8
    __shared__ bf16 As[64*STR];
    __shared__ bf16 Ws[64*STR];
    int m0 = blockIdx.x * 64;
    int c0 = blockIdx.y * 64;
    int t0 = blockIdx.z * 8;
    int t1 = min(TT, t0 + 8);
    int tid = threadIdx.x;
    int lane = tid & 63, w = tid >> 6, n16 = lane & 15, quad = lane >> 4;

    float4v acc[4];
    #pragma unroll
    for (int ct = 0; ct < 4; ++ct) { float4v z = {0.f,0.f,0.f,0.f}; acc[ct] = z; }

    for (int t = t0; t < t1; ++t) {
        for (int idx = tid; idx < 64*64; idx += 256) {     // 64 rows x 64 uints
            int r = idx >> 6, k = (idx & 63)*2;
            int m = m0 + r;
            uint va = 0;
            if (m < NN && k < 104) va = *(const uint*)(h2 + ((size_t)t*NN + m)*104 + k);
            *(uint*)(&As[r*STR + k]) = va;
            int c = c0 + r;
            uint vw = 0;
            if (c < 104 && k < 104) vw = *(const uint*)(wt + (size_t)c*37960 + t*104 + k);
            *(uint*)(&Ws[r*STR + k]) = vw;
        }
        __syncthreads();
        short8v af[4];
        #pragma unroll
        for (int s = 0; s < 4; ++s)
            af[s] = *(const short8v*)(&As[(16*w + n16)*STR + s*32 + quad*8]);
        #pragma unroll
        for (int ct = 0; ct < 4; ++ct) {
            #pragma unroll
            for (int s = 0; s < 4; ++s) {
                short8v bfr = *(const short8v*)(&Ws[(ct*16 + n16)*STR + s*32 + quad*8]);
                acc[ct] = __builtin_amdgcn_mfma_f32_16x16x32_bf16(af[s], bfr, acc[ct], 0, 0, 0);
            }
        }
        __syncthreads();
    }
    #pragma unroll
    for (int ct = 0; ct < 4; ++ct) {
        int c = c0 + ct*16 + n16;
        if (c < 104) {
            #pragma unroll
            for (int reg = 0; reg < 4; ++reg) {
                int m = m0 + 16*w + quad*4 + reg;
                if (m < NN) atomicAdd(&y[(size_t)m*104 + c], acc[ct][reg]);
            }
        }
    }
}

// ---------------- MFMA z1 (v2): z1[t] = softmax(relu(adp adp^T)) @ h[t] ----------------
__global__ void __launch_bounds__(256) z1_mf(
    const bf16* __restrict__ adp_bf, const bf16* __restrict__ hT, bf16* __restrict__ z1)
{
    constexpr int SA = 104;   // 96 + 8
    constexpr int SP = 72;    // 64 + 8
    __shared__ bf16 As[64*SA];
    __shared__ bf16 Bt[64*SA];
    __shared__ bf16 Ht[112*SP];
    __shared__ bf16 P[64*SP];
    int t = blockIdx.y;
    int r0 = blockIdx.x * 64;
    int tid = threadIdx.x;
    int lane = tid & 63, w = tid >> 6, n16 = lane & 15, quad = lane >> 4;

    {   // stage As: 64 rows x 96 bf16 = 64 x 12 uint4  (uint4 = 8 bf16)
        const uint4* src = (const uint4*)(adp_bf + ((size_t)t*NN + r0)*96);
        for (int idx = tid; idx < 768; idx += 256) {
            int r = idx / 12, q = idx - r*12;
            *(uint4*)(&As[r*SA + q*8]) = src[idx];
        }
    }
    __syncthreads();
    short8v af[3];
    #pragma unroll
    for (int s = 0; s < 3; ++s)
        af[s] = *(const short8v*)(&As[(16*w + n16)*SA + s*32 + quad*8]);

    float4v onum[7];
    #pragma unroll
    for (int dt = 0; dt < 7; ++dt) { float4v z = {0.f,0.f,0.f,0.f}; onum[dt] = z; }
    float rs[4] = {0.f,0.f,0.f,0.f};

    for (int c0 = 0; c0 < NN; c0 += 64) {
        {   // stage Bt: 64 rows x 12 uint4 (padded buffer -> branch-free)
            const uint4* srcB = (const uint4*)(adp_bf + ((size_t)t*NN + c0)*96);
            for (int idx = tid; idx < 768; idx += 256) {
                int r = idx / 12, q = idx - r*12;
                *(uint4*)(&Bt[r*SA + q*8]) = srcB[idx];
            }
        }
        {   // stage Ht: 112 rows x 8 uint4 (64 cols) from hT (rows >=104 garbage, masked later)
            const bf16* hb = hT + (size_t)t*104*448 + c0;
            for (int idx = tid; idx < 896; idx += 256) {
                int d = idx >> 3, q = idx & 7;
                *(uint4*)(&Ht[d*SP + q*8]) = *(const uint4*)(hb + (size_t)d*448 + q*8);
            }
        }
        __syncthreads();
        float4v sc[4];
        #pragma unroll
        for (int ct = 0; ct < 4; ++ct) { float4v z = {0.f,0.f,0.f,0.f}; sc[ct] = z; }
        #pragma unroll
        for (int ct = 0; ct < 4; ++ct) {
            #pragma unroll
            for (int s = 0; s < 3; ++s) {
                short8v bfr = *(const short8v*)(&Bt[(ct*16 + n16)*SA + s*32 + quad*8]);
                sc[ct] = __builtin_amdgcn_mfma_f32_16x16x32_bf16(af[s], bfr, sc[ct], 0, 0, 0);
            }
        }
        // exp + mask OOB cols + write P (own-wave rows) + rowsum
        #pragma unroll
        for (int ct = 0; ct < 4; ++ct) {
            bool colok = (c0 + ct*16 + n16) < NN;
            #pragma unroll
            for (int reg = 0; reg < 4; ++reg) {
                float e = colok ? __expf(fmaxf(sc[ct][reg], 0.f)) : 0.f;
                rs[reg] += e;
                P[(16*w + quad*4 + reg)*SP + ct*16 + n16] = f2b(e);
            }
        }
        short8v pf[2];
        #pragma unroll
        for (int s = 0; s < 2; ++s)
            pf[s] = *(const short8v*)(&P[(16*w + n16)*SP + s*32 + quad*8]);
        #pragma unroll
        for (int dt = 0; dt < 7; ++dt) {
            #pragma unroll
            for (int s = 0; s < 2; ++s) {
                short8v bfr = *(const short8v*)(&Ht[(dt*16 + n16)*SP + s*32 + quad*8]);
                onum[dt] = __builtin_amdgcn_mfma_f32_16x16x32_bf16(pf[s], bfr, onum[dt], 0, 0, 0);
            }
        }
        __syncthreads();
    }
    #pragma unroll
    for (int reg = 0; reg < 4; ++reg) {
        float v = rs[reg];
        v += __shfl_xor(v, 1, 64);
        v += __shfl_xor(v, 2, 64);
        v += __shfl_xor(v, 4, 64);
        v += __shfl_xor(v, 8, 64);
        rs[reg] = v;
    }
    #pragma unroll
    for (int reg = 0; reg < 4; ++reg) {
        int row = r0 + 16*w + quad*4 + reg;
        if (row < NN) {
            float inv = 1.f / rs[reg];
            #pragma unroll
            for (int dt = 0; dt < 7; ++dt) {
                int d = dt*16 + n16;
                if (d < 104)
                    z1[((size_t)t*NN + row)*104 + d] = f2b(onum[dt][reg] * inv);
            }
        }
    }
}

// ---------------- linear-attention KV summaries ----------------
__global__ void __launch_bounds__(256) kvs_kernel(
    const bf16* __restrict__ qkv, float* __restrict__ kvs, float* __restrict__ ksum,
    int L, long long strideB, long long strideL)
{
    int b = blockIdx.x, head = blockIdx.y;
    long long base = (long long)b*strideB + 104 + head*HD;   // k; v at +104
    __shared__ float kc[32][27], vc[32][27], inv[32];
    int tid = threadIdx.x;
    float acc[3] = {0.f,0.f,0.f};
    float ks = 0.f;
    for (int l0 = 0; l0 < L; l0 += 32) {
        int lw = min(32, L - l0);
        __syncthreads();
        for (int idx = tid; idx < lw*HD; idx += 256) {
            int ll = idx / HD, m = idx - ll*HD;
            long long a = base + (long long)(l0 + ll)*strideL + m;
            kc[ll][m] = b2f(qkv[a]);
            vc[ll][m] = b2f(qkv[a + 104]);
        }
        __syncthreads();
        if (tid < lw) {
            float ss = 0.f;
            #pragma unroll
            for (int m = 0; m < HD; ++m) { float v = kc[tid][m]; ss += v*v; }
            inv[tid] = 1.f / fmaxf(sqrtf(ss), 1e-12f);
        }
        __syncthreads();
        for (int idx = tid; idx < lw*HD; idx += 256) {
            int ll = idx / HD, m = idx - ll*HD;
            kc[ll][m] *= inv[ll];
        }
        __syncthreads();
        #pragma unroll
        for (int jj = 0; jj < 3; ++jj) {
            int p = tid + jj*256;
            if (p < HD*HD) {
                int m = p / HD, d = p - m*HD;
                float a = 0.f;
                for (int ll = 0; ll < lw; ++ll) a += kc[ll][m] * vc[ll][d];
                acc[jj] += a;
            }
        }
        if (tid < HD) {
            float a = 0.f;
            for (int ll = 0; ll < lw; ++ll) a += kc[ll][tid];
            ks += a;
        }
    }
    long long ob = ((long long)b*NH + head) * (HD*HD);
    #pragma unroll
    for (int jj = 0; jj < 3; ++jj) {
        int p = tid + jj*256;
        if (p < HD*HD) kvs[ob + p] = acc[jj];
    }
    if (tid < HD) ksum[((long long)b*NH + head)*HD + tid] = ks;
}

// ---------------- apply linear attention (v2): 4 rows/block, wave-per-row ----------------
// writes concat into qkv[row][0:208]; kvs_s[t]+ksum_s[t] staged in LDS once per block.
// invq folded multiplicatively: num = invq*(q.kv) + L*v ; den = invq*(q.ksum) + L.
__global__ void __launch_bounds__(256) attn_apply(
    bf16* __restrict__ qkv,
    const float* __restrict__ kvs_s, const float* __restrict__ ksum_s,
    const float* __restrict__ kvs_t, const float* __restrict__ ksum_t)
{
    int g = blockIdx.x;                  // 4 rows per block; 400 % 4 == 0 -> same t
    int row0 = g*4;
    int t = row0 / NN, n0 = row0 - t*NN;
    int tid = threadIdx.x, w = tid >> 6, j = tid & 63;
    __shared__ float kvS[NH][HD][HD+1];
    __shared__ float ksS[NH][HD];
    __shared__ float qs[4][112];
    __shared__ float invq[4][NH];
    __shared__ float denr[4][2*NH];

    const float* src = kvs_s + (size_t)t*(NH*HD*HD);
    for (int i = tid; i < NH*HD*HD; i += 256) {
        int h = i/(HD*HD), p = i - h*HD*HD; int m = p/HD, d = p - m*HD;
        kvS[h][m][d] = src[i];
    }
    for (int i = tid; i < NH*HD; i += 256) {
        int h = i/HD; ksS[h][i - h*HD] = ksum_s[(size_t)t*(NH*HD) + i];
    }
    int row = row0 + w;
    int n = n0 + w;
    size_t rb = (size_t)row * 312;
    if (j < 52) {
        uint u = *(const uint*)(qkv + rb + 2*j);
        ushort ulo = (ushort)(u & 0xffffu), uhi = (ushort)(u >> 16);
        qs[w][2*j]   = b2f(*(bf16*)&ulo);
        qs[w][2*j+1] = b2f(*(bf16*)&uhi);
    }
    __syncthreads();
    if (j < NH) {                               // per-head 1/||q||
        float ss = 0.f;
        #pragma unroll
        for (int m = 0; m < HD; ++m) { float v = qs[w][j*HD + m]; ss += v*v; }
        invq[w][j] = 1.f / fmaxf(sqrtf(ss), 1e-12f);
    } else if (j < 12) {                        // raw denominators (unnormalized)
        int p = j - 4; int sp = p >> 2, h = p & 3;   // sp=0 spatial, 1 temporal
        const float* ks = sp ? &ksum_t[((size_t)n*NH + h)*HD] : &ksS[h][0];
        float s = 0.f;
        #pragma unroll
        for (int m = 0; m < HD; ++m) s += qs[w][h*HD + m] * ks[m];
        denr[w][p] = s;
    }
    __syncthreads();
    const float* kvT = kvs_t + (size_t)n*(NH*HD*HD);
    #pragma unroll
    for (int k = 0; k < 4; ++k) {
        int d = j + 64*k;
        if (d < 208) {
            int sp = (d < 104) ? 0 : 1;          // 0: spatial output, 1: temporal
            int dd = sp ? d - 104 : d;
            int h = dd / HD, c = dd - h*HD;
            float sum = 0.f;
            if (!sp) {
                #pragma unroll
                for (int m = 0; m < HD; ++m) sum += qs[w][h*HD + m] * kvS[h][m][c];
            } else {
                const float* kv = kvT + h*HD*HD + c;
                #pragma unroll
                for (int m = 0; m < HD; ++m) sum += qs[w][h*HD + m] * kv[m*HD];
            }
            float iq = invq[w][h];
            float Lf = sp ? (float)TT : (float)NN;
            float num = iq*sum + Lf * b2f(qkv[rb + 208 + dd]);
            float den = iq*denr[w][sp*4 + h] + Lf;
            qkv[rb + d] = f2b(num / den);
        }
    }
}

__device__ __forceinline__ float bsum128(float v, float* red, int tid) {
    #pragma unroll
    for (int off = 32; off > 0; off >>= 1) v += __shfl_down(v, off, 64);
    __syncthreads();
    if ((tid & 63) == 0) red[tid >> 6] = v;
    __syncthreads();
    return red[0] + red[1];
}

__global__ void __launch_bounds__(128) ln1_kernel(
    bf16* __restrict__ h, const bf16* __restrict__ att0, const bf16* __restrict__ att1,
    const bf16* __restrict__ p0, const bf16* __restrict__ p1,
    const float* __restrict__ gamma, const float* __restrict__ beta)
{
    int tid = threadIdx.x;
    size_t base = (size_t)blockIdx.x * 104;
    __shared__ float red[2];
    float x = 0.f;
    if (tid < 104) {
        float hv = b2f(h[base + tid]);
        x = 2.f * (hv + b2f(att0[base + tid])*b2f(p0[base + tid])
                      + 0.01f*b2f(att1[base + tid])*b2f(p1[base + tid]));
    }
    float mean = bsum128(x, red, tid) * (1.f/104.f);
    float dx = (tid < 104) ? (x - mean) : 0.f;
    float var = bsum128(dx*dx, red, tid) * (1.f/104.f);
    if (tid < 104)
        h[base + tid] = f2b(dx * rsqrtf(var + 1e-5f) * gamma[tid] + beta[tid]);
}

__global__ void __launch_bounds__(128) ln2_kernel(
    const bf16* __restrict__ h1, const bf16* __restrict__ m,
    const float* __restrict__ gamma, const float* __restrict__ beta,
    bf16* __restrict__ h2)
{
    int tid = threadIdx.x;
    size_t base = (size_t)blockIdx.x * 104;
    __shared__ float red[2];
    float x = 0.f;
    if (tid < 104) x = b2f(h1[base + tid]) + b2f(m[base + tid]);
    float mean = bsum128(x, red, tid) * (1.f/104.f);
    float dx = (tid < 104) ? (x - mean) : 0.f;
    float var = bsum128(dx*dx, red, tid) * (1.f/104.f);
    if (tid < 104)
        h2[base + tid] = f2b(dx * rsqrtf(var + 1e-5f) * gamma[tid] + beta[tid]);
}

__global__ void __launch_bounds__(256) y_init_kernel(float* __restrict__ y, const float* __restrict__ ep_b) {
    int i = blockIdx.x*256 + threadIdx.x;
    if (i < NN*104) y[i] = ep_b[i % 104];
}

__global__ void __launch_bounds__(256) enc_kernel(
    float* __restrict__ y, const float* __restrict__ w1, const float* __restrict__ b1,
    const float* __restrict__ w2, const float* __restrict__ b2)
{
    int n = blockIdx.x;
    int tid = threadIdx.x;
    __shared__ float yr[104], hid[208];
    if (tid < 104) yr[tid] = y[(size_t)n*104 + tid];
    __syncthreads();
    if (tid < 208) {
        float s = b1[tid];
        for (int k = 0; k < 104; ++k) s += yr[k] * w1[(size_t)k*208 + tid];
        hid[tid] = fmaxf(s, 0.f);
    }
    __syncthreads();
    if (tid < 104) {
        float s = b2[tid];
        for (int k = 0; k < 208; ++k) s += hid[k] * w2[(size_t)k*104 + tid];
        y[(size_t)n*104 + tid] = yr[tid] + s;
    }
}

__global__ void __launch_bounds__(256) out_kernel(
    const float* __restrict__ y, const float* __restrict__ out_w,
    const float* __restrict__ out_b, float* __restrict__ out)
{
    int n = blockIdx.x;
    int tid = threadIdx.x;
    __shared__ float yr[104];
    if (tid < 104) yr[tid] = y[(size_t)n*104 + tid];
    __syncthreads();
    for (int t = tid; t < TT; t += 256) {
        float s = out_b[t];
        for (int d = 0; d < 104; ++d) s += yr[d] * out_w[(size_t)d*TT + t];
        out[(size_t)n*TT + t] = s;
    }
}

// ---------------- launch ----------------
extern "C" void kernel_launch(void* const* d_in, const int* in_sizes, int n_in,
                              void* d_out, int out_size, void* d_ws, size_t ws_size,
                              hipStream_t stream) {
    if (ws_size < WS_NEEDED) return;   // readable failure instead of page fault

    const float* x      = (const float*)d_in[0];
    const float* W_in   = (const float*)d_in[1];
    const float* b_in   = (const float*)d_in[2];
    const float* adp    = (const float*)d_in[3];
    const float* W_tp   = (const float*)d_in[4];
    const float* b_tp   = (const float*)d_in[5];
    const float* qkv_w  = (const float*)d_in[6];
    const float* op_w   = (const float*)d_in[7];
    const float* op_b   = (const float*)d_in[8];
    const float* pw_w   = (const float*)d_in[9];
    const float* pw_b   = (const float*)d_in[10];
    const float* fc_w1  = (const float*)d_in[11];
    const float* fc_b1  = (const float*)d_in[12];
    const float* fc_w2  = (const float*)d_in[13];
    const float* fc_b2  = (const float*)d_in[14];
    const float* ln1_g  = (const float*)d_in[15];
    const float* ln1_b  = (const float*)d_in[16];
    const float* ln2_g  = (const float*)d_in[17];
    const float* ln2_b  = (const float*)d_in[18];
    const float* ep_w   = (const float*)d_in[19];
    const float* ep_b   = (const float*)d_in[20];
    const float* enc_w1 = (const float*)d_in[21];
    const float* enc_b1 = (const float*)d_in[22];
    const float* enc_w2 = (const float*)d_in[23];
    const float* enc_b2 = (const float*)d_in[24];
    const float* out_w  = (const float*)d_in[25];
    const float* out_b  = (const float*)d_in[26];

    bf16* B0 = (bf16*)d_ws;
    bf16* B1 = B0 + NB0;
    bf16* B2 = B1 + NB1;
    bf16* B3 = B2 + NB2;
    float* kvs_s  = (float*)(B3 + NB3);
    float* ksum_s = kvs_s + NKVS_S;
    float* kvs_t  = ksum_s + NKSUM_S;
    float* ksum_t = kvs_t + NKVS_T;
    float* ybuf   = ksum_t + NKSUM_T;
    bf16* wtp   = (bf16*)(ybuf + NY);
    bf16* wqkv0 = wtp + NW_TP;
    bf16* wqkv1 = wqkv0 + NW_QKV;
    bf16* wop0  = wqkv1 + NW_QKV;
    bf16* wop1  = wop0 + NW_OP;
    bf16* wpw0  = wop1 + NW_OP;
    bf16* wpw1  = wpw0 + NW_PW;
    bf16* wfc1  = wpw1 + NW_PW;
    bf16* wfc2  = wfc1 + NW_FC1;
    bf16* wept  = wfc2 + NW_FC2;
    // z1 scratch aliases B2 (dead between step 2 and step 4)
    bf16* adp_bf = B2;
    bf16* hTbuf  = B2 + NADP;

    // 0. weight prep (tiny)
    prep_w<<<CEILDIV(104*128,256), 256, 0, stream>>>(W_tp, wtp, 104, 104, 128);
    prep_w<<<CEILDIV(312*128,256), 256, 0, stream>>>(qkv_w, wqkv0, 104, 312, 128);
    prep_w<<<CEILDIV(312*128,256), 256, 0, stream>>>(qkv_w + 104*312, wqkv1, 104, 312, 128);
    prep_w<<<CEILDIV(104*224,256), 256, 0, stream>>>(op_w, wop0, 208, 104, 224);
    prep_w<<<CEILDIV(104*224,256), 256, 0, stream>>>(op_w + 208*104, wop1, 208, 104, 224);
    prep_w<<<CEILDIV(104*128,256), 256, 0, stream>>>(pw_w, wpw0, 104, 104, 128);
    prep_w<<<CEILDIV(104*128,256), 256, 0, stream>>>(pw_w + 104*104, wpw1, 104, 104, 128);
    prep_w<<<CEILDIV(208*128,256), 256, 0, stream>>>(fc_w1, wfc1, 104, 208, 128);
    prep_w<<<CEILDIV(104*224,256), 256, 0, stream>>>(fc_w2, wfc2, 208, 104, 224);
    prep_w<<<CEILDIV(104*37960,256), 256, 0, stream>>>(ep_w, wept, 37960, 104, 37960);

    const int GX = CEILDIV(TN, 64);     // 2282
    dim3 g2(GX, 2), g4(GX, 4), g5(GX, 5);

    // 1. hcat -> B2
    hcat_kernel<<<TN, 128, 0, stream>>>(x, W_in, b_in, adp, B2);
    // 2. h = hcat @ W_tp + b_tp -> B0  (hcat dead afterwards)
    gemm_mf<128><<<g2, 256, 0, stream>>>(B2, 104, 104, wtp, b_tp, B0, TN, 104, 0);
    // 2b. z1 pre-staging into B2: adp -> bf16 padded; h -> hT
    prep_adp<<<CEILDIV((int)NADP,256), 256, 0, stream>>>(adp, adp_bf);
    ht_kernel<<<dim3(7, TT), 256, 0, stream>>>(B0, hTbuf);
    // 3. z1 -> B1
    z1_mf<<<dim3(7, TT), 256, 0, stream>>>(adp_bf, hTbuf, B1);
    // 4. attention 0 on h
    gemm_mf<128><<<g5, 256, 0, stream>>>(B0, 104, 104, wqkv0, nullptr, B2, TN, 312, 0);
    kvs_kernel<<<dim3(TT, NH), 256, 0, stream>>>(B2, kvs_s, ksum_s, NN, (long long)NN*312, 312);
    kvs_kernel<<<dim3(NN, NH), 256, 0, stream>>>(B2, kvs_t, ksum_t, TT, 312, (long long)NN*312);
    attn_apply<<<TN/4, 256, 0, stream>>>(B2, kvs_s, ksum_s, kvs_t, ksum_t);
    gemm_mf<224><<<g2, 256, 0, stream>>>(B2, 312, 208, wop0, op_b, B3, TN, 104, 0);      // att0 -> B3
    // 5. attention 1 on z1
    gemm_mf<128><<<g5, 256, 0, stream>>>(B1, 104, 104, wqkv1, nullptr, B2, TN, 312, 0);
    kvs_kernel<<<dim3(TT, NH), 256, 0, stream>>>(B2, kvs_s, ksum_s, NN, (long long)NN*312, 312);
    kvs_kernel<<<dim3(NN, NH), 256, 0, stream>>>(B2, kvs_t, ksum_t, TT, 312, (long long)NN*312);
    attn_apply<<<TN/4, 256, 0, stream>>>(B2, kvs_s, ksum_s, kvs_t, ksum_t);
    gemm_mf<224><<<g2, 256, 0, stream>>>(B2, 312, 208, wop1, op_b + 104, B1, TN, 104, 0); // att1 -> B1
    // 6. pointwise gates -> B2
    gemm_mf<128><<<g2, 256, 0, stream>>>(B0, 104, 104, wpw0, pw_b, B2, TN, 104, 0);
    gemm_mf<128><<<g2, 256, 0, stream>>>(B3, 104, 104, wpw1, pw_b + 104, B2 + (size_t)TN*104, TN, 104, 0);
    // 7. LN1 in-place (B0 -> h1)
    ln1_kernel<<<TN, 128, 0, stream>>>(B0, B3, B1, B2, B2 + (size_t)TN*104, ln1_g, ln1_b);
    // 8. MLP + LN2
    gemm_mf<128><<<g4, 256, 0, stream>>>(B0, 104, 104, wfc1, fc_b1, B2, TN, 208, 1);
    gemm_mf<224><<<g2, 256, 0, stream>>>(B2, 208, 208, wfc2, fc_b2, B1, TN, 104, 0);
    ln2_kernel<<<TN, 128, 0, stream>>>(B0, B1, ln2_g, ln2_b, B3);                        // h2 -> B3
    // 9. encoder_proj
    y_init_kernel<<<CEILDIV(NN*104,256), 256, 0, stream>>>(ybuf, ep_b);
    ep_mf<<<dim3(CEILDIV(NN,64), 2, CEILDIV(TT,8)), 256, 0, stream>>>(B3, wept, ybuf);
    // 10. residual MLP blocks
    for (int i = 0; i < 3; ++i)
        enc_kernel<<<NN, 256, 0, stream>>>(ybuf, enc_w1 + (size_t)i*104*208, enc_b1 + (size_t)i*208,
                                           enc_w2 + (size_t)i*208*104, enc_b2 + (size_t)i*104);
    // 11. output projection
    out_kernel<<<NN, 256, 0, stream>>>(ybuf, out_w, out_b, (float*)d_out);
}

// Round 8
// 2413.908 us; speedup vs baseline: 2.4201x; 1.0215x over previous
//
#include <hip/hip_runtime.h>
#include <hip/hip_bf16.h>
#include <cstddef>

// ---------------- problem constants ----------------
#define TT   365
#define NN   400
#define TN   (TT*NN)            // 146000
#define HD   26                 // head dim
#define NH   4                  // heads

#define CEILDIV(a,b) (((a)+(b)-1)/(b))

typedef __hip_bfloat16 bf16;
typedef short short8v __attribute__((ext_vector_type(8)));
typedef float float4v __attribute__((ext_vector_type(4)));
__device__ __forceinline__ float b2f(bf16 v){ return __bfloat162float(v); }
__device__ __forceinline__ bf16  f2b(float v){ return __float2bfloat16(v); }

// ---------------- workspace layout ----------------
static constexpr size_t NB0 = (size_t)TN*104;   // h / h1
static constexpr size_t NB1 = (size_t)TN*104;   // z1 -> att1 -> m
static constexpr size_t NB2 = (size_t)TN*312;   // hcat -> [adp_bf|hT] -> qkv+concat -> p0|p1 -> hidden
static constexpr size_t NB3 = (size_t)TN*104;   // att0 -> h2
static constexpr size_t NBF = NB0+NB1+NB2+NB3;
static constexpr size_t NKVS_S  = (size_t)TT*NH*HD*HD;
static constexpr size_t NKSUM_S = (size_t)TT*NH*HD;
static constexpr size_t NKVS_T  = (size_t)NN*NH*HD*HD;
static constexpr size_t NKSUM_T = (size_t)NN*NH*HD;
static constexpr size_t NY      = (size_t)NN*104;
static constexpr size_t NAUX    = NKVS_S+NKSUM_S+NKVS_T+NKSUM_T+NY;
// transposed bf16 weights (Wt[n][kp], zero-padded k)
static constexpr size_t NW_TP   = 104*128;
static constexpr size_t NW_QKV  = 312*128;   // x2
static constexpr size_t NW_OP   = 104*224;   // x2
static constexpr size_t NW_PW   = 104*128;   // x2
static constexpr size_t NW_FC1  = 208*128;
static constexpr size_t NW_FC2  = 104*224;
static constexpr size_t NW_EPT  = (size_t)104*37960;   // ep_w transposed, no pad
static constexpr size_t NWT     = NW_TP + 2*NW_QKV + 2*NW_OP + 2*NW_PW + NW_FC1 + NW_FC2 + NW_EPT;
static constexpr size_t WS_NEEDED = NBF*2 + NAUX*4 + NWT*2;
// z1 scratch lives inside B2 (dead between step 2 and step 4):
static constexpr size_t NADP_ROWS = (size_t)TN + 64;           // padded rows (last tile OOB-safe)
static constexpr size_t NADP = NADP_ROWS*96;                   // adp in bf16, width padded to 96
static constexpr size_t NHT  = ((size_t)TT*104 + 8)*448;       // h transposed, width padded to 448, +8 pad rows
static_assert(NADP + NHT <= NB2, "z1 scratch must fit in B2");

// ---------------- weight prep: Wt[n*KP+k] = bf16(W[k*Nc+n]), zero pad k>=K ----------------
__global__ void __launch_bounds__(256) prep_w(
    const float* __restrict__ W, bf16* __restrict__ Wt, int K, int Nc, int KP)
{
    int idx = blockIdx.x*256 + threadIdx.x;
    if (idx >= Nc*KP) return;
    int n = idx / KP, k = idx - n*KP;
    Wt[idx] = (k < K) ? f2b(W[(size_t)k*Nc + n]) : f2b(0.f);
}

// adp_bf[row][e] = bf16(adp[row][e]) for e<80 else 0; rows >= TN are zero.
__global__ void __launch_bounds__(256) prep_adp(
    const float* __restrict__ adp, bf16* __restrict__ out)
{
    size_t i = (size_t)blockIdx.x*256 + threadIdx.x;
    if (i >= NADP) return;
    size_t row = i / 96; int e = (int)(i - row*96);
    float v = (row < TN && e < 80) ? adp[row*80 + e] : 0.f;
    out[i] = f2b(v);
}

// hT[t][d][n] = h[t][n][d], n padded to 448 with zeros (LDS transpose, coalesced both ways)
__global__ void __launch_bounds__(256) ht_kernel(
    const bf16* __restrict__ h, bf16* __restrict__ hT)
{
    __shared__ bf16 As[64*106];
    int t = blockIdx.y, n0 = blockIdx.x*64;
    int tid = threadIdx.x;
    for (int idx = tid; idx < 64*52; idx += 256) {
        int r = idx / 52, k = idx - r*52;
        int n = n0 + r;
        uint v = 0;
        if (n < NN) v = *(const uint*)(h + ((size_t)t*NN + n)*104 + k*2);
        *(uint*)(&As[r*106 + k*2]) = v;
    }
    __syncthreads();
    for (int idx = tid; idx < 104*32; idx += 256) {
        int d = idx >> 5, np = idx & 31;
        int n = np*2;
        ushort lo = *(ushort*)&As[n*106 + d];
        ushort hi = *(ushort*)&As[(n+1)*106 + d];
        uint v = ((uint)hi << 16) | lo;
        *(uint*)(hT + ((size_t)t*104 + d)*448 + n0 + n) = v;
    }
}

// ---------------- hcat ----------------
__global__ void __launch_bounds__(128) hcat_kernel(
    const float* __restrict__ x, const float* __restrict__ W_in,
    const float* __restrict__ b_in, const float* __restrict__ adp,
    bf16* __restrict__ hcat)
{
    int bid = blockIdx.x;            // t*400 + n
    int t = bid / NN, n = bid - t*NN;
    int tid = threadIdx.x;
    if (tid < 24) {
        float s = b_in[tid];
        size_t xb = ((size_t)n*TT + t)*3;
        #pragma unroll
        for (int i = 0; i < 3; ++i) s += x[xb + i] * W_in[i*24 + tid];
        hcat[(size_t)bid*104 + tid] = f2b(s);
    } else if (tid < 104) {
        hcat[(size_t)bid*104 + tid] = f2b(adp[(size_t)bid*80 + (tid - 24)]);
    }
}

// ---------------- MFMA GEMM: C[M,Nc] = A[M,K](lda,bf16) @ W + bias ----------------
template<int KP>
__global__ void __launch_bounds__(256) gemm_mf(
    const bf16* __restrict__ A, int lda, int K,
    const bf16* __restrict__ Wt, const float* __restrict__ bias,
    bf16* __restrict__ C, int M, int Nc, int relu)
{
    constexpr int STR = KP + 8;          // bf16 elems; +8 keeps b128 reads 2-way (free)
    __shared__ bf16 As[64*STR];
    __shared__ bf16 Ws[64*STR];
    int m0 = blockIdx.x * 64;
    int c0 = blockIdx.y * 64;
    int tid = threadIdx.x;
    const int KW = KP/2;                 // uints per row
    for (int idx = tid; idx < 64*KW; idx += 256) {
        int r = idx / KW, kw = idx - r*KW;
        int m = m0 + r, k = kw*2;
        uint v = 0;
        if (m < M && k < K) v = *(const uint*)(A + (size_t)m*lda + k);
        *(uint*)(&As[r*STR + k]) = v;
    }
    for (int idx = tid; idx < 64*KW; idx += 256) {
        int r = idx / KW, kw = idx - r*KW;
        int n = c0 + r, k = kw*2;
        uint v = 0;
        if (n < Nc) v = *(const uint*)(Wt + (size_t)n*KP + k);
        *(uint*)(&Ws[r*STR + k]) = v;
    }
    __syncthreads();

    int lane = tid & 63, w = tid >> 6;
    int n16 = lane & 15, quad = lane >> 4;
    constexpr int KS = KP/32;
    short8v af[KS];
    #pragma unroll
    for (int s = 0; s < KS; ++s)
        af[s] = *(const short8v*)(&As[(16*w + n16)*STR + s*32 + quad*8]);
    float4v acc[4];
    #pragma unroll
    for (int ct = 0; ct < 4; ++ct) { float4v z = {0.f,0.f,0.f,0.f}; acc[ct] = z; }
    #pragma unroll
    for (int ct = 0; ct < 4; ++ct) {
        #pragma unroll
        for (int s = 0; s < KS; ++s) {
            short8v bfr = *(const short8v*)(&Ws[(ct*16 + n16)*STR + s*32 + quad*8]);
            acc[ct] = __builtin_amdgcn_mfma_f32_16x16x32_bf16(af[s], bfr, acc[ct], 0, 0, 0);
        }
    }
    #pragma unroll
    for (int ct = 0; ct < 4; ++ct) {
        int c = c0 + ct*16 + n16;
        if (c < Nc) {
            float b = bias ? bias[c] : 0.f;
            #pragma unroll
            for (int reg = 0; reg < 4; ++reg) {
                int m = m0 + 16*w + quad*4 + reg;
                if (m < M) {
                    float v = acc[ct][reg] + b;
                    if (relu) v = fmaxf(v, 0.f);
                    C[(size_t)m*Nc + c] = f2b(v);
                }
            }
        }
    }
}

// ---------------- MFMA encoder_proj: y[400,104] += sum_t h2[t] @ ep_w[t] ----------------
__global__ void __launch_bounds__(256) ep_mf(
    const bf16* __restrict__ h2, const bf16* __restrict__ wt, float* __restrict__ y)
{
    constexpr int STR = 136;             // 128 padded K + 8
    __shared__ bf16 As[64*STR];
    __shared__ bf16 Ws[64*STR];
    int m0 = blockIdx.x * 64;
    int c0 = blockIdx.y * 64;
    int t0 = blockIdx.z * 8;
    int t1 = min(TT, t0 + 8);
    int tid = threadIdx.x;
    int lane = tid & 63, w = tid >> 6, n16 = lane & 15, quad = lane >> 4;

    float4v acc[4];
    #pragma unroll
    for (int ct = 0; ct < 4; ++ct) { float4v z = {0.f,0.f,0.f,0.f}; acc[ct] = z; }

    for (int t = t0; t < t1; ++t) {
        for (int idx = tid; idx < 64*64; idx += 256) {     // 64 rows x 64 uints
            int r = idx >> 6, k = (idx & 63)*2;
            int m = m0 + r;
            uint va = 0;
            if (m < NN && k < 104) va = *(const uint*)(h2 + ((size_t)t*NN + m)*104 + k);
            *(uint*)(&As[r*STR + k]) = va;
            int c = c0 + r;
            uint vw = 0;
            if (c < 104 && k < 104) vw = *(const uint*)(wt + (size_t)c*37960 + t*104 + k);
            *(uint*)(&Ws[r*STR + k]) = vw;
        }
        __syncthreads();
        short8v af[4];
        #pragma unroll
        for (int s = 0; s < 4; ++s)
            af[s] = *(const short8v*)(&As[(16*w + n16)*STR + s*32 + quad*8]);
        #pragma unroll
        for (int ct = 0; ct < 4; ++ct) {
            #pragma unroll
            for (int s = 0; s < 4; ++s) {
                short8v bfr = *(const short8v*)(&Ws[(ct*16 + n16)*STR + s*32 + quad*8]);
                acc[ct] = __builtin_amdgcn_mfma_f32_16x16x32_bf16(af[s], bfr, acc[ct], 0, 0, 0);
            }
        }
        __syncthreads();
    }
    #pragma unroll
    for (int ct = 0; ct < 4; ++ct) {
        int c = c0 + ct*16 + n16;
        if (c < 104) {
            #pragma unroll
            for (int reg = 0; reg < 4; ++reg) {
                int m = m0 + 16*w + quad*4 + reg;
                if (m < NN) atomicAdd(&y[(size_t)m*104 + c], acc[ct][reg]);
            }
        }
    }
}

// ---------------- MFMA z1 (v2): z1[t] = softmax(relu(adp adp^T)) @ h[t] ----------------
__global__ void __launch_bounds__(256) z1_mf(
    const bf16* __restrict__ adp_bf, const bf16* __restrict__ hT, bf16* __restrict__ z1)
{
    constexpr int SA = 104;   // 96 + 8
    constexpr int SP = 72;    // 64 + 8
    __shared__ bf16 As[64*SA];
    __shared__ bf16 Bt[64*SA];
    __shared__ bf16 Ht[112*SP];
    __shared__ bf16 P[64*SP];
    int t = blockIdx.y;
    int r0 = blockIdx.x * 64;
    int tid = threadIdx.x;
    int lane = tid & 63, w = tid >> 6, n16 = lane & 15, quad = lane >> 4;

    {   // stage As: 64 rows x 96 bf16 = 64 x 12 uint4  (uint4 = 8 bf16)
        const uint4* src = (const uint4*)(adp_bf + ((size_t)t*NN + r0)*96);
        for (int idx = tid; idx < 768; idx += 256) {
            int r = idx / 12, q = idx - r*12;
            *(uint4*)(&As[r*SA + q*8]) = src[idx];
        }
    }
    __syncthreads();
    short8v af[3];
    #pragma unroll
    for (int s = 0; s < 3; ++s)
        af[s] = *(const short8v*)(&As[(16*w + n16)*SA + s*32 + quad*8]);

    float4v onum[7];
    #pragma unroll
    for (int dt = 0; dt < 7; ++dt) { float4v z = {0.f,0.f,0.f,0.f}; onum[dt] = z; }
    float rs[4] = {0.f,0.f,0.f,0.f};

    for (int c0 = 0; c0 < NN; c0 += 64) {
        {   // stage Bt: 64 rows x 12 uint4 (padded buffer -> branch-free)
            const uint4* srcB = (const uint4*)(adp_bf + ((size_t)t*NN + c0)*96);
            for (int idx = tid; idx < 768; idx += 256) {
                int r = idx / 12, q = idx - r*12;
                *(uint4*)(&Bt[r*SA + q*8]) = srcB[idx];
            }
        }
        {   // stage Ht: 112 rows x 8 uint4 (64 cols) from hT (rows >=104 garbage, masked later)
            const bf16* hb = hT + (size_t)t*104*448 + c0;
            for (int idx = tid; idx < 896; idx += 256) {
                int d = idx >> 3, q = idx & 7;
                *(uint4*)(&Ht[d*SP + q*8]) = *(const uint4*)(hb + (size_t)d*448 + q*8);
            }
        }
        __syncthreads();
        float4v sc[4];
        #pragma unroll
        for (int ct = 0; ct < 4; ++ct) { float4v z = {0.f,0.f,0.f,0.f}; sc[ct] = z; }
        #pragma unroll
        for (int ct = 0; ct < 4; ++ct) {
            #pragma unroll
            for (int s = 0; s < 3; ++s) {
                short8v bfr = *(const short8v*)(&Bt[(ct*16 + n16)*SA + s*32 + quad*8]);
                sc[ct] = __builtin_amdgcn_mfma_f32_16x16x32_bf16(af[s], bfr, sc[ct], 0, 0, 0);
            }
        }
        // exp + mask OOB cols + write P (own-wave rows) + rowsum
        #pragma unroll
        for (int ct = 0; ct < 4; ++ct) {
            bool colok = (c0 + ct*16 + n16) < NN;
            #pragma unroll
            for (int reg = 0; reg < 4; ++reg) {
                float e = colok ? __expf(fmaxf(sc[ct][reg], 0.f)) : 0.f;
                rs[reg] += e;
                P[(16*w + quad*4 + reg)*SP + ct*16 + n16] = f2b(e);
            }
        }
        short8v pf[2];
        #pragma unroll
        for (int s = 0; s < 2; ++s)
            pf[s] = *(const short8v*)(&P[(16*w + n16)*SP + s*32 + quad*8]);
        #pragma unroll
        for (int dt = 0; dt < 7; ++dt) {
            #pragma unroll
            for (int s = 0; s < 2; ++s) {
                short8v bfr = *(const short8v*)(&Ht[(dt*16 + n16)*SP + s*32 + quad*8]);
                onum[dt] = __builtin_amdgcn_mfma_f32_16x16x32_bf16(pf[s], bfr, onum[dt], 0, 0, 0);
            }
        }
        __syncthreads();
    }
    #pragma unroll
    for (int reg = 0; reg < 4; ++reg) {
        float v = rs[reg];
        v += __shfl_xor(v, 1, 64);
        v += __shfl_xor(v, 2, 64);
        v += __shfl_xor(v, 4, 64);
        v += __shfl_xor(v, 8, 64);
        rs[reg] = v;
    }
    #pragma unroll
    for (int reg = 0; reg < 4; ++reg) {
        int row = r0 + 16*w + quad*4 + reg;
        if (row < NN) {
            float inv = 1.f / rs[reg];
            #pragma unroll
            for (int dt = 0; dt < 7; ++dt) {
                int d = dt*16 + n16;
                if (d < 104)
                    z1[((size_t)t*NN + row)*104 + d] = f2b(onum[dt][reg] * inv);
            }
        }
    }
}

// ---------------- linear-attention KV summaries ----------------
__global__ void __launch_bounds__(256) kvs_kernel(
    const bf16* __restrict__ qkv, float* __restrict__ kvs, float* __restrict__ ksum,
    int L, long long strideB, long long strideL)
{
    int b = blockIdx.x, head = blockIdx.y;
    long long base = (long long)b*strideB + 104 + head*HD;   // k; v at +104
    __shared__ float kc[32][27], vc[32][27], inv[32];
    int tid = threadIdx.x;
    float acc[3] = {0.f,0.f,0.f};
    float ks = 0.f;
    for (int l0 = 0; l0 < L; l0 += 32) {
        int lw = min(32, L - l0);
        __syncthreads();
        for (int idx = tid; idx < lw*HD; idx += 256) {
            int ll = idx / HD, m = idx - ll*HD;
            long long a = base + (long long)(l0 + ll)*strideL + m;
            kc[ll][m] = b2f(qkv[a]);
            vc[ll][m] = b2f(qkv[a + 104]);
        }
        __syncthreads();
        if (tid < lw) {
            float ss = 0.f;
            #pragma unroll
            for (int m = 0; m < HD; ++m) { float v = kc[tid][m]; ss += v*v; }
            inv[tid] = 1.f / fmaxf(sqrtf(ss), 1e-12f);
        }
        __syncthreads();
        for (int idx = tid; idx < lw*HD; idx += 256) {
            int ll = idx / HD, m = idx - ll*HD;
            kc[ll][m] *= inv[ll];
        }
        __syncthreads();
        #pragma unroll
        for (int jj = 0; jj < 3; ++jj) {
            int p = tid + jj*256;
            if (p < HD*HD) {
                int m = p / HD, d = p - m*HD;
                float a = 0.f;
                for (int ll = 0; ll < lw; ++ll) a += kc[ll][m] * vc[ll][d];
                acc[jj] += a;
            }
        }
        if (tid < HD) {
            float a = 0.f;
            for (int ll = 0; ll < lw; ++ll) a += kc[ll][tid];
            ks += a;
        }
    }
    long long ob = ((long long)b*NH + head) * (HD*HD);
    #pragma unroll
    for (int jj = 0; jj < 3; ++jj) {
        int p = tid + jj*256;
        if (p < HD*HD) kvs[ob + p] = acc[jj];
    }
    if (tid < HD) ksum[((long long)b*NH + head)*HD + tid] = ks;
}

// ---------------- MFMA linear-attention apply ----------------
// out[m][c] = (iq*(q[m].KVblk[:,c]) + Lf*v[m][c]) / (iq*(q[m].ksum_h) + Lf),  h=c/26
// B-tile (112x128): cols 0..103 = block-diag kvs; cols 104..107 = ksum per head (-> den via MFMA).
// spatial: bb=t, rows n (rowStride=312);  temporal: bb=n, rows t (rowStride=400*312).
// Temporal must run FIRST (writes [104:208]=dead k slot; spatial overwrites q [0:104] after reading).
__global__ void __launch_bounds__(256) attn_mm(
    bf16* __restrict__ qkv, const float* __restrict__ kvs, const float* __restrict__ ksum,
    int M, long long bStride, long long rowStride, float Lf, int outOff)
{
    constexpr int STR = 136;
    __shared__ bf16 As[64*STR];
    __shared__ bf16 Ws[112*STR];
    __shared__ float nsqL[64*4];
    __shared__ float denL[64*4];
    int mt = blockIdx.x, bb = blockIdx.y;
    int tid = threadIdx.x;
    int lane = tid & 63, w = tid >> 6, n16 = lane & 15, quad = lane >> 4;
    bf16* base = qkv + (size_t)bb * bStride;
    const float* kv = kvs + (size_t)bb * (NH*HD*HD);
    const float* ks = ksum + (size_t)bb * (NH*HD);
    int r0 = mt*64;

    // stage A: 64 rows x 104 q-cols (bf16), zero-padded to 128
    for (int idx = tid; idx < 64*64; idx += 256) {
        int r = idx >> 6, kw = idx & 63;
        int m = r0 + r;
        uint v = 0;
        if (m < M && kw < 52) v = *(const uint*)(base + (size_t)m*rowStride + kw*2);
        *(uint*)(&As[r*STR + kw*2]) = v;
    }
    // stage Ws: 112 cols x 128 k (bf16)
    for (int idx = tid; idx < 112*64; idx += 256) {
        int c = idx >> 6, k0 = (idx & 63)*2;
        float v0 = 0.f, v1 = 0.f;
        if (c < 104) {
            int h = c / 26, d = c - h*26, lo = h*26;
            if (k0   >= lo && k0   < lo+26) v0 = kv[(h*HD + (k0-lo))*HD + d];
            if (k0+1 >= lo && k0+1 < lo+26) v1 = kv[(h*HD + (k0+1-lo))*HD + d];
        } else if (c < 108) {
            int h = c - 104, lo = h*26;
            if (k0   >= lo && k0   < lo+26) v0 = ks[h*HD + (k0-lo)];
            if (k0+1 >= lo && k0+1 < lo+26) v1 = ks[h*HD + (k0+1-lo)];
        }
        Ws[c*STR + k0]     = f2b(v0);
        Ws[c*STR + k0 + 1] = f2b(v1);
    }
    __syncthreads();

    short8v af[4];
    #pragma unroll
    for (int s = 0; s < 4; ++s)
        af[s] = *(const short8v*)(&As[(16*w + n16)*STR + s*32 + quad*8]);
    float4v acc[7];
    #pragma unroll
    for (int ct = 0; ct < 7; ++ct) { float4v z = {0.f,0.f,0.f,0.f}; acc[ct] = z; }
    #pragma unroll
    for (int ct = 0; ct < 7; ++ct) {
        #pragma unroll
        for (int s = 0; s < 4; ++s) {
            short8v bfr = *(const short8v*)(&Ws[(ct*16 + n16)*STR + s*32 + quad*8]);
            acc[ct] = __builtin_amdgcn_mfma_f32_16x16x32_bf16(af[s], bfr, acc[ct], 0, 0, 0);
        }
    }
    // per-(row,head) ||q||^2 from staged A
    {
        int row = tid >> 2, hh = tid & 3;
        const bf16* qr = &As[row*STR + hh*26];
        float ss = 0.f;
        #pragma unroll
        for (int m = 0; m < HD; ++m) { float v = b2f(qr[m]); ss += v*v; }
        nsqL[row*4 + hh] = ss;
    }
    // den_raw cols (104..107) -> LDS
    if (n16 >= 8 && n16 < 12) {
        #pragma unroll
        for (int reg = 0; reg < 4; ++reg)
            denL[(16*w + quad*4 + reg)*4 + (n16 - 8)] = acc[6][reg];
    }
    __syncthreads();
    // epilogue
    #pragma unroll
    for (int ct = 0; ct < 7; ++ct) {
        int c = ct*16 + n16;
        if (c < 104) {
            int hh = c / 26;
            #pragma unroll
            for (int reg = 0; reg < 4; ++reg) {
                int lr = 16*w + quad*4 + reg;
                int m = r0 + lr;
                if (m < M) {
                    float iq = 1.f / fmaxf(sqrtf(nsqL[lr*4 + hh]), 1e-12f);
                    float den = iq * denL[lr*4 + hh] + Lf;
                    bf16* rp = base + (size_t)m*rowStride;
                    float num = iq * acc[ct][reg] + Lf * b2f(rp[208 + c]);
                    rp[outOff + c] = f2b(num / den);
                }
            }
        }
    }
}

__device__ __forceinline__ float bsum128(float v, float* red, int tid) {
    #pragma unroll
    for (int off = 32; off > 0; off >>= 1) v += __shfl_down(v, off, 64);
    __syncthreads();
    if ((tid & 63) == 0) red[tid >> 6] = v;
    __syncthreads();
    return red[0] + red[1];
}

__global__ void __launch_bounds__(128) ln1_kernel(
    bf16* __restrict__ h, const bf16* __restrict__ att0, const bf16* __restrict__ att1,
    const bf16* __restrict__ p0, const bf16* __restrict__ p1,
    const float* __restrict__ gamma, const float* __restrict__ beta)
{
    int tid = threadIdx.x;
    size_t base = (size_t)blockIdx.x * 104;
    __shared__ float red[2];
    float x = 0.f;
    if (tid < 104) {
        float hv = b2f(h[base + tid]);
        x = 2.f * (hv + b2f(att0[base + tid])*b2f(p0[base + tid])
                      + 0.01f*b2f(att1[base + tid])*b2f(p1[base + tid]));
    }
    float mean = bsum128(x, red, tid) * (1.f/104.f);
    float dx = (tid < 104) ? (x - mean) : 0.f;
    float var = bsum128(dx*dx, red, tid) * (1.f/104.f);
    if (tid < 104)
        h[base + tid] = f2b(dx * rsqrtf(var + 1e-5f) * gamma[tid] + beta[tid]);
}

__global__ void __launch_bounds__(128) ln2_kernel(
    const bf16* __restrict__ h1, const bf16* __restrict__ m,
    const float* __restrict__ gamma, const float* __restrict__ beta,
    bf16* __restrict__ h2)
{
    int tid = threadIdx.x;
    size_t base = (size_t)blockIdx.x * 104;
    __shared__ float red[2];
    float x = 0.f;
    if (tid < 104) x = b2f(h1[base + tid]) + b2f(m[base + tid]);
    float mean = bsum128(x, red, tid) * (1.f/104.f);
    float dx = (tid < 104) ? (x - mean) : 0.f;
    float var = bsum128(dx*dx, red, tid) * (1.f/104.f);
    if (tid < 104)
        h2[base + tid] = f2b(dx * rsqrtf(var + 1e-5f) * gamma[tid] + beta[tid]);
}

__global__ void __launch_bounds__(256) y_init_kernel(float* __restrict__ y, const float* __restrict__ ep_b) {
    int i = blockIdx.x*256 + threadIdx.x;
    if (i < NN*104) y[i] = ep_b[i % 104];
}

__global__ void __launch_bounds__(256) enc_kernel(
    float* __restrict__ y, const float* __restrict__ w1, const float* __restrict__ b1,
    const float* __restrict__ w2, const float* __restrict__ b2)
{
    int n = blockIdx.x;
    int tid = threadIdx.x;
    __shared__ float yr[104], hid[208];
    if (tid < 104) yr[tid] = y[(size_t)n*104 + tid];
    __syncthreads();
    if (tid < 208) {
        float s = b1[tid];
        for (int k = 0; k < 104; ++k) s += yr[k] * w1[(size_t)k*208 + tid];
        hid[tid] = fmaxf(s, 0.f);
    }
    __syncthreads();
    if (tid < 104) {
        float s = b2[tid];
        for (int k = 0; k < 208; ++k) s += hid[k] * w2[(size_t)k*104 + tid];
        y[(size_t)n*104 + tid] = yr[tid] + s;
    }
}

__global__ void __launch_bounds__(256) out_kernel(
    const float* __restrict__ y, const float* __restrict__ out_w,
    const float* __restrict__ out_b, float* __restrict__ out)
{
    int n = blockIdx.x;
    int tid = threadIdx.x;
    __shared__ float yr[104];
    if (tid < 104) yr[tid] = y[(size_t)n*104 + tid];
    __syncthreads();
    for (int t = tid; t < TT; t += 256) {
        float s = out_b[t];
        for (int d = 0; d < 104; ++d) s += yr[d] * out_w[(size_t)d*TT + t];
        out[(size_t)n*TT + t] = s;
    }
}

// ---------------- launch ----------------
extern "C" void kernel_launch(void* const* d_in, const int* in_sizes, int n_in,
                              void* d_out, int out_size, void* d_ws, size_t ws_size,
                              hipStream_t stream) {
    if (ws_size < WS_NEEDED) return;   // readable failure instead of page fault

    const float* x      = (const float*)d_in[0];
    const float* W_in   = (const float*)d_in[1];
    const float* b_in   = (const float*)d_in[2];
    const float* adp    = (const float*)d_in[3];
    const float* W_tp   = (const float*)d_in[4];
    const float* b_tp   = (const float*)d_in[5];
    const float* qkv_w  = (const float*)d_in[6];
    const float* op_w   = (const float*)d_in[7];
    const float* op_b   = (const float*)d_in[8];
    const float* pw_w   = (const float*)d_in[9];
    const float* pw_b   = (const float*)d_in[10];
    const float* fc_w1  = (const float*)d_in[11];
    const float* fc_b1  = (const float*)d_in[12];
    const float* fc_w2  = (const float*)d_in[13];
    const float* fc_b2  = (const float*)d_in[14];
    const float* ln1_g  = (const float*)d_in[15];
    const float* ln1_b  = (const float*)d_in[16];
    const float* ln2_g  = (const float*)d_in[17];
    const float* ln2_b  = (const float*)d_in[18];
    const float* ep_w   = (const float*)d_in[19];
    const float* ep_b   = (const float*)d_in[20];
    const float* enc_w1 = (const float*)d_in[21];
    const float* enc_b1 = (const float*)d_in[22];
    const float* enc_w2 = (const float*)d_in[23];
    const float* enc_b2 = (const float*)d_in[24];
    const float* out_w  = (const float*)d_in[25];
    const float* out_b  = (const float*)d_in[26];

    bf16* B0 = (bf16*)d_ws;
    bf16* B1 = B0 + NB0;
    bf16* B2 = B1 + NB1;
    bf16* B3 = B2 + NB2;
    float* kvs_s  = (float*)(B3 + NB3);
    float* ksum_s = kvs_s + NKVS_S;
    float* kvs_t  = ksum_s + NKSUM_S;
    float* ksum_t = kvs_t + NKVS_T;
    float* ybuf   = ksum_t + NKSUM_T;
    bf16* wtp   = (bf16*)(ybuf + NY);
    bf16* wqkv0 = wtp + NW_TP;
    bf16* wqkv1 = wqkv0 + NW_QKV;
    bf16* wop0  = wqkv1 + NW_QKV;
    bf16* wop1  = wop0 + NW_OP;
    bf16* wpw0  = wop1 + NW_OP;
    bf16* wpw1  = wpw0 + NW_PW;
    bf16* wfc1  = wpw1 + NW_PW;
    bf16* wfc2  = wfc1 + NW_FC1;
    bf16* wept  = wfc2 + NW_FC2;
    // z1 scratch aliases B2 (dead between step 2 and step 4)
    bf16* adp_bf = B2;
    bf16* hTbuf  = B2 + NADP;

    // 0. weight prep (tiny)
    prep_w<<<CEILDIV(104*128,256), 256, 0, stream>>>(W_tp, wtp, 104, 104, 128);
    prep_w<<<CEILDIV(312*128,256), 256, 0, stream>>>(qkv_w, wqkv0, 104, 312, 128);
    prep_w<<<CEILDIV(312*128,256), 256, 0, stream>>>(qkv_w + 104*312, wqkv1, 104, 312, 128);
    prep_w<<<CEILDIV(104*224,256), 256, 0, stream>>>(op_w, wop0, 208, 104, 224);
    prep_w<<<CEILDIV(104*224,256), 256, 0, stream>>>(op_w + 208*104, wop1, 208, 104, 224);
    prep_w<<<CEILDIV(104*128,256), 256, 0, stream>>>(pw_w, wpw0, 104, 104, 128);
    prep_w<<<CEILDIV(104*128,256), 256, 0, stream>>>(pw_w + 104*104, wpw1, 104, 104, 128);
    prep_w<<<CEILDIV(208*128,256), 256, 0, stream>>>(fc_w1, wfc1, 104, 208, 128);
    prep_w<<<CEILDIV(104*224,256), 256, 0, stream>>>(fc_w2, wfc2, 208, 104, 224);
    prep_w<<<CEILDIV(104*37960,256), 256, 0, stream>>>(ep_w, wept, 37960, 104, 37960);

    const int GX = CEILDIV(TN, 64);     // 2282
    dim3 g2(GX, 2), g4(GX, 4), g5(GX, 5);

    // 1. hcat -> B2
    hcat_kernel<<<TN, 128, 0, stream>>>(x, W_in, b_in, adp, B2);
    // 2. h = hcat @ W_tp + b_tp -> B0  (hcat dead afterwards)
    gemm_mf<128><<<g2, 256, 0, stream>>>(B2, 104, 104, wtp, b_tp, B0, TN, 104, 0);
    // 2b. z1 pre-staging into B2: adp -> bf16 padded; h -> hT
    prep_adp<<<CEILDIV((int)NADP,256), 256, 0, stream>>>(adp, adp_bf);
    ht_kernel<<<dim3(7, TT), 256, 0, stream>>>(B0, hTbuf);
    // 3. z1 -> B1
    z1_mf<<<dim3(7, TT), 256, 0, stream>>>(adp_bf, hTbuf, B1);
    // 4. attention 0 on h
    gemm_mf<128><<<g5, 256, 0, stream>>>(B0, 104, 104, wqkv0, nullptr, B2, TN, 312, 0);
    kvs_kernel<<<dim3(TT, NH), 256, 0, stream>>>(B2, kvs_s, ksum_s, NN, (long long)NN*312, 312);
    kvs_kernel<<<dim3(NN, NH), 256, 0, stream>>>(B2, kvs_t, ksum_t, TT, 312, (long long)NN*312);
    attn_mm<<<dim3(6, NN), 256, 0, stream>>>(B2, kvs_t, ksum_t, TT, 312, (long long)NN*312, (float)TT, 104);
    attn_mm<<<dim3(7, TT), 256, 0, stream>>>(B2, kvs_s, ksum_s, NN, (long long)NN*312, 312, (float)NN, 0);
    gemm_mf<224><<<g2, 256, 0, stream>>>(B2, 312, 208, wop0, op_b, B3, TN, 104, 0);      // att0 -> B3
    // 5. attention 1 on z1
    gemm_mf<128><<<g5, 256, 0, stream>>>(B1, 104, 104, wqkv1, nullptr, B2, TN, 312, 0);
    kvs_kernel<<<dim3(TT, NH), 256, 0, stream>>>(B2, kvs_s, ksum_s, NN, (long long)NN*312, 312);
    kvs_kernel<<<dim3(NN, NH), 256, 0, stream>>>(B2, kvs_t, ksum_t, TT, 312, (long long)NN*312);
    attn_mm<<<dim3(6, NN), 256, 0, stream>>>(B2, kvs_t, ksum_t, TT, 312, (long long)NN*312, (float)TT, 104);
    attn_mm<<<dim3(7, TT), 256, 0, stream>>>(B2, kvs_s, ksum_s, NN, (long long)NN*312, 312, (float)NN, 0);
    gemm_mf<224><<<g2, 256, 0, stream>>>(B2, 312, 208, wop1, op_b + 104, B1, TN, 104, 0); // att1 -> B1
    // 6. pointwise gates -> B2
    gemm_mf<128><<<g2, 256, 0, stream>>>(B0, 104, 104, wpw0, pw_b, B2, TN, 104, 0);
    gemm_mf<128><<<g2, 256, 0, stream>>>(B3, 104, 104, wpw1, pw_b + 104, B2 + (size_t)TN*104, TN, 104, 0);
    // 7. LN1 in-place (B0 -> h1)
    ln1_kernel<<<TN, 128, 0, stream>>>(B0, B3, B1, B2, B2 + (size_t)TN*104, ln1_g, ln1_b);
    // 8. MLP + LN2
    gemm_mf<128><<<g4, 256, 0, stream>>>(B0, 104, 104, wfc1, fc_b1, B2, TN, 208, 1);
    gemm_mf<224><<<g2, 256, 0, stream>>>(B2, 208, 208, wfc2, fc_b2, B1, TN, 104, 0);
    ln2_kernel<<<TN, 128, 0, stream>>>(B0, B1, ln2_g, ln2_b, B3);                        // h2 -> B3
    // 9. encoder_proj
    y_init_kernel<<<CEILDIV(NN*104,256), 256, 0, stream>>>(ybuf, ep_b);
    ep_mf<<<dim3(CEILDIV(NN,64), 2, CEILDIV(TT,8)), 256, 0, stream>>>(B3, wept, ybuf);
    // 10. residual MLP blocks
    for (int i = 0; i < 3; ++i)
        enc_kernel<<<NN, 256, 0, stream>>>(ybuf, enc_w1 + (size_t)i*104*208, enc_b1 + (size_t)i*208,
                                           enc_w2 + (size_t)i*208*104, enc_b2 + (size_t)i*104);
    // 11. output projection
    out_kernel<<<NN, 256, 0, stream>>>(ybuf, out_w, out_b, (float*)d_out);
}

// Round 9
// 1675.683 us; speedup vs baseline: 3.4863x; 1.4406x over previous
//
#include <hip/hip_runtime.h>
#include <hip/hip_bf16.h>
#include <cstddef>

// ---------------- problem constants ----------------
#define TT   365
#define NN   400
#define TN   (TT*NN)            // 146000
#define HD   26                 // head dim
#define NH   4                  // heads

#define CEILDIV(a,b) (((a)+(b)-1)/(b))

typedef __hip_bfloat16 bf16;
typedef short short8v __attribute__((ext_vector_type(8)));
typedef float float4v __attribute__((ext_vector_type(4)));
__device__ __forceinline__ float b2f(bf16 v){ return __bfloat162float(v); }
__device__ __forceinline__ bf16  f2b(float v){ return __float2bfloat16(v); }

// ---------------- workspace layout ----------------
static constexpr size_t NB0 = (size_t)TN*104;   // h / h1
static constexpr size_t NB1 = (size_t)TN*104;   // z1 -> att1 -> m
static constexpr size_t NB2 = (size_t)TN*312;   // hcat -> [adp_bf|hT] -> qkv+concat -> p0|p1 -> hidden
static constexpr size_t NB3 = (size_t)TN*104;   // att0 -> h2
static constexpr size_t NBF = NB0+NB1+NB2+NB3;
// compact band KV tiles: per b, 108 rows x 32 (band cols 0..25 = k-lo), bf16
static constexpr size_t NTILE   = (size_t)108*32;
static constexpr size_t NKVSB_S = (size_t)TT*NTILE;
static constexpr size_t NKVSB_T = (size_t)NN*NTILE;
static constexpr size_t NY      = (size_t)NN*104;
// transposed bf16 weights (Wt[n][kp], zero-padded k)
static constexpr size_t NW_TP   = 104*128;
static constexpr size_t NW_QKV  = 312*128;   // x2
static constexpr size_t NW_OP   = 104*224;   // x2
static constexpr size_t NW_PW   = 104*128;   // x2
static constexpr size_t NW_FC1  = 208*128;
static constexpr size_t NW_FC2  = 104*224;
static constexpr size_t NW_EPT  = (size_t)104*37960;   // ep_w transposed, no pad
static constexpr size_t NWT     = NW_TP + 2*NW_QKV + 2*NW_OP + 2*NW_PW + NW_FC1 + NW_FC2 + NW_EPT;
static constexpr size_t WS_NEEDED = NBF*2 + (NKVSB_S+NKVSB_T)*2 + NY*4 + NWT*2;
// z1 scratch lives inside B2 (dead between step 2 and step 4):
static constexpr size_t NADP_ROWS = (size_t)TN + 64;           // padded rows (last tile OOB-safe)
static constexpr size_t NADP = NADP_ROWS*96;                   // adp in bf16, width padded to 96
static constexpr size_t NHT  = ((size_t)TT*104 + 8)*448;       // h transposed, width padded to 448, +8 pad rows
static_assert(NADP + NHT <= NB2, "z1 scratch must fit in B2");

// ---------------- weight prep: Wt[n*KP+k] = bf16(W[k*Nc+n]), zero pad k>=K ----------------
__global__ void __launch_bounds__(256) prep_w(
    const float* __restrict__ W, bf16* __restrict__ Wt, int K, int Nc, int KP)
{
    int idx = blockIdx.x*256 + threadIdx.x;
    if (idx >= Nc*KP) return;
    int n = idx / KP, k = idx - n*KP;
    Wt[idx] = (k < K) ? f2b(W[(size_t)k*Nc + n]) : f2b(0.f);
}

// adp_bf[row][e] = bf16(adp[row][e]) for e<80 else 0; rows >= TN are zero.
__global__ void __launch_bounds__(256) prep_adp(
    const float* __restrict__ adp, bf16* __restrict__ out)
{
    size_t i = (size_t)blockIdx.x*256 + threadIdx.x;
    if (i >= NADP) return;
    size_t row = i / 96; int e = (int)(i - row*96);
    float v = (row < TN && e < 80) ? adp[row*80 + e] : 0.f;
    out[i] = f2b(v);
}

// hT[t][d][n] = h[t][n][d], n padded to 448 with zeros (LDS transpose, coalesced both ways)
__global__ void __launch_bounds__(256) ht_kernel(
    const bf16* __restrict__ h, bf16* __restrict__ hT)
{
    __shared__ bf16 As[64*106];
    int t = blockIdx.y, n0 = blockIdx.x*64;
    int tid = threadIdx.x;
    for (int idx = tid; idx < 64*52; idx += 256) {
        int r = idx / 52, k = idx - r*52;
        int n = n0 + r;
        uint v = 0;
        if (n < NN) v = *(const uint*)(h + ((size_t)t*NN + n)*104 + k*2);
        *(uint*)(&As[r*106 + k*2]) = v;
    }
    __syncthreads();
    for (int idx = tid; idx < 104*32; idx += 256) {
        int d = idx >> 5, np = idx & 31;
        int n = np*2;
        ushort lo = *(ushort*)&As[n*106 + d];
        ushort hi = *(ushort*)&As[(n+1)*106 + d];
        uint v = ((uint)hi << 16) | lo;
        *(uint*)(hT + ((size_t)t*104 + d)*448 + n0 + n) = v;
    }
}

// ---------------- hcat ----------------
__global__ void __launch_bounds__(128) hcat_kernel(
    const float* __restrict__ x, const float* __restrict__ W_in,
    const float* __restrict__ b_in, const float* __restrict__ adp,
    bf16* __restrict__ hcat)
{
    int bid = blockIdx.x;            // t*400 + n
    int t = bid / NN, n = bid - t*NN;
    int tid = threadIdx.x;
    if (tid < 24) {
        float s = b_in[tid];
        size_t xb = ((size_t)n*TT + t)*3;
        #pragma unroll
        for (int i = 0; i < 3; ++i) s += x[xb + i] * W_in[i*24 + tid];
        hcat[(size_t)bid*104 + tid] = f2b(s);
    } else if (tid < 104) {
        hcat[(size_t)bid*104 + tid] = f2b(adp[(size_t)bid*80 + (tid - 24)]);
    }
}

// ---------------- MFMA GEMM: C[M,Nc] = A[M,K](lda,bf16) @ W + bias ----------------
// uint4 (16B) staging; all row bases 16B-aligned (lda in {104,208,312}).
template<int KP>
__global__ void __launch_bounds__(256) gemm_mf(
    const bf16* __restrict__ A, int lda, int K,
    const bf16* __restrict__ Wt, const float* __restrict__ bias,
    bf16* __restrict__ C, int M, int Nc, int relu)
{
    constexpr int STR = KP + 8;          // bf16 elems; +8 keeps b128 reads 2-way (free)
    constexpr int KPQ = KP/8;            // uint4 per padded row
    __shared__ bf16 As[64*STR];
    __shared__ bf16 Ws[64*STR];
    int m0 = blockIdx.x * 64;
    int c0 = blockIdx.y * 64;
    int tid = threadIdx.x;
    const int KQ = K/8;                  // data uint4 per row (K % 8 == 0)
    uint4 z4 = {0u,0u,0u,0u};
    for (int idx = tid; idx < 64*KPQ; idx += 256) {
        int r = idx / KPQ, q = idx - r*KPQ;
        int m = m0 + r;
        uint4 v = z4;
        if (m < M && q < KQ) v = *(const uint4*)(A + (size_t)m*lda + q*8);
        *(uint4*)(&As[r*STR + q*8]) = v;
    }
    for (int idx = tid; idx < 64*KPQ; idx += 256) {
        int r = idx / KPQ, q = idx - r*KPQ;
        int n = c0 + r;
        uint4 v = z4;
        if (n < Nc) v = *(const uint4*)(Wt + (size_t)n*KP + q*8);
        *(uint4*)(&Ws[r*STR + q*8]) = v;
    }
    __syncthreads();

    int lane = tid & 63, w = tid >> 6;
    int n16 = lane & 15, quad = lane >> 4;
    constexpr int KS = KP/32;
    short8v af[KS];
    #pragma unroll
    for (int s = 0; s < KS; ++s)
        af[s] = *(const short8v*)(&As[(16*w + n16)*STR + s*32 + quad*8]);
    float4v acc[4];
    #pragma unroll
    for (int ct = 0; ct < 4; ++ct) { float4v z = {0.f,0.f,0.f,0.f}; acc[ct] = z; }
    #pragma unroll
    for (int ct = 0; ct < 4; ++ct) {
        #pragma unroll
        for (int s = 0; s < KS; ++s) {
            short8v bfr = *(const short8v*)(&Ws[(ct*16 + n16)*STR + s*32 + quad*8]);
            acc[ct] = __builtin_amdgcn_mfma_f32_16x16x32_bf16(af[s], bfr, acc[ct], 0, 0, 0);
        }
    }
    #pragma unroll
    for (int ct = 0; ct < 4; ++ct) {
        int c = c0 + ct*16 + n16;
        if (c < Nc) {
            float b = bias ? bias[c] : 0.f;
            #pragma unroll
            for (int reg = 0; reg < 4; ++reg) {
                int m = m0 + 16*w + quad*4 + reg;
                if (m < M) {
                    float v = acc[ct][reg] + b;
                    if (relu) v = fmaxf(v, 0.f);
                    C[(size_t)m*Nc + c] = f2b(v);
                }
            }
        }
    }
}

// ---------------- MFMA encoder_proj: y[400,104] += sum_t h2[t] @ ep_w[t] ----------------
__global__ void __launch_bounds__(256) ep_mf(
    const bf16* __restrict__ h2, const bf16* __restrict__ wt, float* __restrict__ y)
{
    constexpr int STR = 136;             // 128 padded K + 8
    __shared__ bf16 As[64*STR];
    __shared__ bf16 Ws[64*STR];
    int m0 = blockIdx.x * 64;
    int c0 = blockIdx.y * 64;
    int t0 = blockIdx.z * 8;
    int t1 = min(TT, t0 + 8);
    int tid = threadIdx.x;
    int lane = tid & 63, w = tid >> 6, n16 = lane & 15, quad = lane >> 4;
    uint4 z4 = {0u,0u,0u,0u};

    float4v acc[4];
    #pragma unroll
    for (int ct = 0; ct < 4; ++ct) { float4v z = {0.f,0.f,0.f,0.f}; acc[ct] = z; }

    for (int t = t0; t < t1; ++t) {
        for (int idx = tid; idx < 64*16; idx += 256) {     // 64 rows x 16 uint4
            int r = idx >> 4, q = idx & 15;
            int m = m0 + r;
            uint4 va = z4;
            if (m < NN && q < 13) va = *(const uint4*)(h2 + ((size_t)t*NN + m)*104 + q*8);
            *(uint4*)(&As[r*STR + q*8]) = va;
            int c = c0 + r;
            uint4 vw = z4;
            if (c < 104 && q < 13) vw = *(const uint4*)(wt + (size_t)c*37960 + t*104 + q*8);
            *(uint4*)(&Ws[r*STR + q*8]) = vw;
        }
        __syncthreads();
        short8v af[4];
        #pragma unroll
        for (int s = 0; s < 4; ++s)
            af[s] = *(const short8v*)(&As[(16*w + n16)*STR + s*32 + quad*8]);
        #pragma unroll
        for (int ct = 0; ct < 4; ++ct) {
            #pragma unroll
            for (int s = 0; s < 4; ++s) {
                short8v bfr = *(const short8v*)(&Ws[(ct*16 + n16)*STR + s*32 + quad*8]);
                acc[ct] = __builtin_amdgcn_mfma_f32_16x16x32_bf16(af[s], bfr, acc[ct], 0, 0, 0);
            }
        }
        __syncthreads();
    }
    #pragma unroll
    for (int ct = 0; ct < 4; ++ct) {
        int c = c0 + ct*16 + n16;
        if (c < 104) {
            #pragma unroll
            for (int reg = 0; reg < 4; ++reg) {
                int m = m0 + 16*w + quad*4 + reg;
                if (m < NN) atomicAdd(&y[(size_t)m*104 + c], acc[ct][reg]);
            }
        }
    }
}

// ---------------- MFMA z1 (v2): z1[t] = softmax(relu(adp adp^T)) @ h[t] ----------------
__global__ void __launch_bounds__(256) z1_mf(
    const bf16* __restrict__ adp_bf, const bf16* __restrict__ hT, bf16* __restrict__ z1)
{
    constexpr int SA = 104;   // 96 + 8
    constexpr int SP = 72;    // 64 + 8
    __shared__ bf16 As[64*SA];
    __shared__ bf16 Bt[64*SA];
    __shared__ bf16 Ht[112*SP];
    __shared__ bf16 P[64*SP];
    int t = blockIdx.y;
    int r0 = blockIdx.x * 64;
    int tid = threadIdx.x;
    int lane = tid & 63, w = tid >> 6, n16 = lane & 15, quad = lane >> 4;

    {   // stage As: 64 rows x 96 bf16 = 64 x 12 uint4  (uint4 = 8 bf16)
        const uint4* src = (const uint4*)(adp_bf + ((size_t)t*NN + r0)*96);
        for (int idx = tid; idx < 768; idx += 256) {
            int r = idx / 12, q = idx - r*12;
            *(uint4*)(&As[r*SA + q*8]) = src[idx];
        }
    }
    __syncthreads();
    short8v af[3];
    #pragma unroll
    for (int s = 0; s < 3; ++s)
        af[s] = *(const short8v*)(&As[(16*w + n16)*SA + s*32 + quad*8]);

    float4v onum[7];
    #pragma unroll
    for (int dt = 0; dt < 7; ++dt) { float4v z = {0.f,0.f,0.f,0.f}; onum[dt] = z; }
    float rs[4] = {0.f,0.f,0.f,0.f};

    for (int c0 = 0; c0 < NN; c0 += 64) {
        {   // stage Bt: 64 rows x 12 uint4 (padded buffer -> branch-free)
            const uint4* srcB = (const uint4*)(adp_bf + ((size_t)t*NN + c0)*96);
            for (int idx = tid; idx < 768; idx += 256) {
                int r = idx / 12, q = idx - r*12;
                *(uint4*)(&Bt[r*SA + q*8]) = srcB[idx];
            }
        }
        {   // stage Ht: 112 rows x 8 uint4 (64 cols) from hT (rows >=104 garbage, masked later)
            const bf16* hb = hT + (size_t)t*104*448 + c0;
            for (int idx = tid; idx < 896; idx += 256) {
                int d = idx >> 3, q = idx & 7;
                *(uint4*)(&Ht[d*SP + q*8]) = *(const uint4*)(hb + (size_t)d*448 + q*8);
            }
        }
        __syncthreads();
        float4v sc[4];
        #pragma unroll
        for (int ct = 0; ct < 4; ++ct) { float4v z = {0.f,0.f,0.f,0.f}; sc[ct] = z; }
        #pragma unroll
        for (int ct = 0; ct < 4; ++ct) {
            #pragma unroll
            for (int s = 0; s < 3; ++s) {
                short8v bfr = *(const short8v*)(&Bt[(ct*16 + n16)*SA + s*32 + quad*8]);
                sc[ct] = __builtin_amdgcn_mfma_f32_16x16x32_bf16(af[s], bfr, sc[ct], 0, 0, 0);
            }
        }
        // exp + mask OOB cols + write P (own-wave rows) + rowsum
        #pragma unroll
        for (int ct = 0; ct < 4; ++ct) {
            bool colok = (c0 + ct*16 + n16) < NN;
            #pragma unroll
            for (int reg = 0; reg < 4; ++reg) {
                float e = colok ? __expf(fmaxf(sc[ct][reg], 0.f)) : 0.f;
                rs[reg] += e;
                P[(16*w + quad*4 + reg)*SP + ct*16 + n16] = f2b(e);
            }
        }
        short8v pf[2];
        #pragma unroll
        for (int s = 0; s < 2; ++s)
            pf[s] = *(const short8v*)(&P[(16*w + n16)*SP + s*32 + quad*8]);
        #pragma unroll
        for (int dt = 0; dt < 7; ++dt) {
            #pragma unroll
            for (int s = 0; s < 2; ++s) {
                short8v bfr = *(const short8v*)(&Ht[(dt*16 + n16)*SP + s*32 + quad*8]);
                onum[dt] = __builtin_amdgcn_mfma_f32_16x16x32_bf16(pf[s], bfr, onum[dt], 0, 0, 0);
            }
        }
        __syncthreads();
    }
    #pragma unroll
    for (int reg = 0; reg < 4; ++reg) {
        float v = rs[reg];
        v += __shfl_xor(v, 1, 64);
        v += __shfl_xor(v, 2, 64);
        v += __shfl_xor(v, 4, 64);
        v += __shfl_xor(v, 8, 64);
        rs[reg] = v;
    }
    #pragma unroll
    for (int reg = 0; reg < 4; ++reg) {
        int row = r0 + 16*w + quad*4 + reg;
        if (row < NN) {
            float inv = 1.f / rs[reg];
            #pragma unroll
            for (int dt = 0; dt < 7; ++dt) {
                int d = dt*16 + n16;
                if (d < 104)
                    z1[((size_t)t*NN + row)*104 + d] = f2b(onum[dt][reg] * inv);
            }
        }
    }
}

// ---------------- linear-attention KV summaries -> compact band tile ----------------
// kvsb[b][c][j] (108 x 32 bf16): c<104: row c=lo+d holds kvs[h][m=j][d] at j; c=104+h holds ksum.
// Each (b,head) block writes only its own 27 rows -> race-free; pad cols never read.
__global__ void __launch_bounds__(256) kvs_kernel(
    const bf16* __restrict__ qkv, bf16* __restrict__ kvsb,
    int L, long long strideB, long long strideL)
{
    int b = blockIdx.x, head = blockIdx.y;
    long long base = (long long)b*strideB + 104 + head*HD;   // k; v at +104
    __shared__ float kc[32][27], vc[32][27], inv[32];
    int tid = threadIdx.x;
    float acc[3] = {0.f,0.f,0.f};
    float ks = 0.f;
    for (int l0 = 0; l0 < L; l0 += 32) {
        int lw = min(32, L - l0);
        __syncthreads();
        for (int idx = tid; idx < lw*HD; idx += 256) {
            int ll = idx / HD, m = idx - ll*HD;
            long long a = base + (long long)(l0 + ll)*strideL + m;
            kc[ll][m] = b2f(qkv[a]);
            vc[ll][m] = b2f(qkv[a + 104]);
        }
        __syncthreads();
        if (tid < lw) {
            float ss = 0.f;
            #pragma unroll
            for (int m = 0; m < HD; ++m) { float v = kc[tid][m]; ss += v*v; }
            inv[tid] = 1.f / fmaxf(sqrtf(ss), 1e-12f);
        }
        __syncthreads();
        for (int idx = tid; idx < lw*HD; idx += 256) {
            int ll = idx / HD, m = idx - ll*HD;
            kc[ll][m] *= inv[ll];
        }
        __syncthreads();
        #pragma unroll
        for (int jj = 0; jj < 3; ++jj) {
            int p = tid + jj*256;
            if (p < HD*HD) {
                int m = p / HD, d = p - m*HD;
                float a = 0.f;
                for (int ll = 0; ll < lw; ++ll) a += kc[ll][m] * vc[ll][d];
                acc[jj] += a;
            }
        }
        if (tid < HD) {
            float a = 0.f;
            for (int ll = 0; ll < lw; ++ll) a += kc[ll][tid];
            ks += a;
        }
    }
    long long tb = (long long)b * NTILE;
    int lo = head*HD;
    #pragma unroll
    for (int jj = 0; jj < 3; ++jj) {
        int p = tid + jj*256;
        if (p < HD*HD) {
            int m = p / HD, d = p - m*HD;
            kvsb[tb + (size_t)(lo + d)*32 + m] = f2b(acc[jj]);
        }
    }
    if (tid < HD) kvsb[tb + (size_t)(104 + head)*32 + tid] = f2b(ks);
}

// ---------------- MFMA linear-attention apply ----------------
// out[m][c] = (iq*(q[m].KVblk[:,c]) + Lf*v[m][c]) / (iq*(q[m].ksum_h) + Lf),  h=c/26
// Ws 112x128: zero-filled in LDS, band copied from compact kvsb.
// Temporal runs FIRST (writes [104:208]); spatial then reads q and writes [0:104].
__global__ void __launch_bounds__(256) attn_mm(
    bf16* __restrict__ qkv, const bf16* __restrict__ kvsb,
    int M, long long bStride, long long rowStride, float Lf, int outOff)
{
    constexpr int STR = 136;
    __shared__ bf16 As[64*STR];
    __shared__ bf16 Ws[112*STR];
    __shared__ float nsqL[64*4];
    __shared__ float denL[64*4];
    int mt = blockIdx.x, bb = blockIdx.y;
    int tid = threadIdx.x;
    int lane = tid & 63, w = tid >> 6, n16 = lane & 15, quad = lane >> 4;
    bf16* base = qkv + (size_t)bb * bStride;
    int r0 = mt*64;
    uint4 z4 = {0u,0u,0u,0u};

    // stage A: 64 rows x 16 uint4 (13 data covering q[0:104], 3 zero)
    for (int idx = tid; idx < 64*16; idx += 256) {
        int r = idx >> 4, q = idx & 15;
        int m = r0 + r;
        uint4 v = z4;
        if (m < M && q < 13) v = *(const uint4*)(base + (size_t)m*rowStride + q*8);
        *(uint4*)(&As[r*STR + q*8]) = v;
    }
    // zero Ws k-range 0..127
    for (int idx = tid; idx < 112*16; idx += 256) {
        int c = idx >> 4, q = idx & 15;
        *(uint4*)(&Ws[c*STR + q*8]) = z4;
    }
    __syncthreads();
    // copy band: 108 rows x 13 uints into [lo, lo+26)
    {
        const bf16* kb = kvsb + (size_t)bb * NTILE;
        for (int idx = tid; idx < 108*13; idx += 256) {
            int c = idx / 13, qu = idx - c*13;
            int lo = (c < 104) ? (c/26)*26 : (c-104)*26;
            *(uint*)(&Ws[c*STR + lo + qu*2]) = *(const uint*)(kb + (size_t)c*32 + qu*2);
        }
    }
    __syncthreads();

    short8v af[4];
    #pragma unroll
    for (int s = 0; s < 4; ++s)
        af[s] = *(const short8v*)(&As[(16*w + n16)*STR + s*32 + quad*8]);
    float4v acc[7];
    #pragma unroll
    for (int ct = 0; ct < 7; ++ct) { float4v z = {0.f,0.f,0.f,0.f}; acc[ct] = z; }
    #pragma unroll
    for (int ct = 0; ct < 7; ++ct) {
        #pragma unroll
        for (int s = 0; s < 4; ++s) {
            short8v bfr = *(const short8v*)(&Ws[(ct*16 + n16)*STR + s*32 + quad*8]);
            acc[ct] = __builtin_amdgcn_mfma_f32_16x16x32_bf16(af[s], bfr, acc[ct], 0, 0, 0);
        }
    }
    // per-(row,head) ||q||^2 from staged A
    {
        int row = tid >> 2, hh = tid & 3;
        const bf16* qr = &As[row*STR + hh*26];
        float ss = 0.f;
        #pragma unroll
        for (int m = 0; m < HD; ++m) { float v = b2f(qr[m]); ss += v*v; }
        nsqL[row*4 + hh] = ss;
    }
    // den_raw cols (104..107) -> LDS
    if (n16 >= 8 && n16 < 12) {
        #pragma unroll
        for (int reg = 0; reg < 4; ++reg)
            denL[(16*w + quad*4 + reg)*4 + (n16 - 8)] = acc[6][reg];
    }
    __syncthreads();
    // epilogue
    #pragma unroll
    for (int ct = 0; ct < 7; ++ct) {
        int c = ct*16 + n16;
        if (c < 104) {
            int hh = c / 26;
            #pragma unroll
            for (int reg = 0; reg < 4; ++reg) {
                int lr = 16*w + quad*4 + reg;
                int m = r0 + lr;
                if (m < M) {
                    float iq = 1.f / fmaxf(sqrtf(nsqL[lr*4 + hh]), 1e-12f);
                    float den = iq * denL[lr*4 + hh] + Lf;
                    bf16* rp = base + (size_t)m*rowStride;
                    float num = iq * acc[ct][reg] + Lf * b2f(rp[208 + c]);
                    rp[outOff + c] = f2b(num / den);
                }
            }
        }
    }
}

__device__ __forceinline__ float bsum128(float v, float* red, int tid) {
    #pragma unroll
    for (int off = 32; off > 0; off >>= 1) v += __shfl_down(v, off, 64);
    __syncthreads();
    if ((tid & 63) == 0) red[tid >> 6] = v;
    __syncthreads();
    return red[0] + red[1];
}

__global__ void __launch_bounds__(128) ln1_kernel(
    bf16* __restrict__ h, const bf16* __restrict__ att0, const bf16* __restrict__ att1,
    const bf16* __restrict__ p0, const bf16* __restrict__ p1,
    const float* __restrict__ gamma, const float* __restrict__ beta)
{
    int tid = threadIdx.x;
    size_t base = (size_t)blockIdx.x * 104;
    __shared__ float red[2];
    float x = 0.f;
    if (tid < 104) {
        float hv = b2f(h[base + tid]);
        x = 2.f * (hv + b2f(att0[base + tid])*b2f(p0[base + tid])
                      + 0.01f*b2f(att1[base + tid])*b2f(p1[base + tid]));
    }
    float mean = bsum128(x, red, tid) * (1.f/104.f);
    float dx = (tid < 104) ? (x - mean) : 0.f;
    float var = bsum128(dx*dx, red, tid) * (1.f/104.f);
    if (tid < 104)
        h[base + tid] = f2b(dx * rsqrtf(var + 1e-5f) * gamma[tid] + beta[tid]);
}

__global__ void __launch_bounds__(128) ln2_kernel(
    const bf16* __restrict__ h1, const bf16* __restrict__ m,
    const float* __restrict__ gamma, const float* __restrict__ beta,
    bf16* __restrict__ h2)
{
    int tid = threadIdx.x;
    size_t base = (size_t)blockIdx.x * 104;
    __shared__ float red[2];
    float x = 0.f;
    if (tid < 104) x = b2f(h1[base + tid]) + b2f(m[base + tid]);
    float mean = bsum128(x, red, tid) * (1.f/104.f);
    float dx = (tid < 104) ? (x - mean) : 0.f;
    float var = bsum128(dx*dx, red, tid) * (1.f/104.f);
    if (tid < 104)
        h2[base + tid] = f2b(dx * rsqrtf(var + 1e-5f) * gamma[tid] + beta[tid]);
}

__global__ void __launch_bounds__(256) y_init_kernel(float* __restrict__ y, const float* __restrict__ ep_b) {
    int i = blockIdx.x*256 + threadIdx.x;
    if (i < NN*104) y[i] = ep_b[i % 104];
}

__global__ void __launch_bounds__(256) enc_kernel(
    float* __restrict__ y, const float* __restrict__ w1, const float* __restrict__ b1,
    const float* __restrict__ w2, const float* __restrict__ b2)
{
    int n = blockIdx.x;
    int tid = threadIdx.x;
    __shared__ float yr[104], hid[208];
    if (tid < 104) yr[tid] = y[(size_t)n*104 + tid];
    __syncthreads();
    if (tid < 208) {
        float s = b1[tid];
        for (int k = 0; k < 104; ++k) s += yr[k] * w1[(size_t)k*208 + tid];
        hid[tid] = fmaxf(s, 0.f);
    }
    __syncthreads();
    if (tid < 104) {
        float s = b2[tid];
        for (int k = 0; k < 208; ++k) s += hid[k] * w2[(size_t)k*104 + tid];
        y[(size_t)n*104 + tid] = yr[tid] + s;
    }
}

__global__ void __launch_bounds__(256) out_kernel(
    const float* __restrict__ y, const float* __restrict__ out_w,
    const float* __restrict__ out_b, float* __restrict__ out)
{
    int n = blockIdx.x;
    int tid = threadIdx.x;
    __shared__ float yr[104];
    if (tid < 104) yr[tid] = y[(size_t)n*104 + tid];
    __syncthreads();
    for (int t = tid; t < TT; t += 256) {
        float s = out_b[t];
        for (int d = 0; d < 104; ++d) s += yr[d] * out_w[(size_t)d*TT + t];
        out[(size_t)n*TT + t] = s;
    }
}

// ---------------- launch ----------------
extern "C" void kernel_launch(void* const* d_in, const int* in_sizes, int n_in,
                              void* d_out, int out_size, void* d_ws, size_t ws_size,
                              hipStream_t stream) {
    if (ws_size < WS_NEEDED) return;   // readable failure instead of page fault

    const float* x      = (const float*)d_in[0];
    const float* W_in   = (const float*)d_in[1];
    const float* b_in   = (const float*)d_in[2];
    const float* adp    = (const float*)d_in[3];
    const float* W_tp   = (const float*)d_in[4];
    const float* b_tp   = (const float*)d_in[5];
    const float* qkv_w  = (const float*)d_in[6];
    const float* op_w   = (const float*)d_in[7];
    const float* op_b   = (const float*)d_in[8];
    const float* pw_w   = (const float*)d_in[9];
    const float* pw_b   = (const float*)d_in[10];
    const float* fc_w1  = (const float*)d_in[11];
    const float* fc_b1  = (const float*)d_in[12];
    const float* fc_w2  = (const float*)d_in[13];
    const float* fc_b2  = (const float*)d_in[14];
    const float* ln1_g  = (const float*)d_in[15];
    const float* ln1_b  = (const float*)d_in[16];
    const float* ln2_g  = (const float*)d_in[17];
    const float* ln2_b  = (const float*)d_in[18];
    const float* ep_w   = (const float*)d_in[19];
    const float* ep_b   = (const float*)d_in[20];
    const float* enc_w1 = (const float*)d_in[21];
    const float* enc_b1 = (const float*)d_in[22];
    const float* enc_w2 = (const float*)d_in[23];
    const float* enc_b2 = (const float*)d_in[24];
    const float* out_w  = (const float*)d_in[25];
    const float* out_b  = (const float*)d_in[26];

    bf16* B0 = (bf16*)d_ws;
    bf16* B1 = B0 + NB0;
    bf16* B2 = B1 + NB1;
    bf16* B3 = B2 + NB2;
    bf16* kvsb_s = B3 + NB3;
    bf16* kvsb_t = kvsb_s + NKVSB_S;
    float* ybuf  = (float*)(kvsb_t + NKVSB_T);
    bf16* wtp   = (bf16*)(ybuf + NY);
    bf16* wqkv0 = wtp + NW_TP;
    bf16* wqkv1 = wqkv0 + NW_QKV;
    bf16* wop0  = wqkv1 + NW_QKV;
    bf16* wop1  = wop0 + NW_OP;
    bf16* wpw0  = wop1 + NW_OP;
    bf16* wpw1  = wpw0 + NW_PW;
    bf16* wfc1  = wpw1 + NW_PW;
    bf16* wfc2  = wfc1 + NW_FC1;
    bf16* wept  = wfc2 + NW_FC2;
    // z1 scratch aliases B2 (dead between step 2 and step 4)
    bf16* adp_bf = B2;
    bf16* hTbuf  = B2 + NADP;

    // 0. weight prep (tiny)
    prep_w<<<CEILDIV(104*128,256), 256, 0, stream>>>(W_tp, wtp, 104, 104, 128);
    prep_w<<<CEILDIV(312*128,256), 256, 0, stream>>>(qkv_w, wqkv0, 104, 312, 128);
    prep_w<<<CEILDIV(312*128,256), 256, 0, stream>>>(qkv_w + 104*312, wqkv1, 104, 312, 128);
    prep_w<<<CEILDIV(104*224,256), 256, 0, stream>>>(op_w, wop0, 208, 104, 224);
    prep_w<<<CEILDIV(104*224,256), 256, 0, stream>>>(op_w + 208*104, wop1, 208, 104, 224);
    prep_w<<<CEILDIV(104*128,256), 256, 0, stream>>>(pw_w, wpw0, 104, 104, 128);
    prep_w<<<CEILDIV(104*128,256), 256, 0, stream>>>(pw_w + 104*104, wpw1, 104, 104, 128);
    prep_w<<<CEILDIV(208*128,256), 256, 0, stream>>>(fc_w1, wfc1, 104, 208, 128);
    prep_w<<<CEILDIV(104*224,256), 256, 0, stream>>>(fc_w2, wfc2, 208, 104, 224);
    prep_w<<<CEILDIV(104*37960,256), 256, 0, stream>>>(ep_w, wept, 37960, 104, 37960);

    const int GX = CEILDIV(TN, 64);     // 2282
    dim3 g2(GX, 2), g4(GX, 4), g5(GX, 5);

    // 1. hcat -> B2
    hcat_kernel<<<TN, 128, 0, stream>>>(x, W_in, b_in, adp, B2);
    // 2. h = hcat @ W_tp + b_tp -> B0  (hcat dead afterwards)
    gemm_mf<128><<<g2, 256, 0, stream>>>(B2, 104, 104, wtp, b_tp, B0, TN, 104, 0);
    // 2b. z1 pre-staging into B2: adp -> bf16 padded; h -> hT
    prep_adp<<<CEILDIV((int)NADP,256), 256, 0, stream>>>(adp, adp_bf);
    ht_kernel<<<dim3(7, TT), 256, 0, stream>>>(B0, hTbuf);
    // 3. z1 -> B1
    z1_mf<<<dim3(7, TT), 256, 0, stream>>>(adp_bf, hTbuf, B1);
    // 4. attention 0 on h
    gemm_mf<128><<<g5, 256, 0, stream>>>(B0, 104, 104, wqkv0, nullptr, B2, TN, 312, 0);
    kvs_kernel<<<dim3(TT, NH), 256, 0, stream>>>(B2, kvsb_s, NN, (long long)NN*312, 312);
    kvs_kernel<<<dim3(NN, NH), 256, 0, stream>>>(B2, kvsb_t, TT, 312, (long long)NN*312);
    attn_mm<<<dim3(6, NN), 256, 0, stream>>>(B2, kvsb_t, TT, 312, (long long)NN*312, (float)TT, 104);
    attn_mm<<<dim3(7, TT), 256, 0, stream>>>(B2, kvsb_s, NN, (long long)NN*312, 312, (float)NN, 0);
    gemm_mf<224><<<g2, 256, 0, stream>>>(B2, 312, 208, wop0, op_b, B3, TN, 104, 0);      // att0 -> B3
    // 5. attention 1 on z1
    gemm_mf<128><<<g5, 256, 0, stream>>>(B1, 104, 104, wqkv1, nullptr, B2, TN, 312, 0);
    kvs_kernel<<<dim3(TT, NH), 256, 0, stream>>>(B2, kvsb_s, NN, (long long)NN*312, 312);
    kvs_kernel<<<dim3(NN, NH), 256, 0, stream>>>(B2, kvsb_t, TT, 312, (long long)NN*312);
    attn_mm<<<dim3(6, NN), 256, 0, stream>>>(B2, kvsb_t, TT, 312, (long long)NN*312, (float)TT, 104);
    attn_mm<<<dim3(7, TT), 256, 0, stream>>>(B2, kvsb_s, NN, (long long)NN*312, 312, (float)NN, 0);
    gemm_mf<224><<<g2, 256, 0, stream>>>(B2, 312, 208, wop1, op_b + 104, B1, TN, 104, 0); // att1 -> B1
    // 6. pointwise gates -> B2
    gemm_mf<128><<<g2, 256, 0, stream>>>(B0, 104, 104, wpw0, pw_b, B2, TN, 104, 0);
    gemm_mf<128><<<g2, 256, 0, stream>>>(B3, 104, 104, wpw1, pw_b + 104, B2 + (size_t)TN*104, TN, 104, 0);
    // 7. LN1 in-place (B0 -> h1)
    ln1_kernel<<<TN, 128, 0, stream>>>(B0, B3, B1, B2, B2 + (size_t)TN*104, ln1_g, ln1_b);
    // 8. MLP + LN2
    gemm_mf<128><<<g4, 256, 0, stream>>>(B0, 104, 104, wfc1, fc_b1, B2, TN, 208, 1);
    gemm_mf<224><<<g2, 256, 0, stream>>>(B2, 208, 208, wfc2, fc_b2, B1, TN, 104, 0);
    ln2_kernel<<<TN, 128, 0, stream>>>(B0, B1, ln2_g, ln2_b, B3);                        // h2 -> B3
    // 9. encoder_proj
    y_init_kernel<<<CEILDIV(NN*104,256), 256, 0, stream>>>(ybuf, ep_b);
    ep_mf<<<dim3(CEILDIV(NN,64), 2, CEILDIV(TT,8)), 256, 0, stream>>>(B3, wept, ybuf);
    // 10. residual MLP blocks
    for (int i = 0; i < 3; ++i)
        enc_kernel<<<NN, 256, 0, stream>>>(ybuf, enc_w1 + (size_t)i*104*208, enc_b1 + (size_t)i*208,
                                           enc_w2 + (size_t)i*208*104, enc_b2 + (size_t)i*104);
    // 11. output projection
    out_kernel<<<NN, 256, 0, stream>>>(ybuf, out_w, out_b, (float*)d_out);
}

// Round 10
// 1525.621 us; speedup vs baseline: 3.8292x; 1.0984x over previous
//
#include <hip/hip_runtime.h>
#include <hip/hip_bf16.h>
#include <cstddef>

// ---------------- problem constants ----------------
#define TT   365
#define NN   400
#define TN   (TT*NN)            // 146000
#define HD   26                 // head dim
#define NH   4                  // heads

#define CEILDIV(a,b) (((a)+(b)-1)/(b))

typedef __hip_bfloat16 bf16;
typedef short short8v __attribute__((ext_vector_type(8)));
typedef float float4v __attribute__((ext_vector_type(4)));
__device__ __forceinline__ float b2f(bf16 v){ return __bfloat162float(v); }
__device__ __forceinline__ bf16  f2b(float v){ return __float2bfloat16(v); }

// ---------------- workspace layout ----------------
static constexpr size_t NB0 = (size_t)TN*104;   // h / h1
static constexpr size_t NB1 = (size_t)TN*104;   // z1 -> att1
static constexpr size_t NB2 = (size_t)TN*312;   // hcat -> [adp_bf|hT] -> qkv+concat -> hidden
static constexpr size_t NB3 = (size_t)TN*104;   // att0 -> h2
static constexpr size_t NBF = NB0+NB1+NB2+NB3;
// compact band KV tiles: per b, 108 rows x 32 (band cols 0..25), bf16
static constexpr size_t NTILE   = (size_t)108*32;
static constexpr size_t NKVSB_S = (size_t)TT*NTILE;
static constexpr size_t NKVSB_T = (size_t)NN*NTILE;
static constexpr size_t NY      = (size_t)NN*104;
// transposed bf16 weights (Wt[n][kp], zero-padded k)
static constexpr size_t NW_TP   = 104*128;
static constexpr size_t NW_QKV  = 312*128;   // x2
static constexpr size_t NW_OP   = 104*224;   // x2
static constexpr size_t NW_PW   = 104*128;   // x2
static constexpr size_t NW_FC1  = 208*128;
static constexpr size_t NW_FC2  = 104*224;
static constexpr size_t NW_EPT  = (size_t)104*37960;   // ep_w transposed, no pad
static constexpr size_t NWT     = NW_TP + 2*NW_QKV + 2*NW_OP + 2*NW_PW + NW_FC1 + NW_FC2 + NW_EPT;
static constexpr size_t WS_NEEDED = NBF*2 + (NKVSB_S+NKVSB_T)*2 + NY*4 + NWT*2;
// z1 scratch lives inside B2 (dead between step 2 and step 4):
static constexpr size_t NADP_ROWS = (size_t)TN + 64;
static constexpr size_t NADP = NADP_ROWS*96;
static constexpr size_t NHT  = ((size_t)TT*104 + 8)*448;
static_assert(NADP + NHT <= NB2, "z1 scratch must fit in B2");

// ---------------- weight prep: Wt[n*KP+k] = bf16(W[k*Nc+n]), zero pad k>=K ----------------
__global__ void __launch_bounds__(256) prep_w(
    const float* __restrict__ W, bf16* __restrict__ Wt, int K, int Nc, int KP)
{
    int idx = blockIdx.x*256 + threadIdx.x;
    if (idx >= Nc*KP) return;
    int n = idx / KP, k = idx - n*KP;
    Wt[idx] = (k < K) ? f2b(W[(size_t)k*Nc + n]) : f2b(0.f);
}

// coalesced LDS transpose for ep weights: Wt[n][k] = bf16(W[k][n]); W is 37960x104 fp32
__global__ void __launch_bounds__(256) prep_wT(
    const float* __restrict__ W, bf16* __restrict__ Wt)
{
    __shared__ float T[64][105];
    int k0 = blockIdx.x * 64;
    int tid = threadIdx.x;
    for (int idx = tid; idx < 64*104; idx += 256) {
        int r = idx / 104, c = idx - r*104;
        int k = k0 + r;
        T[r][c] = (k < 37960) ? W[(size_t)k*104 + c] : 0.f;
    }
    __syncthreads();
    for (int idx = tid; idx < 104*32; idx += 256) {
        int n = idx >> 5, kp = idx & 31;
        int k = kp*2;
        if (k0 + k + 1 < 37960 || k0 + k < 37960) {
            if (k0 + k < 37960) {
                bf16 lo = f2b(T[k][n]);
                bf16 hi = f2b(T[k+1][n]);   // k+1 row is zero-padded if OOB of tile data
                uint v = ((uint)(*(ushort*)&hi) << 16) | (*(ushort*)&lo);
                if (k0 + k + 1 < 37960) *(uint*)(Wt + (size_t)n*37960 + k0 + k) = v;
                else Wt[(size_t)n*37960 + k0 + k] = lo;
            }
        }
    }
}

// adp_bf[row][e] = bf16(adp[row][e]) for e<80 else 0; rows >= TN are zero.
__global__ void __launch_bounds__(256) prep_adp(
    const float* __restrict__ adp, bf16* __restrict__ out)
{
    size_t i = (size_t)blockIdx.x*256 + threadIdx.x;
    if (i >= NADP) return;
    size_t row = i / 96; int e = (int)(i - row*96);
    float v = (row < TN && e < 80) ? adp[row*80 + e] : 0.f;
    out[i] = f2b(v);
}

// hT[t][d][n] = h[t][n][d], n padded to 448 with zeros
__global__ void __launch_bounds__(256) ht_kernel(
    const bf16* __restrict__ h, bf16* __restrict__ hT)
{
    __shared__ bf16 As[64*106];
    int t = blockIdx.y, n0 = blockIdx.x*64;
    int tid = threadIdx.x;
    for (int idx = tid; idx < 64*52; idx += 256) {
        int r = idx / 52, k = idx - r*52;
        int n = n0 + r;
        uint v = 0;
        if (n < NN) v = *(const uint*)(h + ((size_t)t*NN + n)*104 + k*2);
        *(uint*)(&As[r*106 + k*2]) = v;
    }
    __syncthreads();
    for (int idx = tid; idx < 104*32; idx += 256) {
        int d = idx >> 5, np = idx & 31;
        int n = np*2;
        ushort lo = *(ushort*)&As[n*106 + d];
        ushort hi = *(ushort*)&As[(n+1)*106 + d];
        uint v = ((uint)hi << 16) | lo;
        *(uint*)(hT + ((size_t)t*104 + d)*448 + n0 + n) = v;
    }
}

// ---------------- hcat ----------------
__global__ void __launch_bounds__(128) hcat_kernel(
    const float* __restrict__ x, const float* __restrict__ W_in,
    const float* __restrict__ b_in, const float* __restrict__ adp,
    bf16* __restrict__ hcat)
{
    int bid = blockIdx.x;            // t*400 + n
    int t = bid / NN, n = bid - t*NN;
    int tid = threadIdx.x;
    if (tid < 24) {
        float s = b_in[tid];
        size_t xb = ((size_t)n*TT + t)*3;
        #pragma unroll
        for (int i = 0; i < 3; ++i) s += x[xb + i] * W_in[i*24 + tid];
        hcat[(size_t)bid*104 + tid] = f2b(s);
    } else if (tid < 104) {
        hcat[(size_t)bid*104 + tid] = f2b(adp[(size_t)bid*80 + (tid - 24)]);
    }
}

// ---------------- MFMA GEMM: C[M,Nc] = A[M,K](lda,bf16) @ W + bias ----------------
template<int KP>
__global__ void __launch_bounds__(256) gemm_mf(
    const bf16* __restrict__ A, int lda, int K,
    const bf16* __restrict__ Wt, const float* __restrict__ bias,
    bf16* __restrict__ C, int M, int Nc, int relu)
{
    constexpr int STR = KP + 8;
    constexpr int KPQ = KP/8;
    __shared__ bf16 As[64*STR];
    __shared__ bf16 Ws[64*STR];
    int m0 = blockIdx.x * 64;
    int c0 = blockIdx.y * 64;
    int tid = threadIdx.x;
    const int KQ = K/8;
    uint4 z4 = {0u,0u,0u,0u};
    for (int idx = tid; idx < 64*KPQ; idx += 256) {
        int r = idx / KPQ, q = idx - r*KPQ;
        int m = m0 + r;
        uint4 v = z4;
        if (m < M && q < KQ) v = *(const uint4*)(A + (size_t)m*lda + q*8);
        *(uint4*)(&As[r*STR + q*8]) = v;
    }
    for (int idx = tid; idx < 64*KPQ; idx += 256) {
        int r = idx / KPQ, q = idx - r*KPQ;
        int n = c0 + r;
        uint4 v = z4;
        if (n < Nc) v = *(const uint4*)(Wt + (size_t)n*KP + q*8);
        *(uint4*)(&Ws[r*STR + q*8]) = v;
    }
    __syncthreads();

    int lane = tid & 63, w = tid >> 6;
    int n16 = lane & 15, quad = lane >> 4;
    constexpr int KS = KP/32;
    short8v af[KS];
    #pragma unroll
    for (int s = 0; s < KS; ++s)
        af[s] = *(const short8v*)(&As[(16*w + n16)*STR + s*32 + quad*8]);
    float4v acc[4];
    #pragma unroll
    for (int ct = 0; ct < 4; ++ct) { float4v z = {0.f,0.f,0.f,0.f}; acc[ct] = z; }
    #pragma unroll
    for (int ct = 0; ct < 4; ++ct) {
        #pragma unroll
        for (int s = 0; s < KS; ++s) {
            short8v bfr = *(const short8v*)(&Ws[(ct*16 + n16)*STR + s*32 + quad*8]);
            acc[ct] = __builtin_amdgcn_mfma_f32_16x16x32_bf16(af[s], bfr, acc[ct], 0, 0, 0);
        }
    }
    #pragma unroll
    for (int ct = 0; ct < 4; ++ct) {
        int c = c0 + ct*16 + n16;
        if (c < Nc) {
            float b = bias ? bias[c] : 0.f;
            #pragma unroll
            for (int reg = 0; reg < 4; ++reg) {
                int m = m0 + 16*w + quad*4 + reg;
                if (m < M) {
                    float v = acc[ct][reg] + b;
                    if (relu) v = fmaxf(v, 0.f);
                    C[(size_t)m*Nc + c] = f2b(v);
                }
            }
        }
    }
}

// ---------------- fused gates + LN1 ----------------
// h1 = LN(2*(h + att0*(h@pw0+b0) + 0.01*att1*(att0@pw1+b1))) in-place into h.
// Full-row blocks: 64 rows x 104 cols (7 col-tiles), Ws buffer restaged w0 -> w1.
__global__ void __launch_bounds__(256) gate_ln1(
    bf16* __restrict__ h, const bf16* __restrict__ att0, const bf16* __restrict__ att1,
    const bf16* __restrict__ w0t, const bf16* __restrict__ w1t, const float* __restrict__ pwb,
    const float* __restrict__ gamma, const float* __restrict__ beta)
{
    constexpr int STR = 136;
    __shared__ bf16 A0s[64*STR];
    __shared__ bf16 A1s[64*STR];
    __shared__ bf16 Ws[112*STR];
    __shared__ float prm[416];     // pwb(208) | gamma(104) | beta(104)
    int m0 = blockIdx.x * 64;
    int tid = threadIdx.x;
    int lane = tid & 63, w = tid >> 6, n16 = lane & 15, quad = lane >> 4;
    uint4 z4 = {0u,0u,0u,0u};

    for (int idx = tid; idx < 64*16; idx += 256) {
        int r = idx >> 4, q = idx & 15;
        int m = m0 + r;
        uint4 v0 = z4, v1 = z4;
        if (m < TN && q < 13) {
            v0 = *(const uint4*)(h    + (size_t)m*104 + q*8);
            v1 = *(const uint4*)(att0 + (size_t)m*104 + q*8);
        }
        *(uint4*)(&A0s[r*STR + q*8]) = v0;
        *(uint4*)(&A1s[r*STR + q*8]) = v1;
    }
    for (int idx = tid; idx < 112*16; idx += 256) {
        int c = idx >> 4, q = idx & 15;
        uint4 v = z4;
        if (c < 104) v = *(const uint4*)(w0t + (size_t)c*128 + q*8);
        *(uint4*)(&Ws[c*STR + q*8]) = v;
    }
    for (int i = tid; i < 416; i += 256)
        prm[i] = (i < 208) ? pwb[i] : (i < 312 ? gamma[i-208] : beta[i-312]);
    __syncthreads();

    short8v a0f[4], a1f[4];
    #pragma unroll
    for (int s = 0; s < 4; ++s) {
        a0f[s] = *(const short8v*)(&A0s[(16*w + n16)*STR + s*32 + quad*8]);
        a1f[s] = *(const short8v*)(&A1s[(16*w + n16)*STR + s*32 + quad*8]);
    }
    float4v acc0[7], acc1[7];
    #pragma unroll
    for (int ct = 0; ct < 7; ++ct) { float4v z = {0.f,0.f,0.f,0.f}; acc0[ct] = z; acc1[ct] = z; }
    #pragma unroll
    for (int ct = 0; ct < 7; ++ct)
        #pragma unroll
        for (int s = 0; s < 4; ++s) {
            short8v bfr = *(const short8v*)(&Ws[(ct*16 + n16)*STR + s*32 + quad*8]);
            acc0[ct] = __builtin_amdgcn_mfma_f32_16x16x32_bf16(a0f[s], bfr, acc0[ct], 0, 0, 0);
        }
    __syncthreads();
    for (int idx = tid; idx < 112*16; idx += 256) {
        int c = idx >> 4, q = idx & 15;
        uint4 v = z4;
        if (c < 104) v = *(const uint4*)(w1t + (size_t)c*128 + q*8);
        *(uint4*)(&Ws[c*STR + q*8]) = v;
    }
    __syncthreads();
    #pragma unroll
    for (int ct = 0; ct < 7; ++ct)
        #pragma unroll
        for (int s = 0; s < 4; ++s) {
            short8v bfr = *(const short8v*)(&Ws[(ct*16 + n16)*STR + s*32 + quad*8]);
            acc1[ct] = __builtin_amdgcn_mfma_f32_16x16x32_bf16(a1f[s], bfr, acc1[ct], 0, 0, 0);
        }

    // epilogue: g -> LN (row distributed across the 16 n16 lanes)
    float sum[4] = {0.f,0.f,0.f,0.f};
    #pragma unroll
    for (int ct = 0; ct < 7; ++ct) {
        int c = ct*16 + n16;
        bool colok = c < 104;
        float b0 = colok ? prm[c] : 0.f;
        float b1 = colok ? prm[104 + c] : 0.f;
        #pragma unroll
        for (int reg = 0; reg < 4; ++reg) {
            int r = 16*w + quad*4 + reg;
            int m = m0 + r;
            float xv = 0.f;
            if (colok && m < TN) {
                float p0 = acc0[ct][reg] + b0;
                float p1 = acc1[ct][reg] + b1;
                float hv = b2f(A0s[r*STR + c]);
                float a0 = b2f(A1s[r*STR + c]);
                float a1 = b2f(att1[(size_t)m*104 + c]);
                xv = 2.f*(hv + a0*p0 + 0.01f*a1*p1);
            }
            acc0[ct][reg] = xv;
            sum[reg] += xv;
        }
    }
    #pragma unroll
    for (int reg = 0; reg < 4; ++reg) {
        float v = sum[reg];
        v += __shfl_xor(v,1,64); v += __shfl_xor(v,2,64);
        v += __shfl_xor(v,4,64); v += __shfl_xor(v,8,64);
        sum[reg] = v * (1.f/104.f);                     // mean
    }
    float var[4] = {0.f,0.f,0.f,0.f};
    #pragma unroll
    for (int ct = 0; ct < 7; ++ct) {
        bool colok = (ct*16 + n16) < 104;
        #pragma unroll
        for (int reg = 0; reg < 4; ++reg) {
            if (colok) {
                float d = acc0[ct][reg] - sum[reg];
                acc0[ct][reg] = d;
                var[reg] += d*d;
            }
        }
    }
    #pragma unroll
    for (int reg = 0; reg < 4; ++reg) {
        float v = var[reg];
        v += __shfl_xor(v,1,64); v += __shfl_xor(v,2,64);
        v += __shfl_xor(v,4,64); v += __shfl_xor(v,8,64);
        var[reg] = rsqrtf(v * (1.f/104.f) + 1e-5f);
    }
    #pragma unroll
    for (int ct = 0; ct < 7; ++ct) {
        int c = ct*16 + n16;
        if (c < 104) {
            float g = prm[208 + c], be = prm[312 + c];
            #pragma unroll
            for (int reg = 0; reg < 4; ++reg) {
                int m = m0 + 16*w + quad*4 + reg;
                if (m < TN)
                    h[(size_t)m*104 + c] = f2b(acc0[ct][reg]*var[reg]*g + be);
            }
        }
    }
}

// ---------------- fused fc2 + LN2: h2 = LN(h1 + hidden@fc_w2 + b) ----------------
// K=208 (pad 224) staged in two halves to keep LDS at 2 blocks/CU.
__global__ void __launch_bounds__(256) fc2_ln2(
    const bf16* __restrict__ hidden, const bf16* __restrict__ w2t, const float* __restrict__ b2,
    const bf16* __restrict__ h1, const float* __restrict__ gamma, const float* __restrict__ beta,
    bf16* __restrict__ h2)
{
    constexpr int STRA = 232;   // 224 + 8
    constexpr int STRW = 136;   // 128 + 8 (per half)
    __shared__ bf16 As[64*STRA];
    __shared__ bf16 Ws[112*STRW];
    __shared__ float prm[312];  // b2(104) | gamma(104) | beta(104)
    int m0 = blockIdx.x * 64;
    int tid = threadIdx.x;
    int lane = tid & 63, w = tid >> 6, n16 = lane & 15, quad = lane >> 4;
    uint4 z4 = {0u,0u,0u,0u};

    for (int idx = tid; idx < 64*28; idx += 256) {
        int r = idx / 28, q = idx - r*28;
        int m = m0 + r;
        uint4 v = z4;
        if (m < TN && q < 26) v = *(const uint4*)(hidden + (size_t)m*208 + q*8);
        *(uint4*)(&As[r*STRA + q*8]) = v;
    }
    for (int idx = tid; idx < 112*16; idx += 256) {
        int c = idx >> 4, q = idx & 15;
        uint4 v = z4;
        if (c < 104) v = *(const uint4*)(w2t + (size_t)c*224 + q*8);
        *(uint4*)(&Ws[c*STRW + q*8]) = v;
    }
    for (int i = tid; i < 312; i += 256)
        prm[i] = (i < 104) ? b2[i] : (i < 208 ? gamma[i-104] : beta[i-208]);
    __syncthreads();

    short8v af[7];
    #pragma unroll
    for (int s = 0; s < 7; ++s)
        af[s] = *(const short8v*)(&As[(16*w + n16)*STRA + s*32 + quad*8]);
    float4v acc[7];
    #pragma unroll
    for (int ct = 0; ct < 7; ++ct) { float4v z = {0.f,0.f,0.f,0.f}; acc[ct] = z; }
    #pragma unroll
    for (int ct = 0; ct < 7; ++ct)
        #pragma unroll
        for (int s = 0; s < 4; ++s) {
            short8v bfr = *(const short8v*)(&Ws[(ct*16 + n16)*STRW + s*32 + quad*8]);
            acc[ct] = __builtin_amdgcn_mfma_f32_16x16x32_bf16(af[s], bfr, acc[ct], 0, 0, 0);
        }
    __syncthreads();
    for (int idx = tid; idx < 112*16; idx += 256) {   // half 2: k 128..223 (12 data uint4)
        int c = idx >> 4, q = idx & 15;
        uint4 v = z4;
        if (c < 104 && q < 12) v = *(const uint4*)(w2t + (size_t)c*224 + 128 + q*8);
        *(uint4*)(&Ws[c*STRW + q*8]) = v;
    }
    __syncthreads();
    #pragma unroll
    for (int ct = 0; ct < 7; ++ct)
        #pragma unroll
        for (int s = 4; s < 7; ++s) {
            short8v bfr = *(const short8v*)(&Ws[(ct*16 + n16)*STRW + (s-4)*32 + quad*8]);
            acc[ct] = __builtin_amdgcn_mfma_f32_16x16x32_bf16(af[s], bfr, acc[ct], 0, 0, 0);
        }

    // epilogue: x = h1 + m  -> LN
    float sum[4] = {0.f,0.f,0.f,0.f};
    #pragma unroll
    for (int ct = 0; ct < 7; ++ct) {
        int c = ct*16 + n16;
        bool colok = c < 104;
        float bb = colok ? prm[c] : 0.f;
        #pragma unroll
        for (int reg = 0; reg < 4; ++reg) {
            int m = m0 + 16*w + quad*4 + reg;
            float xv = 0.f;
            if (colok && m < TN)
                xv = b2f(h1[(size_t)m*104 + c]) + acc[ct][reg] + bb;
            acc[ct][reg] = xv;
            sum[reg] += xv;
        }
    }
    #pragma unroll
    for (int reg = 0; reg < 4; ++reg) {
        float v = sum[reg];
        v += __shfl_xor(v,1,64); v += __shfl_xor(v,2,64);
        v += __shfl_xor(v,4,64); v += __shfl_xor(v,8,64);
        sum[reg] = v * (1.f/104.f);
    }
    float var[4] = {0.f,0.f,0.f,0.f};
    #pragma unroll
    for (int ct = 0; ct < 7; ++ct) {
        bool colok = (ct*16 + n16) < 104;
        #pragma unroll
        for (int reg = 0; reg < 4; ++reg) {
            if (colok) {
                float d = acc[ct][reg] - sum[reg];
                acc[ct][reg] = d;
                var[reg] += d*d;
            }
        }
    }
    #pragma unroll
    for (int reg = 0; reg < 4; ++reg) {
        float v = var[reg];
        v += __shfl_xor(v,1,64); v += __shfl_xor(v,2,64);
        v += __shfl_xor(v,4,64); v += __shfl_xor(v,8,64);
        var[reg] = rsqrtf(v * (1.f/104.f) + 1e-5f);
    }
    #pragma unroll
    for (int ct = 0; ct < 7; ++ct) {
        int c = ct*16 + n16;
        if (c < 104) {
            float g = prm[104 + c], be = prm[208 + c];
            #pragma unroll
            for (int reg = 0; reg < 4; ++reg) {
                int m = m0 + 16*w + quad*4 + reg;
                if (m < TN)
                    h2[(size_t)m*104 + c] = f2b(acc[ct][reg]*var[reg]*g + be);
            }
        }
    }
}

// ---------------- MFMA encoder_proj ----------------
__global__ void __launch_bounds__(256) ep_mf(
    const bf16* __restrict__ h2, const bf16* __restrict__ wt, float* __restrict__ y)
{
    constexpr int STR = 136;
    __shared__ bf16 As[64*STR];
    __shared__ bf16 Ws[64*STR];
    int m0 = blockIdx.x * 64;
    int c0 = blockIdx.y * 64;
    int t0 = blockIdx.z * 8;
    int t1 = min(TT, t0 + 8);
    int tid = threadIdx.x;
    int lane = tid & 63, w = tid >> 6, n16 = lane & 15, quad = lane >> 4;
    uint4 z4 = {0u,0u,0u,0u};

    float4v acc[4];
    #pragma unroll
    for (int ct = 0; ct < 4; ++ct) { float4v z = {0.f,0.f,0.f,0.f}; acc[ct] = z; }

    for (int t = t0; t < t1; ++t) {
        for (int idx = tid; idx < 64*16; idx += 256) {
            int r = idx >> 4, q = idx & 15;
            int m = m0 + r;
            uint4 va = z4;
            if (m < NN && q < 13) va = *(const uint4*)(h2 + ((size_t)t*NN + m)*104 + q*8);
            *(uint4*)(&As[r*STR + q*8]) = va;
            int c = c0 + r;
            uint4 vw = z4;
            if (c < 104 && q < 13) vw = *(const uint4*)(wt + (size_t)c*37960 + t*104 + q*8);
            *(uint4*)(&Ws[r*STR + q*8]) = vw;
        }
        __syncthreads();
        short8v af[4];
        #pragma unroll
        for (int s = 0; s < 4; ++s)
            af[s] = *(const short8v*)(&As[(16*w + n16)*STR + s*32 + quad*8]);
        #pragma unroll
        for (int ct = 0; ct < 4; ++ct) {
            #pragma unroll
            for (int s = 0; s < 4; ++s) {
                short8v bfr = *(const short8v*)(&Ws[(ct*16 + n16)*STR + s*32 + quad*8]);
                acc[ct] = __builtin_amdgcn_mfma_f32_16x16x32_bf16(af[s], bfr, acc[ct], 0, 0, 0);
            }
        }
        __syncthreads();
    }
    #pragma unroll
    for (int ct = 0; ct < 4; ++ct) {
        int c = c0 + ct*16 + n16;
        if (c < 104) {
            #pragma unroll
            for (int reg = 0; reg < 4; ++reg) {
                int m = m0 + 16*w + quad*4 + reg;
                if (m < NN) atomicAdd(&y[(size_t)m*104 + c], acc[ct][reg]);
            }
        }
    }
}

// ---------------- MFMA z1 ----------------
__global__ void __launch_bounds__(256) z1_mf(
    const bf16* __restrict__ adp_bf, const bf16* __restrict__ hT, bf16* __restrict__ z1)
{
    constexpr int SA = 104;
    constexpr int SP = 72;
    __shared__ bf16 As[64*SA];
    __shared__ bf16 Bt[64*SA];
    __shared__ bf16 Ht[112*SP];
    __shared__ bf16 P[64*SP];
    int t = blockIdx.y;
    int r0 = blockIdx.x * 64;
    int tid = threadIdx.x;
    int lane = tid & 63, w = tid >> 6, n16 = lane & 15, quad = lane >> 4;

    {
        const uint4* src = (const uint4*)(adp_bf + ((size_t)t*NN + r0)*96);
        for (int idx = tid; idx < 768; idx += 256) {
            int r = idx / 12, q = idx - r*12;
            *(uint4*)(&As[r*SA + q*8]) = src[idx];
        }
    }
    __syncthreads();
    short8v af[3];
    #pragma unroll
    for (int s = 0; s < 3; ++s)
        af[s] = *(const short8v*)(&As[(16*w + n16)*SA + s*32 + quad*8]);

    float4v onum[7];
    #pragma unroll
    for (int dt = 0; dt < 7; ++dt) { float4v z = {0.f,0.f,0.f,0.f}; onum[dt] = z; }
    float rs[4] = {0.f,0.f,0.f,0.f};

    for (int c0 = 0; c0 < NN; c0 += 64) {
        {
            const uint4* srcB = (const uint4*)(adp_bf + ((size_t)t*NN + c0)*96);
            for (int idx = tid; idx < 768; idx += 256) {
                int r = idx / 12, q = idx - r*12;
                *(uint4*)(&Bt[r*SA + q*8]) = srcB[idx];
            }
        }
        {
            const bf16* hb = hT + (size_t)t*104*448 + c0;
            for (int idx = tid; idx < 896; idx += 256) {
                int d = idx >> 3, q = idx & 7;
                *(uint4*)(&Ht[d*SP + q*8]) = *(const uint4*)(hb + (size_t)d*448 + q*8);
            }
        }
        __syncthreads();
        float4v sc[4];
        #pragma unroll
        for (int ct = 0; ct < 4; ++ct) { float4v z = {0.f,0.f,0.f,0.f}; sc[ct] = z; }
        #pragma unroll
        for (int ct = 0; ct < 4; ++ct) {
            #pragma unroll
            for (int s = 0; s < 3; ++s) {
                short8v bfr = *(const short8v*)(&Bt[(ct*16 + n16)*SA + s*32 + quad*8]);
                sc[ct] = __builtin_amdgcn_mfma_f32_16x16x32_bf16(af[s], bfr, sc[ct], 0, 0, 0);
            }
        }
        #pragma unroll
        for (int ct = 0; ct < 4; ++ct) {
            bool colok = (c0 + ct*16 + n16) < NN;
            #pragma unroll
            for (int reg = 0; reg < 4; ++reg) {
                float e = colok ? __expf(fmaxf(sc[ct][reg], 0.f)) : 0.f;
                rs[reg] += e;
                P[(16*w + quad*4 + reg)*SP + ct*16 + n16] = f2b(e);
            }
        }
        short8v pf[2];
        #pragma unroll
        for (int s = 0; s < 2; ++s)
            pf[s] = *(const short8v*)(&P[(16*w + n16)*SP + s*32 + quad*8]);
        #pragma unroll
        for (int dt = 0; dt < 7; ++dt) {
            #pragma unroll
            for (int s = 0; s < 2; ++s) {
                short8v bfr = *(const short8v*)(&Ht[(dt*16 + n16)*SP + s*32 + quad*8]);
                onum[dt] = __builtin_amdgcn_mfma_f32_16x16x32_bf16(pf[s], bfr, onum[dt], 0, 0, 0);
            }
        }
        __syncthreads();
    }
    #pragma unroll
    for (int reg = 0; reg < 4; ++reg) {
        float v = rs[reg];
        v += __shfl_xor(v, 1, 64);
        v += __shfl_xor(v, 2, 64);
        v += __shfl_xor(v, 4, 64);
        v += __shfl_xor(v, 8, 64);
        rs[reg] = v;
    }
    #pragma unroll
    for (int reg = 0; reg < 4; ++reg) {
        int row = r0 + 16*w + quad*4 + reg;
        if (row < NN) {
            float inv = 1.f / rs[reg];
            #pragma unroll
            for (int dt = 0; dt < 7; ++dt) {
                int d = dt*16 + n16;
                if (d < 104)
                    z1[((size_t)t*NN + row)*104 + d] = f2b(onum[dt][reg] * inv);
            }
        }
    }
}

// ---------------- merged KV summaries (spatial + temporal) ----------------
__global__ void __launch_bounds__(256) kvs_all(
    const bf16* __restrict__ qkv, bf16* __restrict__ kvsb_s, bf16* __restrict__ kvsb_t)
{
    int bb = blockIdx.x, head = blockIdx.y;
    int b; bf16* out; int L; long long strideB, strideL;
    if (bb < TT) { b = bb;      out = kvsb_s; L = NN; strideB = (long long)NN*312; strideL = 312; }
    else         { b = bb - TT; out = kvsb_t; L = TT; strideB = 312; strideL = (long long)NN*312; }
    long long base = (long long)b*strideB + 104 + head*HD;
    __shared__ float kc[32][27], vc[32][27], inv[32];
    int tid = threadIdx.x;
    float acc[3] = {0.f,0.f,0.f};
    float ks = 0.f;
    for (int l0 = 0; l0 < L; l0 += 32) {
        int lw = min(32, L - l0);
        __syncthreads();
        for (int idx = tid; idx < lw*HD; idx += 256) {
            int ll = idx / HD, m = idx - ll*HD;
            long long a = base + (long long)(l0 + ll)*strideL + m;
            kc[ll][m] = b2f(qkv[a]);
            vc[ll][m] = b2f(qkv[a + 104]);
        }
        __syncthreads();
        if (tid < lw) {
            float ss = 0.f;
            #pragma unroll
            for (int m = 0; m < HD; ++m) { float v = kc[tid][m]; ss += v*v; }
            inv[tid] = 1.f / fmaxf(sqrtf(ss), 1e-12f);
        }
        __syncthreads();
        for (int idx = tid; idx < lw*HD; idx += 256) {
            int ll = idx / HD, m = idx - ll*HD;
            kc[ll][m] *= inv[ll];
        }
        __syncthreads();
        #pragma unroll
        for (int jj = 0; jj < 3; ++jj) {
            int p = tid + jj*256;
            if (p < HD*HD) {
                int m = p / HD, d = p - m*HD;
                float a = 0.f;
                for (int ll = 0; ll < lw; ++ll) a += kc[ll][m] * vc[ll][d];
                acc[jj] += a;
            }
        }
        if (tid < HD) {
            float a = 0.f;
            for (int ll = 0; ll < lw; ++ll) a += kc[ll][tid];
            ks += a;
        }
    }
    long long tb = (long long)b * NTILE;
    int lo = head*HD;
    #pragma unroll
    for (int jj = 0; jj < 3; ++jj) {
        int p = tid + jj*256;
        if (p < HD*HD) {
            int m = p / HD, d = p - m*HD;
            out[tb + (size_t)(lo + d)*32 + m] = f2b(acc[jj]);
        }
    }
    if (tid < HD) out[tb + (size_t)(104 + head)*32 + tid] = f2b(ks);
}

// ---------------- MFMA linear-attention apply ----------------
__global__ void __launch_bounds__(256) attn_mm(
    bf16* __restrict__ qkv, const bf16* __restrict__ kvsb,
    int M, long long bStride, long long rowStride, float Lf, int outOff)
{
    constexpr int STR = 136;
    __shared__ bf16 As[64*STR];
    __shared__ bf16 Ws[112*STR];
    __shared__ float nsqL[64*4];
    __shared__ float denL[64*4];
    int mt = blockIdx.x, bb = blockIdx.y;
    int tid = threadIdx.x;
    int lane = tid & 63, w = tid >> 6, n16 = lane & 15, quad = lane >> 4;
    bf16* base = qkv + (size_t)bb * bStride;
    int r0 = mt*64;
    uint4 z4 = {0u,0u,0u,0u};

    for (int idx = tid; idx < 64*16; idx += 256) {
        int r = idx >> 4, q = idx & 15;
        int m = r0 + r;
        uint4 v = z4;
        if (m < M && q < 13) v = *(const uint4*)(base + (size_t)m*rowStride + q*8);
        *(uint4*)(&As[r*STR + q*8]) = v;
    }
    for (int idx = tid; idx < 112*16; idx += 256) {
        int c = idx >> 4, q = idx & 15;
        *(uint4*)(&Ws[c*STR + q*8]) = z4;
    }
    __syncthreads();
    {
        const bf16* kb = kvsb + (size_t)bb * NTILE;
        for (int idx = tid; idx < 108*13; idx += 256) {
            int c = idx / 13, qu = idx - c*13;
            int lo = (c < 104) ? (c/26)*26 : (c-104)*26;
            *(uint*)(&Ws[c*STR + lo + qu*2]) = *(const uint*)(kb + (size_t)c*32 + qu*2);
        }
    }
    __syncthreads();

    short8v af[4];
    #pragma unroll
    for (int s = 0; s < 4; ++s)
        af[s] = *(const short8v*)(&As[(16*w + n16)*STR + s*32 + quad*8]);
    float4v acc[7];
    #pragma unroll
    for (int ct = 0; ct < 7; ++ct) { float4v z = {0.f,0.f,0.f,0.f}; acc[ct] = z; }
    #pragma unroll
    for (int ct = 0; ct < 7; ++ct) {
        #pragma unroll
        for (int s = 0; s < 4; ++s) {
            short8v bfr = *(const short8v*)(&Ws[(ct*16 + n16)*STR + s*32 + quad*8]);
            acc[ct] = __builtin_amdgcn_mfma_f32_16x16x32_bf16(af[s], bfr, acc[ct], 0, 0, 0);
        }
    }
    {
        int row = tid >> 2, hh = tid & 3;
        const bf16* qr = &As[row*STR + hh*26];
        float ss = 0.f;
        #pragma unroll
        for (int m = 0; m < HD; ++m) { float v = b2f(qr[m]); ss += v*v; }
        nsqL[row*4 + hh] = ss;
    }
    if (n16 >= 8 && n16 < 12) {
        #pragma unroll
        for (int reg = 0; reg < 4; ++reg)
            denL[(16*w + quad*4 + reg)*4 + (n16 - 8)] = acc[6][reg];
    }
    __syncthreads();
    #pragma unroll
    for (int ct = 0; ct < 7; ++ct) {
        int c = ct*16 + n16;
        if (c < 104) {
            int hh = c / 26;
            #pragma unroll
            for (int reg = 0; reg < 4; ++reg) {
                int lr = 16*w + quad*4 + reg;
                int m = r0 + lr;
                if (m < M) {
                    float iq = 1.f / fmaxf(sqrtf(nsqL[lr*4 + hh]), 1e-12f);
                    float den = iq * denL[lr*4 + hh] + Lf;
                    bf16* rp = base + (size_t)m*rowStride;
                    float num = iq * acc[ct][reg] + Lf * b2f(rp[208 + c]);
                    rp[outOff + c] = f2b(num / den);
                }
            }
        }
    }
}

__global__ void __launch_bounds__(256) y_init_kernel(float* __restrict__ y, const float* __restrict__ ep_b) {
    int i = blockIdx.x*256 + threadIdx.x;
    if (i < NN*104) y[i] = ep_b[i % 104];
}

__global__ void __launch_bounds__(256) enc_kernel(
    float* __restrict__ y, const float* __restrict__ w1, const float* __restrict__ b1,
    const float* __restrict__ w2, const float* __restrict__ b2)
{
    int n = blockIdx.x;
    int tid = threadIdx.x;
    __shared__ float yr[104], hid[208];
    if (tid < 104) yr[tid] = y[(size_t)n*104 + tid];
    __syncthreads();
    if (tid < 208) {
        float s = b1[tid];
        for (int k = 0; k < 104; ++k) s += yr[k] * w1[(size_t)k*208 + tid];
        hid[tid] = fmaxf(s, 0.f);
    }
    __syncthreads();
    if (tid < 104) {
        float s = b2[tid];
        for (int k = 0; k < 208; ++k) s += hid[k] * w2[(size_t)k*104 + tid];
        y[(size_t)n*104 + tid] = yr[tid] + s;
    }
}

__global__ void __launch_bounds__(256) out_kernel(
    const float* __restrict__ y, const float* __restrict__ out_w,
    const float* __restrict__ out_b, float* __restrict__ out)
{
    int n = blockIdx.x;
    int tid = threadIdx.x;
    __shared__ float yr[104];
    if (tid < 104) yr[tid] = y[(size_t)n*104 + tid];
    __syncthreads();
    for (int t = tid; t < TT; t += 256) {
        float s = out_b[t];
        for (int d = 0; d < 104; ++d) s += yr[d] * out_w[(size_t)d*TT + t];
        out[(size_t)n*TT + t] = s;
    }
}

// ---------------- launch ----------------
extern "C" void kernel_launch(void* const* d_in, const int* in_sizes, int n_in,
                              void* d_out, int out_size, void* d_ws, size_t ws_size,
                              hipStream_t stream) {
    if (ws_size < WS_NEEDED) return;

    const float* x      = (const float*)d_in[0];
    const float* W_in   = (const float*)d_in[1];
    const float* b_in   = (const float*)d_in[2];
    const float* adp    = (const float*)d_in[3];
    const float* W_tp   = (const float*)d_in[4];
    const float* b_tp   = (const float*)d_in[5];
    const float* qkv_w  = (const float*)d_in[6];
    const float* op_w   = (const float*)d_in[7];
    const float* op_b   = (const float*)d_in[8];
    const float* pw_w   = (const float*)d_in[9];
    const float* pw_b   = (const float*)d_in[10];
    const float* fc_w1  = (const float*)d_in[11];
    const float* fc_b1  = (const float*)d_in[12];
    const float* fc_w2  = (const float*)d_in[13];
    const float* fc_b2  = (const float*)d_in[14];
    const float* ln1_g  = (const float*)d_in[15];
    const float* ln1_b  = (const float*)d_in[16];
    const float* ln2_g  = (const float*)d_in[17];
    const float* ln2_b  = (const float*)d_in[18];
    const float* ep_w   = (const float*)d_in[19];
    const float* ep_b   = (const float*)d_in[20];
    const float* enc_w1 = (const float*)d_in[21];
    const float* enc_b1 = (const float*)d_in[22];
    const float* enc_w2 = (const float*)d_in[23];
    const float* enc_b2 = (const float*)d_in[24];
    const float* out_w  = (const float*)d_in[25];
    const float* out_b  = (const float*)d_in[26];

    bf16* B0 = (bf16*)d_ws;
    bf16* B1 = B0 + NB0;
    bf16* B2 = B1 + NB1;
    bf16* B3 = B2 + NB2;
    bf16* kvsb_s = B3 + NB3;
    bf16* kvsb_t = kvsb_s + NKVSB_S;
    float* ybuf  = (float*)(kvsb_t + NKVSB_T);
    bf16* wtp   = (bf16*)(ybuf + NY);
    bf16* wqkv0 = wtp + NW_TP;
    bf16* wqkv1 = wqkv0 + NW_QKV;
    bf16* wop0  = wqkv1 + NW_QKV;
    bf16* wop1  = wop0 + NW_OP;
    bf16* wpw0  = wop1 + NW_OP;
    bf16* wpw1  = wpw0 + NW_PW;
    bf16* wfc1  = wpw1 + NW_PW;
    bf16* wfc2  = wfc1 + NW_FC1;
    bf16* wept  = wfc2 + NW_FC2;
    bf16* adp_bf = B2;
    bf16* hTbuf  = B2 + NADP;

    // 0. weight prep
    prep_w<<<CEILDIV(104*128,256), 256, 0, stream>>>(W_tp, wtp, 104, 104, 128);
    prep_w<<<CEILDIV(312*128,256), 256, 0, stream>>>(qkv_w, wqkv0, 104, 312, 128);
    prep_w<<<CEILDIV(312*128,256), 256, 0, stream>>>(qkv_w + 104*312, wqkv1, 104, 312, 128);
    prep_w<<<CEILDIV(104*224,256), 256, 0, stream>>>(op_w, wop0, 208, 104, 224);
    prep_w<<<CEILDIV(104*224,256), 256, 0, stream>>>(op_w + 208*104, wop1, 208, 104, 224);
    prep_w<<<CEILDIV(104*128,256), 256, 0, stream>>>(pw_w, wpw0, 104, 104, 128);
    prep_w<<<CEILDIV(104*128,256), 256, 0, stream>>>(pw_w + 104*104, wpw1, 104, 104, 128);
    prep_w<<<CEILDIV(208*128,256), 256, 0, stream>>>(fc_w1, wfc1, 104, 208, 128);
    prep_w<<<CEILDIV(104*224,256), 256, 0, stream>>>(fc_w2, wfc2, 208, 104, 224);
    prep_wT<<<CEILDIV(37960,64), 256, 0, stream>>>(ep_w, wept);

    const int GX = CEILDIV(TN, 64);     // 2282
    dim3 g4(GX, 4), g5(GX, 5);

    // 1. hcat -> B2
    hcat_kernel<<<TN, 128, 0, stream>>>(x, W_in, b_in, adp, B2);
    // 2. h = hcat @ W_tp + b_tp -> B0
    gemm_mf<128><<<dim3(GX,2), 256, 0, stream>>>(B2, 104, 104, wtp, b_tp, B0, TN, 104, 0);
    // 2b. z1 pre-staging into B2
    prep_adp<<<CEILDIV((int)NADP,256), 256, 0, stream>>>(adp, adp_bf);
    ht_kernel<<<dim3(7, TT), 256, 0, stream>>>(B0, hTbuf);
    // 3. z1 -> B1
    z1_mf<<<dim3(7, TT), 256, 0, stream>>>(adp_bf, hTbuf, B1);
    // 4. attention 0 on h
    gemm_mf<128><<<g5, 256, 0, stream>>>(B0, 104, 104, wqkv0, nullptr, B2, TN, 312, 0);
    kvs_all<<<dim3(TT+NN, NH), 256, 0, stream>>>(B2, kvsb_s, kvsb_t);
    attn_mm<<<dim3(6, NN), 256, 0, stream>>>(B2, kvsb_t, TT, 312, (long long)NN*312, (float)TT, 104);
    attn_mm<<<dim3(7, TT), 256, 0, stream>>>(B2, kvsb_s, NN, (long long)NN*312, 312, (float)NN, 0);
    gemm_mf<224><<<dim3(GX,2), 256, 0, stream>>>(B2, 312, 208, wop0, op_b, B3, TN, 104, 0);   // att0 -> B3
    // 5. attention 1 on z1
    gemm_mf<128><<<g5, 256, 0, stream>>>(B1, 104, 104, wqkv1, nullptr, B2, TN, 312, 0);
    kvs_all<<<dim3(TT+NN, NH), 256, 0, stream>>>(B2, kvsb_s, kvsb_t);
    attn_mm<<<dim3(6, NN), 256, 0, stream>>>(B2, kvsb_t, TT, 312, (long long)NN*312, (float)TT, 104);
    attn_mm<<<dim3(7, TT), 256, 0, stream>>>(B2, kvsb_s, NN, (long long)NN*312, 312, (float)NN, 0);
    gemm_mf<224><<<dim3(GX,2), 256, 0, stream>>>(B2, 312, 208, wop1, op_b + 104, B1, TN, 104, 0); // att1 -> B1
    // 6+7. fused gates + LN1 (in-place B0 -> h1)
    gate_ln1<<<GX, 256, 0, stream>>>(B0, B3, B1, wpw0, wpw1, pw_b, ln1_g, ln1_b);
    // 8. MLP: fc1 -> hidden (B2), fused fc2+LN2 -> h2 (B3)
    gemm_mf<128><<<g4, 256, 0, stream>>>(B0, 104, 104, wfc1, fc_b1, B2, TN, 208, 1);
    fc2_ln2<<<GX, 256, 0, stream>>>(B2, wfc2, fc_b2, B0, ln2_g, ln2_b, B3);
    // 9. encoder_proj
    y_init_kernel<<<CEILDIV(NN*104,256), 256, 0, stream>>>(ybuf, ep_b);
    ep_mf<<<dim3(CEILDIV(NN,64), 2, CEILDIV(TT,8)), 256, 0, stream>>>(B3, wept, ybuf);
    // 10. residual MLP blocks
    for (int i = 0; i < 3; ++i)
        enc_kernel<<<NN, 256, 0, stream>>>(ybuf, enc_w1 + (size_t)i*104*208, enc_b1 + (size_t)i*208,
                                           enc_w2 + (size_t)i*208*104, enc_b2 + (size_t)i*104);
    // 11. output projection
    out_kernel<<<NN, 256, 0, stream>>>(ybuf, out_w, out_b, (float*)d_out);
}